// Round 2
// baseline (881.135 us; speedup 1.0000x reference)
//
#include <hip/hip_runtime.h>
#include <math.h>

#define BATCH 512
#define N_NODES 116
#define IN_DIM 123
#define HID 128
#define HEADS 4
#define FLAT_DIM 1280

static constexpr int ROWS = 8;
static constexpr int BN_TOT = BATCH * N_NODES;      // 59392
static constexpr int HROW = N_NODES * HID;          // 14848
static constexpr int ADJROW = N_NODES * N_NODES;    // 13456
static constexpr int EIROW = N_NODES * HEADS;       // 464

__device__ __forceinline__ float elu1(float x) {
    return x > 0.f ? x : expm1f(x);
}

// ---------------- encoder: h = BN(elu(x @ W_enc + b_enc)) ----------------
__global__ __launch_bounds__(128) void enc_kernel(
    const float* __restrict__ x, const float* __restrict__ W,
    const float* __restrict__ bias,
    const float* __restrict__ g, const float* __restrict__ bta,
    const float* __restrict__ mn, const float* __restrict__ vr,
    float* __restrict__ hout)
{
    __shared__ float s_x[ROWS * IN_DIM];
    const int t = threadIdx.x;
    const int row0 = blockIdx.x * ROWS;
    for (int idx = t; idx < ROWS * IN_DIM; idx += 128)
        s_x[idx] = x[(size_t)row0 * IN_DIM + idx];
    __syncthreads();
    float acc[ROWS];
    const float bv = bias[t];
#pragma unroll
    for (int r = 0; r < ROWS; ++r) acc[r] = bv;
    for (int k = 0; k < IN_DIM; ++k) {
        const float w = W[k * HID + t];
#pragma unroll
        for (int r = 0; r < ROWS; ++r) acc[r] += s_x[r * IN_DIM + k] * w;
    }
    const float gg = g[t], bb = bta[t], mm = mn[t];
    const float rstd = rsqrtf(vr[t] + 1e-5f);
#pragma unroll
    for (int r = 0; r < ROWS; ++r) {
        float val = elu1(acc[r]);
        val = (val - mm) * rstd * gg + bb;
        hout[(size_t)(row0 + r) * HID + t] = val;
    }
}

// ---------------- Wh = h @ W, plus ei/ej GAT score halves ----------------
__global__ __launch_bounds__(128) void wh_kernel(
    const float* __restrict__ h, const float* __restrict__ W,
    const float* __restrict__ a,
    float* __restrict__ Wh, float* __restrict__ ei, float* __restrict__ ej)
{
    __shared__ float s_h[ROWS * HID];
    const int t = threadIdx.x;
    const int row0 = blockIdx.x * ROWS;
#pragma unroll
    for (int r = 0; r < ROWS; ++r)
        s_h[r * HID + t] = h[(size_t)(row0 + r) * HID + t];
    __syncthreads();
    float acc[ROWS] = {};
    for (int k = 0; k < HID; ++k) {
        const float w = W[k * HID + t];
#pragma unroll
        for (int r = 0; r < ROWS; ++r) acc[r] += s_h[r * HID + k] * w;
    }
    const int hh = t >> 5, d = t & 31;
    const float asrc = a[hh * 64 + d];
    const float adst = a[hh * 64 + 32 + d];
#pragma unroll
    for (int r = 0; r < ROWS; ++r) {
        const int row = row0 + r;
        Wh[(size_t)row * HID + t] = acc[r];
        float ps = acc[r] * asrc;
        float pd = acc[r] * adst;
#pragma unroll
        for (int off = 16; off; off >>= 1) {
            ps += __shfl_xor(ps, off);
            pd += __shfl_xor(pd, off);
        }
        if (d == 0) {
            ei[row * HEADS + hh] = ps;
            ej[row * HEADS + hh] = pd;
        }
    }
}

// ---------------- GAT attention + aggregation + BN + elu + residual ------
// one block per batch element; h updated in place
template <bool ADD_H>
__global__ __launch_bounds__(256) void gat_aggr(
    const float* __restrict__ Wh, float* __restrict__ hio,
    const float* __restrict__ ei, const float* __restrict__ ej,
    const float* __restrict__ adj,
    const float* __restrict__ g, const float* __restrict__ bta,
    const float* __restrict__ mn, const float* __restrict__ vr)
{
    __shared__ float s_wh[HROW];          // 59392 B
    __shared__ float s_ei[EIROW];
    __shared__ float s_ej[EIROW];
    __shared__ float s_sc[HEADS * N_NODES];  // [h][j]
    __shared__ float s_part[256];
    __shared__ float s_dinv[HEADS];

    const int t = threadIdx.x;
    const int b = blockIdx.x;
    const size_t whbase = (size_t)b * HROW;
    const size_t adjbase = (size_t)b * ADJROW;

    {
        const float4* src = reinterpret_cast<const float4*>(Wh + whbase);
        float4* dst = reinterpret_cast<float4*>(s_wh);
        for (int idx = t; idx < HROW / 4; idx += 256) dst[idx] = src[idx];
        for (int idx = t; idx < EIROW; idx += 256) {
            s_ei[idx] = ei[b * EIROW + idx];
            s_ej[idx] = ej[b * EIROW + idx];
        }
    }
    // per-thread BN params (only t<128 uses them)
    const int f_ep = t & 127;
    const float gg = g[f_ep], bb = bta[f_ep], mm = mn[f_ep];
    const float rstd = rsqrtf(vr[f_ep] + 1e-5f);
    __syncthreads();

    for (int i = 0; i < N_NODES; ++i) {
        // phase A: raw scores — 464 entries, strided over 256 threads
        for (int idx = t; idx < N_NODES * HEADS; idx += 256) {
            const int j = idx >> 2, hh = idx & 3;
            float e = s_ei[i * HEADS + hh] + s_ej[j * HEADS + hh];
            e = e > 0.f ? e : 0.2f * e;
            const float av = adj[adjbase + (size_t)i * N_NODES + j];
            if (av == 0.f) e = -1e30f;
            s_sc[hh * N_NODES + j] = e;
        }
        __syncthreads();
        // per-head softmax prep: wave w handles head w
        {
            const int w = t >> 6, l = t & 63;
            float v1 = s_sc[w * N_NODES + l];
            float v2 = (l < N_NODES - 64) ? s_sc[w * N_NODES + 64 + l] : -1e30f;
            float mx = fmaxf(v1, v2);
#pragma unroll
            for (int off = 32; off; off >>= 1) mx = fmaxf(mx, __shfl_xor(mx, off));
            const float e1 = expf(v1 - mx);
            const float e2 = (l < N_NODES - 64) ? expf(v2 - mx) : 0.f;
            s_sc[w * N_NODES + l] = e1;
            if (l < N_NODES - 64) s_sc[w * N_NODES + 64 + l] = e2;
            float sm = e1 + e2;
#pragma unroll
            for (int off = 32; off; off >>= 1) sm += __shfl_xor(sm, off);
            if (l == 0) s_dinv[w] = 1.f / sm;
        }
        __syncthreads();
        // phase B: aggregation, j split in two halves
        {
            const int half = t >> 7, f = t & 127, hh = f >> 5;
            float acc = 0.f;
            const int j0 = half * (N_NODES / 2);
            for (int jj = 0; jj < N_NODES / 2; ++jj) {
                const int j = j0 + jj;
                acc += s_sc[hh * N_NODES + j] * s_wh[j * HID + f];
            }
            s_part[t] = acc;
        }
        __syncthreads();
        if (t < HID) {
            const int f = t;
            const float aval = (s_part[f] + s_part[f + 128]) * s_dinv[f >> 5];
            float xv = (aval - mm) * rstd * gg + bb;
            xv = elu1(xv);
            float outv = xv + s_wh[i * HID + f];
            if (ADD_H) outv += hio[whbase + (size_t)i * HID + f];
            hio[whbase + (size_t)i * HID + f] = outv;
        }
        __syncthreads();
    }
}

// ---------------- vn0 = vne + mean_n(h) ----------------
__global__ __launch_bounds__(128) void vn0_kernel(
    const float* __restrict__ h, const float* __restrict__ vne,
    float* __restrict__ vn)
{
    const int b = blockIdx.x, f = threadIdx.x;
    float s = 0.f;
    for (int n = 0; n < N_NODES; ++n) s += h[(size_t)b * HROW + n * HID + f];
    vn[b * HID + f] = vne[f] + s * (1.f / N_NODES);
}

// ---------------- vn_out = elu(cat([prev, mean_n(h)]) @ Wv + bv) ----------
__global__ __launch_bounds__(128) void vn_mlp_kernel(
    const float* __restrict__ prev, const float* __restrict__ h,
    const float* __restrict__ Wv, const float* __restrict__ bv,
    float* __restrict__ vout)
{
    __shared__ float cat[2 * HID];
    const int b = blockIdx.x, f = threadIdx.x;
    float s = 0.f;
    for (int n = 0; n < N_NODES; ++n) s += h[(size_t)b * HROW + n * HID + f];
    cat[f] = prev[b * HID + f];
    cat[HID + f] = s * (1.f / N_NODES);
    __syncthreads();
    float acc = bv[f];
    for (int k = 0; k < 2 * HID; ++k) acc += cat[k] * Wv[k * HID + f];
    vout[b * HID + f] = elu1(acc);
}

// ---------------- h += 0.1 * vn_new (broadcast over nodes) ----------------
__global__ __launch_bounds__(256) void add_vn_kernel(
    float* __restrict__ h, const float* __restrict__ vn)
{
    const int idx = blockIdx.x * 256 + threadIdx.x;  // over float4 elems
    float4* h4 = reinterpret_cast<float4*>(h);
    const float4* v4 = reinterpret_cast<const float4*>(vn);
    const int f4 = idx & 31;
    const int row = idx >> 5;
    const int b = row / N_NODES;
    float4 hv = h4[idx];
    const float4 vv = v4[b * 32 + f4];
    hv.x += 0.1f * vv.x; hv.y += 0.1f * vv.y;
    hv.z += 0.1f * vv.z; hv.w += 0.1f * vv.w;
    h4[idx] = hv;
}

// ---------------- pooling + net attention + flat + LayerNorm --------------
__global__ __launch_bounds__(128) void pool_flat_kernel(
    const float* __restrict__ h, const float* __restrict__ vnf,
    const float* __restrict__ pm,
    const float* __restrict__ Wa1, const float* __restrict__ ba1,
    const float* __restrict__ Wa2, const float* __restrict__ ba2,
    const float* __restrict__ ln_g, const float* __restrict__ ln_b,
    float* __restrict__ out)
{
    __shared__ float s_pm[N_NODES * 9];
    __shared__ float s_p[9][HID];
    __shared__ float s_s[9];
    __shared__ float s_red[4];
    const int b = blockIdx.x, f = threadIdx.x;
    for (int idx = f; idx < N_NODES * 9; idx += 128) s_pm[idx] = pm[idx];
    float p[9] = {};
    __syncthreads();
    for (int n = 0; n < N_NODES; ++n) {
        const float hv = h[(size_t)b * HROW + n * HID + f];
#pragma unroll
        for (int k = 0; k < 9; ++k) p[k] += s_pm[n * 9 + k] * hv;
    }
#pragma unroll
    for (int k = 0; k < 9; ++k) s_p[k][f] = p[k];
    __syncthreads();
    // scores: 4 networks per pass, 32 lanes each
    for (int pass = 0; pass < 3; ++pass) {
        const int k = pass * 4 + (f >> 5);
        if (k < 9) {
            const int j = f & 31;
            float z = ba1[j];
            for (int d = 0; d < HID; ++d) z += s_p[k][d] * Wa1[d * 32 + j];
            z = tanhf(z);
            float part = z * Wa2[j];
#pragma unroll
            for (int off = 16; off; off >>= 1) part += __shfl_xor(part, off);
            if (j == 0) s_s[k] = part + ba2[0];
        }
    }
    __syncthreads();
    // softmax over 9 networks (redundant per thread)
    float smax = -1e30f;
#pragma unroll
    for (int k = 0; k < 9; ++k) smax = fmaxf(smax, s_s[k]);
    float wgt[9], ssum = 0.f;
#pragma unroll
    for (int k = 0; k < 9; ++k) { wgt[k] = expf(s_s[k] - smax); ssum += wgt[k]; }
    const float sinv = 1.f / ssum;
    // flat values this thread owns: 9 pooled + 1 vn (feature f of each chunk)
    float vals[10];
#pragma unroll
    for (int k = 0; k < 9; ++k) vals[k] = p[k] * wgt[k] * sinv;
    vals[9] = vnf[b * HID + f];
    float lsum = 0.f, lsq = 0.f;
#pragma unroll
    for (int q = 0; q < 10; ++q) { lsum += vals[q]; lsq += vals[q] * vals[q]; }
#pragma unroll
    for (int off = 32; off; off >>= 1) {
        lsum += __shfl_xor(lsum, off);
        lsq += __shfl_xor(lsq, off);
    }
    const int lane = f & 63, wid = f >> 6;
    if (lane == 0) { s_red[wid * 2] = lsum; s_red[wid * 2 + 1] = lsq; }
    __syncthreads();
    const float tot = s_red[0] + s_red[2];
    const float totsq = s_red[1] + s_red[3];
    const float mean = tot * (1.f / FLAT_DIM);
    const float var = totsq * (1.f / FLAT_DIM) - mean * mean;
    const float rstd = rsqrtf(var + 1e-5f);
    float* fout = out + 1024 + (size_t)b * FLAT_DIM;
#pragma unroll
    for (int k = 0; k < 9; ++k) {
        const int j = k * HID + f;
        fout[j] = (vals[k] - mean) * rstd * ln_g[j] + ln_b[j];
    }
    const int j = 9 * HID + f;
    fout[j] = (vals[9] - mean) * rstd * ln_g[j] + ln_b[j];
}

// ---------------- classifier: logits = elu(flat@Wc1+bc1)@Wc2+bc2 ---------
__global__ __launch_bounds__(256) void cls_kernel(
    const float* __restrict__ flat,
    const float* __restrict__ Wc1, const float* __restrict__ bc1,
    const float* __restrict__ Wc2, const float* __restrict__ bc2,
    float* __restrict__ out)
{
    __shared__ float s_f[ROWS * FLAT_DIM];   // 40 KB
    __shared__ float s_hid[ROWS * 256];      // 8 KB
    const int t = threadIdx.x;
    const int row0 = blockIdx.x * ROWS;
    for (int idx = t; idx < ROWS * FLAT_DIM; idx += 256)
        s_f[idx] = flat[(size_t)row0 * FLAT_DIM + idx];
    __syncthreads();
    float acc[ROWS];
    const float bv = bc1[t];
#pragma unroll
    for (int r = 0; r < ROWS; ++r) acc[r] = bv;
    for (int k = 0; k < FLAT_DIM; ++k) {
        const float w = Wc1[k * 256 + t];
#pragma unroll
        for (int r = 0; r < ROWS; ++r) acc[r] += s_f[r * FLAT_DIM + k] * w;
    }
#pragma unroll
    for (int r = 0; r < ROWS; ++r) s_hid[r * 256 + t] = elu1(acc[r]);
    __syncthreads();
    if (t < 2 * ROWS) {
        const int r = t >> 1, c = t & 1;
        float a = bc2[c];
        for (int q = 0; q < 256; ++q) a += s_hid[r * 256 + q] * Wc2[q * 2 + c];
        out[(size_t)(row0 + r) * 2 + c] = a;
    }
}

extern "C" void kernel_launch(void* const* d_in, const int* in_sizes, int n_in,
                              void* d_out, int out_size, void* d_ws, size_t ws_size,
                              hipStream_t stream)
{
    const float* x     = (const float*)d_in[0];
    const float* adj   = (const float*)d_in[1];
    const float* W_enc = (const float*)d_in[2];
    const float* b_enc = (const float*)d_in[3];
    const float* bn_g  = (const float*)d_in[4];
    const float* bn_b  = (const float*)d_in[5];
    const float* bn_m  = (const float*)d_in[6];
    const float* bn_v  = (const float*)d_in[7];
    const float* vne   = (const float*)d_in[8];
    const float* W1    = (const float*)d_in[9];
    const float* a1    = (const float*)d_in[10];
    const float* g1    = (const float*)d_in[11];
    const float* bt1   = (const float*)d_in[12];
    const float* m1    = (const float*)d_in[13];
    const float* v1    = (const float*)d_in[14];
    const float* W2    = (const float*)d_in[15];
    const float* a2    = (const float*)d_in[16];
    const float* g2    = (const float*)d_in[17];
    const float* bt2   = (const float*)d_in[18];
    const float* m2    = (const float*)d_in[19];
    const float* v2    = (const float*)d_in[20];
    const float* Wv    = (const float*)d_in[21];
    const float* bv    = (const float*)d_in[22];
    const float* pm    = (const float*)d_in[23];
    const float* Wa1   = (const float*)d_in[24];
    const float* ba1   = (const float*)d_in[25];
    const float* Wa2   = (const float*)d_in[26];
    const float* ba2   = (const float*)d_in[27];
    const float* ln_g  = (const float*)d_in[28];
    const float* ln_b  = (const float*)d_in[29];
    const float* Wc1   = (const float*)d_in[30];
    const float* bc1   = (const float*)d_in[31];
    const float* Wc2   = (const float*)d_in[32];
    const float* bc2   = (const float*)d_in[33];
    float* out = (float*)d_out;

    float* ws = (float*)d_ws;
    float* h   = ws;                       // 7,602,176 floats
    float* Wh  = h + (size_t)BN_TOT * HID; // 7,602,176
    float* ei  = Wh + (size_t)BN_TOT * HID;          // 237,568
    float* ej  = ei + (size_t)BN_TOT * HEADS;        // 237,568
    float* vn0 = ej + (size_t)BN_TOT * HEADS;        // 65,536
    float* vnn = vn0 + BATCH * HID;
    float* vnf = vnn + BATCH * HID;

    enc_kernel<<<BN_TOT / ROWS, 128, 0, stream>>>(x, W_enc, b_enc, bn_g, bn_b,
                                                  bn_m, bn_v, h);
    vn0_kernel<<<BATCH, 128, 0, stream>>>(h, vne, vn0);
    // GAT layer 1
    wh_kernel<<<BN_TOT / ROWS, 128, 0, stream>>>(h, W1, a1, Wh, ei, ej);
    gat_aggr<false><<<BATCH, 256, 0, stream>>>(Wh, h, ei, ej, adj, g1, bt1, m1, v1);
    // virtual node update
    vn_mlp_kernel<<<BATCH, 128, 0, stream>>>(vn0, h, Wv, bv, vnn);
    add_vn_kernel<<<(BN_TOT * HID / 4) / 256, 256, 0, stream>>>(h, vnn);
    // GAT layer 2 (+h residual)
    wh_kernel<<<BN_TOT / ROWS, 128, 0, stream>>>(h, W2, a2, Wh, ei, ej);
    gat_aggr<true><<<BATCH, 256, 0, stream>>>(Wh, h, ei, ej, adj, g2, bt2, m2, v2);
    // final virtual node
    vn_mlp_kernel<<<BATCH, 128, 0, stream>>>(vnn, h, Wv, bv, vnf);
    // pooling + flat + LayerNorm (writes out[1024:])
    pool_flat_kernel<<<BATCH, 128, 0, stream>>>(h, vnf, pm, Wa1, ba1, Wa2, ba2,
                                                ln_g, ln_b, out);
    // classifier (reads flat from out, writes out[0:1024])
    cls_kernel<<<BATCH / ROWS, 256, 0, stream>>>(out + 1024, Wc1, bc1, Wc2, bc2, out);
}

// Round 3
// 643.750 us; speedup vs baseline: 1.3688x; 1.3688x over previous
//
#include <hip/hip_runtime.h>
#include <math.h>

#define BATCH 512
#define N_NODES 116
#define IN_DIM 123
#define HID 128
#define HEADS 4
#define FLAT_DIM 1280

static constexpr int ROWS = 8;
static constexpr int BN_TOT = BATCH * N_NODES;      // 59392
static constexpr int HROW = N_NODES * HID;          // 14848
static constexpr int ADJROW = N_NODES * N_NODES;    // 13456

__device__ __forceinline__ float elu1(float x) {
    return x > 0.f ? x : expm1f(x);
}

// ---------------- encoder: h = BN(elu(x @ W_enc + b_enc)) ----------------
__global__ __launch_bounds__(128) void enc_kernel(
    const float* __restrict__ x, const float* __restrict__ W,
    const float* __restrict__ bias,
    const float* __restrict__ g, const float* __restrict__ bta,
    const float* __restrict__ mn, const float* __restrict__ vr,
    float* __restrict__ hout)
{
    __shared__ float s_x[ROWS * IN_DIM];
    const int t = threadIdx.x;
    const int row0 = blockIdx.x * ROWS;
    for (int idx = t; idx < ROWS * IN_DIM; idx += 128)
        s_x[idx] = x[(size_t)row0 * IN_DIM + idx];
    __syncthreads();
    float acc[ROWS];
    const float bv = bias[t];
#pragma unroll
    for (int r = 0; r < ROWS; ++r) acc[r] = bv;
    for (int k = 0; k < IN_DIM; ++k) {
        const float w = W[k * HID + t];
#pragma unroll
        for (int r = 0; r < ROWS; ++r) acc[r] += s_x[r * IN_DIM + k] * w;
    }
    const float gg = g[t], bb = bta[t], mm = mn[t];
    const float rstd = rsqrtf(vr[t] + 1e-5f);
#pragma unroll
    for (int r = 0; r < ROWS; ++r) {
        float val = elu1(acc[r]);
        val = (val - mm) * rstd * gg + bb;
        hout[(size_t)(row0 + r) * HID + t] = val;
    }
}

// ---------------- Wh = h @ W, plus ei/ej GAT score halves ----------------
__global__ __launch_bounds__(128) void wh_kernel(
    const float* __restrict__ h, const float* __restrict__ W,
    const float* __restrict__ a,
    float* __restrict__ Wh, float* __restrict__ ei, float* __restrict__ ej)
{
    __shared__ float s_h[ROWS * HID];
    const int t = threadIdx.x;
    const int row0 = blockIdx.x * ROWS;
#pragma unroll
    for (int r = 0; r < ROWS; ++r)
        s_h[r * HID + t] = h[(size_t)(row0 + r) * HID + t];
    __syncthreads();
    float acc[ROWS] = {};
    for (int k = 0; k < HID; ++k) {
        const float w = W[k * HID + t];
#pragma unroll
        for (int r = 0; r < ROWS; ++r) acc[r] += s_h[r * HID + k] * w;
    }
    const int hh = t >> 5, d = t & 31;
    const float asrc = a[hh * 64 + d];
    const float adst = a[hh * 64 + 32 + d];
#pragma unroll
    for (int r = 0; r < ROWS; ++r) {
        const int row = row0 + r;
        Wh[(size_t)row * HID + t] = acc[r];
        float ps = acc[r] * asrc;
        float pd = acc[r] * adst;
#pragma unroll
        for (int off = 16; off; off >>= 1) {
            ps += __shfl_xor(ps, off);
            pd += __shfl_xor(pd, off);
        }
        if (d == 0) {
            ei[row * HEADS + hh] = ps;
            ej[row * HEADS + hh] = pd;
        }
    }
}

// ---------------- GAT attention + aggregation + BN + elu + residual ------
// one block per (batch, head); h updated in place on the block's feature slice
template <bool ADD_H>
__global__ __launch_bounds__(256) void gat_aggr(
    const float* __restrict__ Wh, float* __restrict__ hio,
    const float* __restrict__ ei, const float* __restrict__ ej,
    const float* __restrict__ adj,
    const float* __restrict__ g, const float* __restrict__ bta,
    const float* __restrict__ mn, const float* __restrict__ vr)
{
    constexpr int PP = 124;                 // pitch: mult of 4 (16B align)
    __shared__ float s_p[N_NODES][PP];      // softmaxed probs, row-major
    __shared__ float s_wt[32][PP];          // Whh^T : [d][j]
    __shared__ float s_ei[N_NODES];
    __shared__ float s_ej[N_NODES];

    const int t = threadIdx.x;
    const int b = blockIdx.x >> 2;
    const int h = blockIdx.x & 3;
    const size_t whbase = (size_t)b * HROW + h * 32;

    // ---- phase 1: stage WhhT + ei/ej ----
    for (int idx = t; idx < N_NODES * 32; idx += 256) {
        const int j = idx >> 5, d = idx & 31;
        s_wt[d][j] = Wh[whbase + (size_t)j * HID + d];
    }
    for (int idx = t; idx < 2 * N_NODES; idx += 256) {
        if (idx < N_NODES)
            s_ei[idx] = ei[((size_t)b * N_NODES + idx) * HEADS + h];
        else
            s_ej[idx - N_NODES] = ej[((size_t)b * N_NODES + idx - N_NODES) * HEADS + h];
    }
    __syncthreads();

    // ---- phase 2: scores + row softmax (wave w owns rows [29w, 29w+29)) ----
    {
        const int w = t >> 6, l = t & 63;
        const size_t adjb = (size_t)b * ADJROW;
        const float ejl = s_ej[l];
        const float ejl2 = (l < N_NODES - 64) ? s_ej[l + 64] : 0.f;
        for (int i = w * 29; i < w * 29 + 29; ++i) {
            const float eii = s_ei[i];
            float e1 = eii + ejl;
            e1 = e1 > 0.f ? e1 : 0.2f * e1;
            const float av1 = adj[adjb + (size_t)i * N_NODES + l];
            if (av1 == 0.f) e1 = -1e30f;
            float e2 = -1e30f;
            if (l < N_NODES - 64) {
                e2 = eii + ejl2;
                e2 = e2 > 0.f ? e2 : 0.2f * e2;
                const float av2 = adj[adjb + (size_t)i * N_NODES + l + 64];
                if (av2 == 0.f) e2 = -1e30f;
            }
            float mx = fmaxf(e1, e2);
#pragma unroll
            for (int off = 32; off; off >>= 1) mx = fmaxf(mx, __shfl_xor(mx, off));
            const float x1 = expf(e1 - mx);
            const float x2 = (l < N_NODES - 64) ? expf(e2 - mx) : 0.f;
            float sm = x1 + x2;
#pragma unroll
            for (int off = 32; off; off >>= 1) sm += __shfl_xor(sm, off);
            const float rinv = 1.f / sm;
            s_p[i][l] = x1 * rinv;
            if (l < N_NODES - 64) s_p[i][l + 64] = x2 * rinv;
        }
    }
    __syncthreads();

    // ---- phase 3: register-tiled aggregation: out[i0:4][d0:4] ----
    if (t < 232) {
        const int rg = t >> 3;          // 0..28
        const int cg = t & 7;           // 0..7
        const int i0 = rg * 4, d0 = cg * 4;
        float acc[4][4] = {};
        for (int j = 0; j < N_NODES; j += 4) {
            float4 p0 = *(const float4*)&s_p[i0 + 0][j];
            float4 p1 = *(const float4*)&s_p[i0 + 1][j];
            float4 p2 = *(const float4*)&s_p[i0 + 2][j];
            float4 p3 = *(const float4*)&s_p[i0 + 3][j];
            float4 w0 = *(const float4*)&s_wt[d0 + 0][j];
            float4 w1 = *(const float4*)&s_wt[d0 + 1][j];
            float4 w2 = *(const float4*)&s_wt[d0 + 2][j];
            float4 w3 = *(const float4*)&s_wt[d0 + 3][j];
            const float4 pr[4] = {p0, p1, p2, p3};
            const float4 wc[4] = {w0, w1, w2, w3};
#pragma unroll
            for (int r = 0; r < 4; ++r)
#pragma unroll
                for (int c = 0; c < 4; ++c) {
                    acc[r][c] += pr[r].x * wc[c].x + pr[r].y * wc[c].y
                               + pr[r].z * wc[c].z + pr[r].w * wc[c].w;
                }
        }
        // ---- epilogue: BN + elu + residual (+old h), write in place ----
        const int f0 = h * 32 + d0;
        const float4 gv = *(const float4*)&g[f0];
        const float4 bv = *(const float4*)&bta[f0];
        const float4 mv = *(const float4*)&mn[f0];
        const float4 vv = *(const float4*)&vr[f0];
        const float rs0 = rsqrtf(vv.x + 1e-5f);
        const float rs1 = rsqrtf(vv.y + 1e-5f);
        const float rs2 = rsqrtf(vv.z + 1e-5f);
        const float rs3 = rsqrtf(vv.w + 1e-5f);
#pragma unroll
        for (int r = 0; r < 4; ++r) {
            const int i = i0 + r;
            float4* dst = (float4*)&hio[((size_t)b * N_NODES + i) * HID + f0];
            float4 res;
            res.x = s_wt[d0 + 0][i];
            res.y = s_wt[d0 + 1][i];
            res.z = s_wt[d0 + 2][i];
            res.w = s_wt[d0 + 3][i];
            float4 old = {0.f, 0.f, 0.f, 0.f};
            if (ADD_H) old = *dst;
            float4 o;
            o.x = elu1((acc[r][0] - mv.x) * rs0 * gv.x + bv.x) + res.x + old.x;
            o.y = elu1((acc[r][1] - mv.y) * rs1 * gv.y + bv.y) + res.y + old.y;
            o.z = elu1((acc[r][2] - mv.z) * rs2 * gv.z + bv.z) + res.z + old.z;
            o.w = elu1((acc[r][3] - mv.w) * rs3 * gv.w + bv.w) + res.w + old.w;
            *dst = o;
        }
    }
}

// ---------------- vn0 = vne + mean_n(h) ----------------
__global__ __launch_bounds__(128) void vn0_kernel(
    const float* __restrict__ h, const float* __restrict__ vne,
    float* __restrict__ vn)
{
    const int b = blockIdx.x, f = threadIdx.x;
    float s = 0.f;
    for (int n = 0; n < N_NODES; ++n) s += h[(size_t)b * HROW + n * HID + f];
    vn[b * HID + f] = vne[f] + s * (1.f / N_NODES);
}

// ---------------- vn_out = elu(cat([prev, mean_n(h)]) @ Wv + bv) ----------
__global__ __launch_bounds__(128) void vn_mlp_kernel(
    const float* __restrict__ prev, const float* __restrict__ h,
    const float* __restrict__ Wv, const float* __restrict__ bv,
    float* __restrict__ vout)
{
    __shared__ float cat[2 * HID];
    const int b = blockIdx.x, f = threadIdx.x;
    float s = 0.f;
    for (int n = 0; n < N_NODES; ++n) s += h[(size_t)b * HROW + n * HID + f];
    cat[f] = prev[b * HID + f];
    cat[HID + f] = s * (1.f / N_NODES);
    __syncthreads();
    float acc = bv[f];
    for (int k = 0; k < 2 * HID; ++k) acc += cat[k] * Wv[k * HID + f];
    vout[b * HID + f] = elu1(acc);
}

// ---------------- h += 0.1 * vn_new (broadcast over nodes) ----------------
__global__ __launch_bounds__(256) void add_vn_kernel(
    float* __restrict__ h, const float* __restrict__ vn)
{
    const int idx = blockIdx.x * 256 + threadIdx.x;  // over float4 elems
    float4* h4 = reinterpret_cast<float4*>(h);
    const float4* v4 = reinterpret_cast<const float4*>(vn);
    const int f4 = idx & 31;
    const int row = idx >> 5;
    const int b = row / N_NODES;
    float4 hv = h4[idx];
    const float4 vv = v4[b * 32 + f4];
    hv.x += 0.1f * vv.x; hv.y += 0.1f * vv.y;
    hv.z += 0.1f * vv.z; hv.w += 0.1f * vv.w;
    h4[idx] = hv;
}

// ---------------- pooling + net attention + flat + LayerNorm --------------
__global__ __launch_bounds__(128) void pool_flat_kernel(
    const float* __restrict__ h, const float* __restrict__ vnf,
    const float* __restrict__ pm,
    const float* __restrict__ Wa1, const float* __restrict__ ba1,
    const float* __restrict__ Wa2, const float* __restrict__ ba2,
    const float* __restrict__ ln_g, const float* __restrict__ ln_b,
    float* __restrict__ out)
{
    __shared__ float s_pm[N_NODES * 9];
    __shared__ float s_p[9][HID];
    __shared__ float s_s[9];
    __shared__ float s_red[4];
    const int b = blockIdx.x, f = threadIdx.x;
    for (int idx = f; idx < N_NODES * 9; idx += 128) s_pm[idx] = pm[idx];
    float p[9] = {};
    __syncthreads();
    for (int n = 0; n < N_NODES; ++n) {
        const float hv = h[(size_t)b * HROW + n * HID + f];
#pragma unroll
        for (int k = 0; k < 9; ++k) p[k] += s_pm[n * 9 + k] * hv;
    }
#pragma unroll
    for (int k = 0; k < 9; ++k) s_p[k][f] = p[k];
    __syncthreads();
    // scores: 4 networks per pass, 32 lanes each
    for (int pass = 0; pass < 3; ++pass) {
        const int k = pass * 4 + (f >> 5);
        if (k < 9) {
            const int j = f & 31;
            float z = ba1[j];
            for (int d = 0; d < HID; ++d) z += s_p[k][d] * Wa1[d * 32 + j];
            z = tanhf(z);
            float part = z * Wa2[j];
#pragma unroll
            for (int off = 16; off; off >>= 1) part += __shfl_xor(part, off);
            if (j == 0) s_s[k] = part + ba2[0];
        }
    }
    __syncthreads();
    // softmax over 9 networks (redundant per thread)
    float smax = -1e30f;
#pragma unroll
    for (int k = 0; k < 9; ++k) smax = fmaxf(smax, s_s[k]);
    float wgt[9], ssum = 0.f;
#pragma unroll
    for (int k = 0; k < 9; ++k) { wgt[k] = expf(s_s[k] - smax); ssum += wgt[k]; }
    const float sinv = 1.f / ssum;
    float vals[10];
#pragma unroll
    for (int k = 0; k < 9; ++k) vals[k] = p[k] * wgt[k] * sinv;
    vals[9] = vnf[b * HID + f];
    float lsum = 0.f, lsq = 0.f;
#pragma unroll
    for (int q = 0; q < 10; ++q) { lsum += vals[q]; lsq += vals[q] * vals[q]; }
#pragma unroll
    for (int off = 32; off; off >>= 1) {
        lsum += __shfl_xor(lsum, off);
        lsq += __shfl_xor(lsq, off);
    }
    const int lane = f & 63, wid = f >> 6;
    if (lane == 0) { s_red[wid * 2] = lsum; s_red[wid * 2 + 1] = lsq; }
    __syncthreads();
    const float tot = s_red[0] + s_red[2];
    const float totsq = s_red[1] + s_red[3];
    const float mean = tot * (1.f / FLAT_DIM);
    const float var = totsq * (1.f / FLAT_DIM) - mean * mean;
    const float rstd = rsqrtf(var + 1e-5f);
    float* fout = out + 1024 + (size_t)b * FLAT_DIM;
#pragma unroll
    for (int k = 0; k < 9; ++k) {
        const int j = k * HID + f;
        fout[j] = (vals[k] - mean) * rstd * ln_g[j] + ln_b[j];
    }
    const int j = 9 * HID + f;
    fout[j] = (vals[9] - mean) * rstd * ln_g[j] + ln_b[j];
}

// ---------------- classifier: logits = elu(flat@Wc1+bc1)@Wc2+bc2 ---------
__global__ __launch_bounds__(256) void cls_kernel(
    const float* __restrict__ flat,
    const float* __restrict__ Wc1, const float* __restrict__ bc1,
    const float* __restrict__ Wc2, const float* __restrict__ bc2,
    float* __restrict__ out)
{
    __shared__ float s_f[ROWS * FLAT_DIM];   // 40 KB
    __shared__ float s_hid[ROWS * 256];      // 8 KB
    const int t = threadIdx.x;
    const int row0 = blockIdx.x * ROWS;
    for (int idx = t; idx < ROWS * FLAT_DIM; idx += 256)
        s_f[idx] = flat[(size_t)row0 * FLAT_DIM + idx];
    __syncthreads();
    float acc[ROWS];
    const float bv = bc1[t];
#pragma unroll
    for (int r = 0; r < ROWS; ++r) acc[r] = bv;
    for (int k = 0; k < FLAT_DIM; ++k) {
        const float w = Wc1[k * 256 + t];
#pragma unroll
        for (int r = 0; r < ROWS; ++r) acc[r] += s_f[r * FLAT_DIM + k] * w;
    }
#pragma unroll
    for (int r = 0; r < ROWS; ++r) s_hid[r * 256 + t] = elu1(acc[r]);
    __syncthreads();
    if (t < 2 * ROWS) {
        const int r = t >> 1, c = t & 1;
        float a = bc2[c];
        for (int q = 0; q < 256; ++q) a += s_hid[r * 256 + q] * Wc2[q * 2 + c];
        out[(size_t)(row0 + r) * 2 + c] = a;
    }
}

extern "C" void kernel_launch(void* const* d_in, const int* in_sizes, int n_in,
                              void* d_out, int out_size, void* d_ws, size_t ws_size,
                              hipStream_t stream)
{
    const float* x     = (const float*)d_in[0];
    const float* adj   = (const float*)d_in[1];
    const float* W_enc = (const float*)d_in[2];
    const float* b_enc = (const float*)d_in[3];
    const float* bn_g  = (const float*)d_in[4];
    const float* bn_b  = (const float*)d_in[5];
    const float* bn_m  = (const float*)d_in[6];
    const float* bn_v  = (const float*)d_in[7];
    const float* vne   = (const float*)d_in[8];
    const float* W1    = (const float*)d_in[9];
    const float* a1    = (const float*)d_in[10];
    const float* g1    = (const float*)d_in[11];
    const float* bt1   = (const float*)d_in[12];
    const float* m1    = (const float*)d_in[13];
    const float* v1    = (const float*)d_in[14];
    const float* W2    = (const float*)d_in[15];
    const float* a2    = (const float*)d_in[16];
    const float* g2    = (const float*)d_in[17];
    const float* bt2   = (const float*)d_in[18];
    const float* m2    = (const float*)d_in[19];
    const float* v2    = (const float*)d_in[20];
    const float* Wv    = (const float*)d_in[21];
    const float* bv    = (const float*)d_in[22];
    const float* pm    = (const float*)d_in[23];
    const float* Wa1   = (const float*)d_in[24];
    const float* ba1   = (const float*)d_in[25];
    const float* Wa2   = (const float*)d_in[26];
    const float* ba2   = (const float*)d_in[27];
    const float* ln_g  = (const float*)d_in[28];
    const float* ln_b  = (const float*)d_in[29];
    const float* Wc1   = (const float*)d_in[30];
    const float* bc1   = (const float*)d_in[31];
    const float* Wc2   = (const float*)d_in[32];
    const float* bc2   = (const float*)d_in[33];
    float* out = (float*)d_out;

    float* ws = (float*)d_ws;
    float* h   = ws;                       // 7,602,176 floats
    float* Wh  = h + (size_t)BN_TOT * HID; // 7,602,176
    float* ei  = Wh + (size_t)BN_TOT * HID;          // 237,568
    float* ej  = ei + (size_t)BN_TOT * HEADS;        // 237,568
    float* vn0 = ej + (size_t)BN_TOT * HEADS;        // 65,536
    float* vnn = vn0 + BATCH * HID;
    float* vnf = vnn + BATCH * HID;

    enc_kernel<<<BN_TOT / ROWS, 128, 0, stream>>>(x, W_enc, b_enc, bn_g, bn_b,
                                                  bn_m, bn_v, h);
    vn0_kernel<<<BATCH, 128, 0, stream>>>(h, vne, vn0);
    // GAT layer 1
    wh_kernel<<<BN_TOT / ROWS, 128, 0, stream>>>(h, W1, a1, Wh, ei, ej);
    gat_aggr<false><<<BATCH * HEADS, 256, 0, stream>>>(Wh, h, ei, ej, adj, g1, bt1, m1, v1);
    // virtual node update
    vn_mlp_kernel<<<BATCH, 128, 0, stream>>>(vn0, h, Wv, bv, vnn);
    add_vn_kernel<<<(BN_TOT * HID / 4) / 256, 256, 0, stream>>>(h, vnn);
    // GAT layer 2 (+h residual)
    wh_kernel<<<BN_TOT / ROWS, 128, 0, stream>>>(h, W2, a2, Wh, ei, ej);
    gat_aggr<true><<<BATCH * HEADS, 256, 0, stream>>>(Wh, h, ei, ej, adj, g2, bt2, m2, v2);
    // final virtual node
    vn_mlp_kernel<<<BATCH, 128, 0, stream>>>(vnn, h, Wv, bv, vnf);
    // pooling + flat + LayerNorm (writes out[1024:])
    pool_flat_kernel<<<BATCH, 128, 0, stream>>>(h, vnf, pm, Wa1, ba1, Wa2, ba2,
                                                ln_g, ln_b, out);
    // classifier (reads flat from out, writes out[0:1024])
    cls_kernel<<<BATCH / ROWS, 256, 0, stream>>>(out + 1024, Wc1, bc1, Wc2, bc2, out);
}

// Round 4
// 560.508 us; speedup vs baseline: 1.5720x; 1.1485x over previous
//
#include <hip/hip_runtime.h>
#include <hip/hip_bf16.h>
#include <math.h>

#define BATCH 512
#define N_NODES 116
#define IN_DIM 123
#define HID 128
#define HEADS 4
#define FLAT_DIM 1280

static constexpr int ROWS = 8;
static constexpr int BN_TOT = BATCH * N_NODES;      // 59392
static constexpr int HROW = N_NODES * HID;          // 14848
static constexpr int ADJROW = N_NODES * N_NODES;    // 13456

typedef short short8 __attribute__((ext_vector_type(8)));
typedef float f32x16 __attribute__((ext_vector_type(16)));

__device__ __forceinline__ float elu1(float x) {
    return x > 0.f ? x : expm1f(x);
}

// ---------------- encoder: h = BN(elu(x @ W_enc + b_enc)) ----------------
__global__ __launch_bounds__(128) void enc_kernel(
    const float* __restrict__ x, const float* __restrict__ W,
    const float* __restrict__ bias,
    const float* __restrict__ g, const float* __restrict__ bta,
    const float* __restrict__ mn, const float* __restrict__ vr,
    float* __restrict__ hout)
{
    __shared__ float s_x[ROWS * IN_DIM];
    const int t = threadIdx.x;
    const int row0 = blockIdx.x * ROWS;
    for (int idx = t; idx < ROWS * IN_DIM; idx += 128)
        s_x[idx] = x[(size_t)row0 * IN_DIM + idx];
    __syncthreads();
    float acc[ROWS];
    const float bv = bias[t];
#pragma unroll
    for (int r = 0; r < ROWS; ++r) acc[r] = bv;
    for (int k = 0; k < IN_DIM; ++k) {
        const float w = W[k * HID + t];
#pragma unroll
        for (int r = 0; r < ROWS; ++r) acc[r] += s_x[r * IN_DIM + k] * w;
    }
    const float gg = g[t], bb = bta[t], mm = mn[t];
    const float rstd = rsqrtf(vr[t] + 1e-5f);
#pragma unroll
    for (int r = 0; r < ROWS; ++r) {
        float val = elu1(acc[r]);
        val = (val - mm) * rstd * gg + bb;
        hout[(size_t)(row0 + r) * HID + t] = val;
    }
}

// ---------------- Wh = h @ W, plus ei/ej GAT score halves ----------------
__global__ __launch_bounds__(128) void wh_kernel(
    const float* __restrict__ h, const float* __restrict__ W,
    const float* __restrict__ a,
    float* __restrict__ Wh, float* __restrict__ ei, float* __restrict__ ej)
{
    __shared__ float s_h[ROWS * HID];
    const int t = threadIdx.x;
    const int row0 = blockIdx.x * ROWS;
#pragma unroll
    for (int r = 0; r < ROWS; ++r)
        s_h[r * HID + t] = h[(size_t)(row0 + r) * HID + t];
    __syncthreads();
    float acc[ROWS] = {};
    for (int k = 0; k < HID; ++k) {
        const float w = W[k * HID + t];
#pragma unroll
        for (int r = 0; r < ROWS; ++r) acc[r] += s_h[r * HID + k] * w;
    }
    const int hh = t >> 5, d = t & 31;
    const float asrc = a[hh * 64 + d];
    const float adst = a[hh * 64 + 32 + d];
#pragma unroll
    for (int r = 0; r < ROWS; ++r) {
        const int row = row0 + r;
        Wh[(size_t)row * HID + t] = acc[r];
        float ps = acc[r] * asrc;
        float pd = acc[r] * adst;
#pragma unroll
        for (int off = 16; off; off >>= 1) {
            ps += __shfl_xor(ps, off);
            pd += __shfl_xor(pd, off);
        }
        if (d == 0) {
            ei[row * HEADS + hh] = ps;
            ej[row * HEADS + hh] = pd;
        }
    }
}

// ---------------- GAT attention + aggregation + BN + elu + residual ------
// one block per (batch, head); MFMA aggregation; h updated in place
template <bool ADD_H>
__global__ __launch_bounds__(256) void gat_aggr(
    const float* __restrict__ Wh, float* __restrict__ hio,
    const float* __restrict__ ei, const float* __restrict__ ej,
    const float* __restrict__ adj,
    const float* __restrict__ g, const float* __restrict__ bta,
    const float* __restrict__ mn, const float* __restrict__ vr)
{
    constexpr int KP = 136;  // bf16 pitch: 272 B, multiple of 16 B
    __shared__ __align__(16) __hip_bfloat16 s_p[128][KP];  // P, bf16, rows=i, cols=j(K)
    __shared__ __align__(16) __hip_bfloat16 s_b[32][KP];   // WhT, bf16, rows=d(N), cols=j(K)
    __shared__ float s_ei[N_NODES];
    __shared__ float s_ej[N_NODES];

    const int t = threadIdx.x;
    // XCD-grouping remap: the 4 head-blocks of one b land on one XCD (n%8 const)
    const int n_ = blockIdx.x;
    const int b = (n_ & 7) * 64 + (n_ >> 5);
    const int h = (n_ >> 3) & 3;
    const size_t whbase = (size_t)b * HROW + h * 32;

    // ---- phase 1: stage WhT slice (bf16, zero-pad K to 128) + ei/ej ----
    for (int idx = t; idx < 32 * 128; idx += 256) {
        const int d = idx & 31, j = idx >> 5;
        const float v = (j < N_NODES) ? Wh[whbase + (size_t)j * HID + d] : 0.f;
        s_b[d][j] = __float2bfloat16(v);
    }
    for (int idx = t; idx < 2 * N_NODES; idx += 256) {
        if (idx < N_NODES)
            s_ei[idx] = ei[((size_t)b * N_NODES + idx) * HEADS + h];
        else
            s_ej[idx - N_NODES] = ej[((size_t)b * N_NODES + idx - N_NODES) * HEADS + h];
    }
    __syncthreads();

    // ---- phase 2: scores + row softmax; write P rows bf16 (cols 116..127 -> 0) ----
    {
        const int w = t >> 6, l = t & 63;
        const size_t adjb = (size_t)b * ADJROW;
        const float ejl = s_ej[l];
        const float ejl2 = (l < N_NODES - 64) ? s_ej[l + 64] : 0.f;
        for (int i = w * 29; i < w * 29 + 29; ++i) {
            const float eii = s_ei[i];
            float e1 = eii + ejl;
            e1 = e1 > 0.f ? e1 : 0.2f * e1;
            const float av1 = adj[adjb + (size_t)i * N_NODES + l];
            if (av1 == 0.f) e1 = -1e30f;
            float e2 = -1e30f;
            if (l < N_NODES - 64) {
                e2 = eii + ejl2;
                e2 = e2 > 0.f ? e2 : 0.2f * e2;
                const float av2 = adj[adjb + (size_t)i * N_NODES + l + 64];
                if (av2 == 0.f) e2 = -1e30f;
            }
            float mx = fmaxf(e1, e2);
#pragma unroll
            for (int off = 32; off; off >>= 1) mx = fmaxf(mx, __shfl_xor(mx, off));
            const float x1 = expf(e1 - mx);
            const float x2 = (l < N_NODES - 64) ? expf(e2 - mx) : 0.f;
            float sm = x1 + x2;
#pragma unroll
            for (int off = 32; off; off >>= 1) sm += __shfl_xor(sm, off);
            const float rinv = 1.f / sm;
            s_p[i][l] = __float2bfloat16(x1 * rinv);
            // unconditional: zeros K-pad cols 116..127
            s_p[i][l + 64] = __float2bfloat16((l < N_NODES - 64) ? x2 * rinv : 0.f);
        }
    }
    __syncthreads();

    // ---- phase 3: MFMA aggregation — wave w owns M-tile rows [32w, 32w+32) ----
    {
        const int lane = t & 63, w = t >> 6;
        const int half = lane >> 5, nn = lane & 31;
        f32x16 acc = {};
#pragma unroll
        for (int s = 0; s < 8; ++s) {
            const int k0 = s * 16 + half * 8;
            const short8 afrag = *reinterpret_cast<const short8*>(&s_p[w * 32 + nn][k0]);
            const short8 bfrag = *reinterpret_cast<const short8*>(&s_b[nn][k0]);
            acc = __builtin_amdgcn_mfma_f32_32x32x16_bf16(afrag, bfrag, acc, 0, 0, 0);
        }
        // ---- epilogue: BN + elu + residual (f32 from global Wh) ----
        const int f = h * 32 + nn;
        const float gg = g[f], bb = bta[f], mm = mn[f];
        const float rstd = rsqrtf(vr[f] + 1e-5f);
#pragma unroll
        for (int reg = 0; reg < 16; ++reg) {
            const int row = (reg & 3) + 8 * (reg >> 2) + 4 * half;
            const int i = w * 32 + row;
            if (i < N_NODES) {
                const size_t off = ((size_t)b * N_NODES + i) * HID + f;
                float xv = elu1((acc[reg] - mm) * rstd * gg + bb);
                float outv = xv + Wh[off];
                if (ADD_H) outv += hio[off];
                hio[off] = outv;
            }
        }
    }
}

// ---------------- vn0 = vne + mean_n(h) ----------------
__global__ __launch_bounds__(128) void vn0_kernel(
    const float* __restrict__ h, const float* __restrict__ vne,
    float* __restrict__ vn)
{
    const int b = blockIdx.x, f = threadIdx.x;
    float s = 0.f;
    for (int n = 0; n < N_NODES; ++n) s += h[(size_t)b * HROW + n * HID + f];
    vn[b * HID + f] = vne[f] + s * (1.f / N_NODES);
}

// ---------------- vn_out = elu(cat([prev, mean_n(h)]) @ Wv + bv) ----------
__global__ __launch_bounds__(128) void vn_mlp_kernel(
    const float* __restrict__ prev, const float* __restrict__ h,
    const float* __restrict__ Wv, const float* __restrict__ bv,
    float* __restrict__ vout)
{
    __shared__ float cat[2 * HID];
    const int b = blockIdx.x, f = threadIdx.x;
    float s = 0.f;
    for (int n = 0; n < N_NODES; ++n) s += h[(size_t)b * HROW + n * HID + f];
    cat[f] = prev[b * HID + f];
    cat[HID + f] = s * (1.f / N_NODES);
    __syncthreads();
    float acc = bv[f];
    for (int k = 0; k < 2 * HID; ++k) acc += cat[k] * Wv[k * HID + f];
    vout[b * HID + f] = elu1(acc);
}

// ---------------- h += 0.1 * vn_new (broadcast over nodes) ----------------
__global__ __launch_bounds__(256) void add_vn_kernel(
    float* __restrict__ h, const float* __restrict__ vn)
{
    const int idx = blockIdx.x * 256 + threadIdx.x;  // over float4 elems
    float4* h4 = reinterpret_cast<float4*>(h);
    const float4* v4 = reinterpret_cast<const float4*>(vn);
    const int f4 = idx & 31;
    const int row = idx >> 5;
    const int b = row / N_NODES;
    float4 hv = h4[idx];
    const float4 vv = v4[b * 32 + f4];
    hv.x += 0.1f * vv.x; hv.y += 0.1f * vv.y;
    hv.z += 0.1f * vv.z; hv.w += 0.1f * vv.w;
    h4[idx] = hv;
}

// ---------------- pooling + net attention + flat + LayerNorm --------------
__global__ __launch_bounds__(128) void pool_flat_kernel(
    const float* __restrict__ h, const float* __restrict__ vnf,
    const float* __restrict__ pm,
    const float* __restrict__ Wa1, const float* __restrict__ ba1,
    const float* __restrict__ Wa2, const float* __restrict__ ba2,
    const float* __restrict__ ln_g, const float* __restrict__ ln_b,
    float* __restrict__ out)
{
    __shared__ float s_pm[N_NODES * 9];
    __shared__ float s_p[9][HID];
    __shared__ float s_s[9];
    __shared__ float s_red[4];
    const int b = blockIdx.x, f = threadIdx.x;
    for (int idx = f; idx < N_NODES * 9; idx += 128) s_pm[idx] = pm[idx];
    float p[9] = {};
    __syncthreads();
    for (int n = 0; n < N_NODES; ++n) {
        const float hv = h[(size_t)b * HROW + n * HID + f];
#pragma unroll
        for (int k = 0; k < 9; ++k) p[k] += s_pm[n * 9 + k] * hv;
    }
#pragma unroll
    for (int k = 0; k < 9; ++k) s_p[k][f] = p[k];
    __syncthreads();
    // scores: 4 networks per pass, 32 lanes each
    for (int pass = 0; pass < 3; ++pass) {
        const int k = pass * 4 + (f >> 5);
        if (k < 9) {
            const int j = f & 31;
            float z = ba1[j];
            for (int d = 0; d < HID; ++d) z += s_p[k][d] * Wa1[d * 32 + j];
            z = tanhf(z);
            float part = z * Wa2[j];
#pragma unroll
            for (int off = 16; off; off >>= 1) part += __shfl_xor(part, off);
            if (j == 0) s_s[k] = part + ba2[0];
        }
    }
    __syncthreads();
    // softmax over 9 networks (redundant per thread)
    float smax = -1e30f;
#pragma unroll
    for (int k = 0; k < 9; ++k) smax = fmaxf(smax, s_s[k]);
    float wgt[9], ssum = 0.f;
#pragma unroll
    for (int k = 0; k < 9; ++k) { wgt[k] = expf(s_s[k] - smax); ssum += wgt[k]; }
    const float sinv = 1.f / ssum;
    float vals[10];
#pragma unroll
    for (int k = 0; k < 9; ++k) vals[k] = p[k] * wgt[k] * sinv;
    vals[9] = vnf[b * HID + f];
    float lsum = 0.f, lsq = 0.f;
#pragma unroll
    for (int q = 0; q < 10; ++q) { lsum += vals[q]; lsq += vals[q] * vals[q]; }
#pragma unroll
    for (int off = 32; off; off >>= 1) {
        lsum += __shfl_xor(lsum, off);
        lsq += __shfl_xor(lsq, off);
    }
    const int lane = f & 63, wid = f >> 6;
    if (lane == 0) { s_red[wid * 2] = lsum; s_red[wid * 2 + 1] = lsq; }
    __syncthreads();
    const float tot = s_red[0] + s_red[2];
    const float totsq = s_red[1] + s_red[3];
    const float mean = tot * (1.f / FLAT_DIM);
    const float var = totsq * (1.f / FLAT_DIM) - mean * mean;
    const float rstd = rsqrtf(var + 1e-5f);
    float* fout = out + 1024 + (size_t)b * FLAT_DIM;
#pragma unroll
    for (int k = 0; k < 9; ++k) {
        const int j = k * HID + f;
        fout[j] = (vals[k] - mean) * rstd * ln_g[j] + ln_b[j];
    }
    const int j = 9 * HID + f;
    fout[j] = (vals[9] - mean) * rstd * ln_g[j] + ln_b[j];
}

// ---------------- classifier: logits = elu(flat@Wc1+bc1)@Wc2+bc2 ---------
__global__ __launch_bounds__(256) void cls_kernel(
    const float* __restrict__ flat,
    const float* __restrict__ Wc1, const float* __restrict__ bc1,
    const float* __restrict__ Wc2, const float* __restrict__ bc2,
    float* __restrict__ out)
{
    __shared__ float s_f[ROWS * FLAT_DIM];   // 40 KB
    __shared__ float s_hid[ROWS * 256];      // 8 KB
    const int t = threadIdx.x;
    const int row0 = blockIdx.x * ROWS;
    for (int idx = t; idx < ROWS * FLAT_DIM; idx += 256)
        s_f[idx] = flat[(size_t)row0 * FLAT_DIM + idx];
    __syncthreads();
    float acc[ROWS];
    const float bv = bc1[t];
#pragma unroll
    for (int r = 0; r < ROWS; ++r) acc[r] = bv;
    for (int k = 0; k < FLAT_DIM; ++k) {
        const float w = Wc1[k * 256 + t];
#pragma unroll
        for (int r = 0; r < ROWS; ++r) acc[r] += s_f[r * FLAT_DIM + k] * w;
    }
#pragma unroll
    for (int r = 0; r < ROWS; ++r) s_hid[r * 256 + t] = elu1(acc[r]);
    __syncthreads();
    if (t < 2 * ROWS) {
        const int r = t >> 1, c = t & 1;
        float a = bc2[c];
        for (int q = 0; q < 256; ++q) a += s_hid[r * 256 + q] * Wc2[q * 2 + c];
        out[(size_t)(row0 + r) * 2 + c] = a;
    }
}

extern "C" void kernel_launch(void* const* d_in, const int* in_sizes, int n_in,
                              void* d_out, int out_size, void* d_ws, size_t ws_size,
                              hipStream_t stream)
{
    const float* x     = (const float*)d_in[0];
    const float* adj   = (const float*)d_in[1];
    const float* W_enc = (const float*)d_in[2];
    const float* b_enc = (const float*)d_in[3];
    const float* bn_g  = (const float*)d_in[4];
    const float* bn_b  = (const float*)d_in[5];
    const float* bn_m  = (const float*)d_in[6];
    const float* bn_v  = (const float*)d_in[7];
    const float* vne   = (const float*)d_in[8];
    const float* W1    = (const float*)d_in[9];
    const float* a1    = (const float*)d_in[10];
    const float* g1    = (const float*)d_in[11];
    const float* bt1   = (const float*)d_in[12];
    const float* m1    = (const float*)d_in[13];
    const float* v1    = (const float*)d_in[14];
    const float* W2    = (const float*)d_in[15];
    const float* a2    = (const float*)d_in[16];
    const float* g2    = (const float*)d_in[17];
    const float* bt2   = (const float*)d_in[18];
    const float* m2    = (const float*)d_in[19];
    const float* v2    = (const float*)d_in[20];
    const float* Wv    = (const float*)d_in[21];
    const float* bv    = (const float*)d_in[22];
    const float* pm    = (const float*)d_in[23];
    const float* Wa1   = (const float*)d_in[24];
    const float* ba1   = (const float*)d_in[25];
    const float* Wa2   = (const float*)d_in[26];
    const float* ba2   = (const float*)d_in[27];
    const float* ln_g  = (const float*)d_in[28];
    const float* ln_b  = (const float*)d_in[29];
    const float* Wc1   = (const float*)d_in[30];
    const float* bc1   = (const float*)d_in[31];
    const float* Wc2   = (const float*)d_in[32];
    const float* bc2   = (const float*)d_in[33];
    float* out = (float*)d_out;

    float* ws = (float*)d_ws;
    float* h   = ws;                       // 7,602,176 floats
    float* Wh  = h + (size_t)BN_TOT * HID; // 7,602,176
    float* ei  = Wh + (size_t)BN_TOT * HID;          // 237,568
    float* ej  = ei + (size_t)BN_TOT * HEADS;        // 237,568
    float* vn0 = ej + (size_t)BN_TOT * HEADS;        // 65,536
    float* vnn = vn0 + BATCH * HID;
    float* vnf = vnn + BATCH * HID;

    enc_kernel<<<BN_TOT / ROWS, 128, 0, stream>>>(x, W_enc, b_enc, bn_g, bn_b,
                                                  bn_m, bn_v, h);
    vn0_kernel<<<BATCH, 128, 0, stream>>>(h, vne, vn0);
    // GAT layer 1
    wh_kernel<<<BN_TOT / ROWS, 128, 0, stream>>>(h, W1, a1, Wh, ei, ej);
    gat_aggr<false><<<BATCH * HEADS, 256, 0, stream>>>(Wh, h, ei, ej, adj, g1, bt1, m1, v1);
    // virtual node update
    vn_mlp_kernel<<<BATCH, 128, 0, stream>>>(vn0, h, Wv, bv, vnn);
    add_vn_kernel<<<(BN_TOT * HID / 4) / 256, 256, 0, stream>>>(h, vnn);
    // GAT layer 2 (+h residual)
    wh_kernel<<<BN_TOT / ROWS, 128, 0, stream>>>(h, W2, a2, Wh, ei, ej);
    gat_aggr<true><<<BATCH * HEADS, 256, 0, stream>>>(Wh, h, ei, ej, adj, g2, bt2, m2, v2);
    // final virtual node
    vn_mlp_kernel<<<BATCH, 128, 0, stream>>>(vnn, h, Wv, bv, vnf);
    // pooling + flat + LayerNorm (writes out[1024:])
    pool_flat_kernel<<<BATCH, 128, 0, stream>>>(h, vnf, pm, Wa1, ba1, Wa2, ba2,
                                                ln_g, ln_b, out);
    // classifier (reads flat from out, writes out[0:1024])
    cls_kernel<<<BATCH / ROWS, 256, 0, stream>>>(out + 1024, Wc1, bc1, Wc2, bc2, out);
}

// Round 5
// 456.165 us; speedup vs baseline: 1.9316x; 1.2287x over previous
//
#include <hip/hip_runtime.h>
#include <hip/hip_bf16.h>
#include <math.h>

#define BATCH 512
#define N_NODES 116
#define IN_DIM 123
#define HID 128
#define HEADS 4
#define FLAT_DIM 1280

static constexpr int ROWS = 8;
static constexpr int BN_TOT = BATCH * N_NODES;      // 59392
static constexpr int HROW = N_NODES * HID;          // 14848
static constexpr int ADJROW = N_NODES * N_NODES;    // 13456

typedef short short8 __attribute__((ext_vector_type(8)));
typedef float f32x16 __attribute__((ext_vector_type(16)));

__device__ __forceinline__ float elu1(float x) {
    return x > 0.f ? x : expm1f(x);
}

// ---------------- encoder: h = BN(elu(x @ W_enc + b_enc)) ----------------
__global__ __launch_bounds__(128) void enc_kernel(
    const float* __restrict__ x, const float* __restrict__ W,
    const float* __restrict__ bias,
    const float* __restrict__ g, const float* __restrict__ bta,
    const float* __restrict__ mn, const float* __restrict__ vr,
    float* __restrict__ hout)
{
    __shared__ float s_x[ROWS * IN_DIM];
    const int t = threadIdx.x;
    const int row0 = blockIdx.x * ROWS;
    for (int idx = t; idx < ROWS * IN_DIM; idx += 128)
        s_x[idx] = x[(size_t)row0 * IN_DIM + idx];
    __syncthreads();
    float acc[ROWS];
    const float bv = bias[t];
#pragma unroll
    for (int r = 0; r < ROWS; ++r) acc[r] = bv;
    for (int k = 0; k < IN_DIM; ++k) {
        const float w = W[k * HID + t];
#pragma unroll
        for (int r = 0; r < ROWS; ++r) acc[r] += s_x[r * IN_DIM + k] * w;
    }
    const float gg = g[t], bb = bta[t], mm = mn[t];
    const float rstd = rsqrtf(vr[t] + 1e-5f);
#pragma unroll
    for (int r = 0; r < ROWS; ++r) {
        float val = elu1(acc[r]);
        val = (val - mm) * rstd * gg + bb;
        hout[(size_t)(row0 + r) * HID + t] = val;
    }
}

// ---------------- Wh = h @ W, plus ei/ej GAT score halves ----------------
__global__ __launch_bounds__(128) void wh_kernel(
    const float* __restrict__ h, const float* __restrict__ W,
    const float* __restrict__ a,
    float* __restrict__ Wh, float* __restrict__ ei, float* __restrict__ ej)
{
    __shared__ float s_h[ROWS * HID];
    const int t = threadIdx.x;
    const int row0 = blockIdx.x * ROWS;
#pragma unroll
    for (int r = 0; r < ROWS; ++r)
        s_h[r * HID + t] = h[(size_t)(row0 + r) * HID + t];
    __syncthreads();
    float acc[ROWS] = {};
    for (int k = 0; k < HID; ++k) {
        const float w = W[k * HID + t];
#pragma unroll
        for (int r = 0; r < ROWS; ++r) acc[r] += s_h[r * HID + k] * w;
    }
    const int hh = t >> 5, d = t & 31;
    const float asrc = a[hh * 64 + d];
    const float adst = a[hh * 64 + 32 + d];
#pragma unroll
    for (int r = 0; r < ROWS; ++r) {
        const int row = row0 + r;
        Wh[(size_t)row * HID + t] = acc[r];
        float ps = acc[r] * asrc;
        float pd = acc[r] * adst;
#pragma unroll
        for (int off = 16; off; off >>= 1) {
            ps += __shfl_xor(ps, off);
            pd += __shfl_xor(pd, off);
        }
        if (d == 0) {
            ei[row * HEADS + hh] = ps;
            ej[row * HEADS + hh] = pd;
        }
    }
}

// ---------------- GAT attention + aggregation + BN + elu + residual ------
// one block per (batch, head); MFMA aggregation; h updated in place
template <bool ADD_H>
__global__ __launch_bounds__(256) void gat_aggr(
    const float* __restrict__ Wh, float* __restrict__ hio,
    const float* __restrict__ ei, const float* __restrict__ ej,
    const float* __restrict__ adj,
    const float* __restrict__ g, const float* __restrict__ bta,
    const float* __restrict__ mn, const float* __restrict__ vr)
{
    constexpr int KP = 136;  // bf16 pitch: 272 B, 17 dwords -> conflict-free MFMA reads
    __shared__ __align__(16) __hip_bfloat16 s_p[128][KP];  // P, bf16, rows=i, cols=j(K)
    __shared__ __align__(16) __hip_bfloat16 s_b[32][KP];   // WhT, bf16, rows=d(N), cols=j(K)
    __shared__ float s_ei[N_NODES];
    __shared__ float s_ej[N_NODES];

    const int t = threadIdx.x;
    // XCD-grouping remap: the 4 head-blocks of one b land on one XCD (n%8 const)
    const int n_ = blockIdx.x;
    const int b = (n_ & 7) * 64 + (n_ >> 5);
    const int h = (n_ >> 3) & 3;
    const size_t whbase = (size_t)b * HROW + h * 32;

    // ---- phase 1: stage WhT slice (bf16, zero-pad K to 128) + ei/ej ----
    for (int idx = t; idx < 32 * 128; idx += 256) {
        const int d = idx & 31, j = idx >> 5;
        const float v = (j < N_NODES) ? Wh[whbase + (size_t)j * HID + d] : 0.f;
        s_b[d][j] = __float2bfloat16(v);
    }
    for (int idx = t; idx < 2 * N_NODES; idx += 256) {
        if (idx < N_NODES)
            s_ei[idx] = ei[((size_t)b * N_NODES + idx) * HEADS + h];
        else
            s_ej[idx - N_NODES] = ej[((size_t)b * N_NODES + idx - N_NODES) * HEADS + h];
    }
    __syncthreads();

    // ---- phase 2: scores + row softmax (no max-sub: scores are small;
    //      masked -> exp(-1e30)=0; self-loop guarantees sm>0). adj prefetched.
    {
        const int w = t >> 6, l = t & 63;
        const size_t adjb = (size_t)b * ADJROW;
        const float ejl = s_ej[l];
        const bool up = (l < N_NODES - 64);
        const float ejl2 = up ? s_ej[l + 64] : 0.f;
        const int i0 = w * 29;
        float av1 = adj[adjb + (size_t)i0 * N_NODES + l];
        float av2 = up ? adj[adjb + (size_t)i0 * N_NODES + l + 64] : 0.f;
        for (int i = i0; i < i0 + 29; ++i) {
            float nav1 = 0.f, nav2 = 0.f;
            if (i + 1 < i0 + 29) {   // prefetch next row's adj off the chain
                nav1 = adj[adjb + (size_t)(i + 1) * N_NODES + l];
                nav2 = up ? adj[adjb + (size_t)(i + 1) * N_NODES + l + 64] : 0.f;
            }
            const float eii = s_ei[i];
            float e1 = eii + ejl;
            e1 = e1 > 0.f ? e1 : 0.2f * e1;
            float x1 = (av1 != 0.f) ? __expf(e1) : 0.f;
            float x2 = 0.f;
            if (up) {
                float e2 = eii + ejl2;
                e2 = e2 > 0.f ? e2 : 0.2f * e2;
                x2 = (av2 != 0.f) ? __expf(e2) : 0.f;
            }
            float sm = x1 + x2;
#pragma unroll
            for (int off = 32; off; off >>= 1) sm += __shfl_xor(sm, off);
            const float rinv = 1.f / sm;
            s_p[i][l] = __float2bfloat16(x1 * rinv);
            s_p[i][l + 64] = __float2bfloat16(x2 * rinv);  // zeros K-pad cols
            av1 = nav1; av2 = nav2;
        }
    }
    __syncthreads();

    // ---- phase 3: MFMA aggregation — wave w owns M-tile rows [32w, 32w+32) ----
    {
        const int lane = t & 63, w = t >> 6;
        const int half = lane >> 5, nn = lane & 31;
        f32x16 acc = {};
#pragma unroll
        for (int s = 0; s < 8; ++s) {
            const int k0 = s * 16 + half * 8;
            const short8 afrag = *reinterpret_cast<const short8*>(&s_p[w * 32 + nn][k0]);
            const short8 bfrag = *reinterpret_cast<const short8*>(&s_b[nn][k0]);
            acc = __builtin_amdgcn_mfma_f32_32x32x16_bf16(afrag, bfrag, acc, 0, 0, 0);
        }
        // ---- epilogue: BN + elu + residual (f32 from global Wh) ----
        const int f = h * 32 + nn;
        const float gg = g[f], bb = bta[f], mm = mn[f];
        const float rstd = rsqrtf(vr[f] + 1e-5f);
#pragma unroll
        for (int reg = 0; reg < 16; ++reg) {
            const int row = (reg & 3) + 8 * (reg >> 2) + 4 * half;
            const int i = w * 32 + row;
            if (i < N_NODES) {
                const size_t off = ((size_t)b * N_NODES + i) * HID + f;
                float xv = elu1((acc[reg] - mm) * rstd * gg + bb);
                float outv = xv + Wh[off];
                if (ADD_H) outv += hio[off];
                hio[off] = outv;
            }
        }
    }
}

// ---------------- vn0 = vne + mean_n(h) ----------------
__global__ __launch_bounds__(128) void vn0_kernel(
    const float* __restrict__ h, const float* __restrict__ vne,
    float* __restrict__ vn)
{
    const int b = blockIdx.x, f = threadIdx.x;
    float s = 0.f;
    for (int n = 0; n < N_NODES; ++n) s += h[(size_t)b * HROW + n * HID + f];
    vn[b * HID + f] = vne[f] + s * (1.f / N_NODES);
}

// ---------------- vn_out = elu(cat([prev, mean_n(h)]) @ Wv + bv) ----------
__global__ __launch_bounds__(128) void vn_mlp_kernel(
    const float* __restrict__ prev, const float* __restrict__ h,
    const float* __restrict__ Wv, const float* __restrict__ bv,
    float* __restrict__ vout)
{
    __shared__ float cat[2 * HID];
    const int b = blockIdx.x, f = threadIdx.x;
    float s = 0.f;
    for (int n = 0; n < N_NODES; ++n) s += h[(size_t)b * HROW + n * HID + f];
    cat[f] = prev[b * HID + f];
    cat[HID + f] = s * (1.f / N_NODES);
    __syncthreads();
    float acc = bv[f];
    for (int k = 0; k < 2 * HID; ++k) acc += cat[k] * Wv[k * HID + f];
    vout[b * HID + f] = elu1(acc);
}

// ---------------- h += 0.1 * vn_new (broadcast over nodes) ----------------
__global__ __launch_bounds__(256) void add_vn_kernel(
    float* __restrict__ h, const float* __restrict__ vn)
{
    const int idx = blockIdx.x * 256 + threadIdx.x;  // over float4 elems
    float4* h4 = reinterpret_cast<float4*>(h);
    const float4* v4 = reinterpret_cast<const float4*>(vn);
    const int f4 = idx & 31;
    const int row = idx >> 5;
    const int b = row / N_NODES;
    float4 hv = h4[idx];
    const float4 vv = v4[b * 32 + f4];
    hv.x += 0.1f * vv.x; hv.y += 0.1f * vv.y;
    hv.z += 0.1f * vv.z; hv.w += 0.1f * vv.w;
    h4[idx] = hv;
}

// ---------------- pooling + net attention + flat + LayerNorm --------------
__global__ __launch_bounds__(128) void pool_flat_kernel(
    const float* __restrict__ h, const float* __restrict__ vnf,
    const float* __restrict__ pm,
    const float* __restrict__ Wa1, const float* __restrict__ ba1,
    const float* __restrict__ Wa2, const float* __restrict__ ba2,
    const float* __restrict__ ln_g, const float* __restrict__ ln_b,
    float* __restrict__ out)
{
    __shared__ float s_pm[N_NODES * 9];
    __shared__ float s_p[9][HID];
    __shared__ float s_s[9];
    __shared__ float s_red[4];
    const int b = blockIdx.x, f = threadIdx.x;
    for (int idx = f; idx < N_NODES * 9; idx += 128) s_pm[idx] = pm[idx];
    float p[9] = {};
    __syncthreads();
    for (int n = 0; n < N_NODES; ++n) {
        const float hv = h[(size_t)b * HROW + n * HID + f];
#pragma unroll
        for (int k = 0; k < 9; ++k) p[k] += s_pm[n * 9 + k] * hv;
    }
#pragma unroll
    for (int k = 0; k < 9; ++k) s_p[k][f] = p[k];
    __syncthreads();
    // scores: 4 networks per pass, 32 lanes each
    for (int pass = 0; pass < 3; ++pass) {
        const int k = pass * 4 + (f >> 5);
        if (k < 9) {
            const int j = f & 31;
            float z = ba1[j];
            for (int d = 0; d < HID; ++d) z += s_p[k][d] * Wa1[d * 32 + j];
            z = tanhf(z);
            float part = z * Wa2[j];
#pragma unroll
            for (int off = 16; off; off >>= 1) part += __shfl_xor(part, off);
            if (j == 0) s_s[k] = part + ba2[0];
        }
    }
    __syncthreads();
    // softmax over 9 networks (redundant per thread)
    float smax = -1e30f;
#pragma unroll
    for (int k = 0; k < 9; ++k) smax = fmaxf(smax, s_s[k]);
    float wgt[9], ssum = 0.f;
#pragma unroll
    for (int k = 0; k < 9; ++k) { wgt[k] = expf(s_s[k] - smax); ssum += wgt[k]; }
    const float sinv = 1.f / ssum;
    float vals[10];
#pragma unroll
    for (int k = 0; k < 9; ++k) vals[k] = p[k] * wgt[k] * sinv;
    vals[9] = vnf[b * HID + f];
    float lsum = 0.f, lsq = 0.f;
#pragma unroll
    for (int q = 0; q < 10; ++q) { lsum += vals[q]; lsq += vals[q] * vals[q]; }
#pragma unroll
    for (int off = 32; off; off >>= 1) {
        lsum += __shfl_xor(lsum, off);
        lsq += __shfl_xor(lsq, off);
    }
    const int lane = f & 63, wid = f >> 6;
    if (lane == 0) { s_red[wid * 2] = lsum; s_red[wid * 2 + 1] = lsq; }
    __syncthreads();
    const float tot = s_red[0] + s_red[2];
    const float totsq = s_red[1] + s_red[3];
    const float mean = tot * (1.f / FLAT_DIM);
    const float var = totsq * (1.f / FLAT_DIM) - mean * mean;
    const float rstd = rsqrtf(var + 1e-5f);
    float* fout = out + 1024 + (size_t)b * FLAT_DIM;
#pragma unroll
    for (int k = 0; k < 9; ++k) {
        const int j = k * HID + f;
        fout[j] = (vals[k] - mean) * rstd * ln_g[j] + ln_b[j];
    }
    const int j = 9 * HID + f;
    fout[j] = (vals[9] - mean) * rstd * ln_g[j] + ln_b[j];
}

// ---------------- classifier: one row per block ---------------------------
__global__ __launch_bounds__(256) void cls_kernel(
    const float* __restrict__ flat,
    const float* __restrict__ Wc1, const float* __restrict__ bc1,
    const float* __restrict__ Wc2, const float* __restrict__ bc2,
    float* __restrict__ out)
{
    __shared__ float s_f[FLAT_DIM];
    __shared__ float s_hid[256];
    const int t = threadIdx.x;
    const int row = blockIdx.x;
    {
        const float4* src = reinterpret_cast<const float4*>(flat + (size_t)row * FLAT_DIM);
        float4* dst = reinterpret_cast<float4*>(s_f);
        for (int idx = t; idx < FLAT_DIM / 4; idx += 256) dst[idx] = src[idx];
    }
    __syncthreads();
    float acc = bc1[t];
#pragma unroll 8
    for (int k = 0; k < FLAT_DIM; ++k)
        acc += s_f[k] * Wc1[k * 256 + t];
    s_hid[t] = elu1(acc);
    __syncthreads();
    const int w = t >> 6, l = t & 63;
    if (w < 2) {
        float part = 0.f;
#pragma unroll
        for (int q = 0; q < 4; ++q) part += s_hid[q * 64 + l] * Wc2[(q * 64 + l) * 2 + w];
#pragma unroll
        for (int off = 32; off; off >>= 1) part += __shfl_xor(part, off);
        if (l == 0) out[(size_t)row * 2 + w] = part + bc2[w];
    }
}

extern "C" void kernel_launch(void* const* d_in, const int* in_sizes, int n_in,
                              void* d_out, int out_size, void* d_ws, size_t ws_size,
                              hipStream_t stream)
{
    const float* x     = (const float*)d_in[0];
    const float* adj   = (const float*)d_in[1];
    const float* W_enc = (const float*)d_in[2];
    const float* b_enc = (const float*)d_in[3];
    const float* bn_g  = (const float*)d_in[4];
    const float* bn_b  = (const float*)d_in[5];
    const float* bn_m  = (const float*)d_in[6];
    const float* bn_v  = (const float*)d_in[7];
    const float* vne   = (const float*)d_in[8];
    const float* W1    = (const float*)d_in[9];
    const float* a1    = (const float*)d_in[10];
    const float* g1    = (const float*)d_in[11];
    const float* bt1   = (const float*)d_in[12];
    const float* m1    = (const float*)d_in[13];
    const float* v1    = (const float*)d_in[14];
    const float* W2    = (const float*)d_in[15];
    const float* a2    = (const float*)d_in[16];
    const float* g2    = (const float*)d_in[17];
    const float* bt2   = (const float*)d_in[18];
    const float* m2    = (const float*)d_in[19];
    const float* v2    = (const float*)d_in[20];
    const float* Wv    = (const float*)d_in[21];
    const float* bv    = (const float*)d_in[22];
    const float* pm    = (const float*)d_in[23];
    const float* Wa1   = (const float*)d_in[24];
    const float* ba1   = (const float*)d_in[25];
    const float* Wa2   = (const float*)d_in[26];
    const float* ba2   = (const float*)d_in[27];
    const float* ln_g  = (const float*)d_in[28];
    const float* ln_b  = (const float*)d_in[29];
    const float* Wc1   = (const float*)d_in[30];
    const float* bc1   = (const float*)d_in[31];
    const float* Wc2   = (const float*)d_in[32];
    const float* bc2   = (const float*)d_in[33];
    float* out = (float*)d_out;

    float* ws = (float*)d_ws;
    float* h   = ws;                       // 7,602,176 floats
    float* Wh  = h + (size_t)BN_TOT * HID; // 7,602,176
    float* ei  = Wh + (size_t)BN_TOT * HID;          // 237,568
    float* ej  = ei + (size_t)BN_TOT * HEADS;        // 237,568
    float* vn0 = ej + (size_t)BN_TOT * HEADS;        // 65,536
    float* vnn = vn0 + BATCH * HID;
    float* vnf = vnn + BATCH * HID;

    enc_kernel<<<BN_TOT / ROWS, 128, 0, stream>>>(x, W_enc, b_enc, bn_g, bn_b,
                                                  bn_m, bn_v, h);
    vn0_kernel<<<BATCH, 128, 0, stream>>>(h, vne, vn0);
    // GAT layer 1
    wh_kernel<<<BN_TOT / ROWS, 128, 0, stream>>>(h, W1, a1, Wh, ei, ej);
    gat_aggr<false><<<BATCH * HEADS, 256, 0, stream>>>(Wh, h, ei, ej, adj, g1, bt1, m1, v1);
    // virtual node update
    vn_mlp_kernel<<<BATCH, 128, 0, stream>>>(vn0, h, Wv, bv, vnn);
    add_vn_kernel<<<(BN_TOT * HID / 4) / 256, 256, 0, stream>>>(h, vnn);
    // GAT layer 2 (+h residual)
    wh_kernel<<<BN_TOT / ROWS, 128, 0, stream>>>(h, W2, a2, Wh, ei, ej);
    gat_aggr<true><<<BATCH * HEADS, 256, 0, stream>>>(Wh, h, ei, ej, adj, g2, bt2, m2, v2);
    // final virtual node
    vn_mlp_kernel<<<BATCH, 128, 0, stream>>>(vnn, h, Wv, bv, vnf);
    // pooling + flat + LayerNorm (writes out[1024:])
    pool_flat_kernel<<<BATCH, 128, 0, stream>>>(h, vnf, pm, Wa1, ba1, Wa2, ba2,
                                                ln_g, ln_b, out);
    // classifier (reads flat from out, writes out[0:1024])
    cls_kernel<<<BATCH, 256, 0, stream>>>(out + 1024, Wc1, bc1, Wc2, bc2, out);
}

// Round 6
// 411.610 us; speedup vs baseline: 2.1407x; 1.1082x over previous
//
#include <hip/hip_runtime.h>
#include <hip/hip_bf16.h>
#include <math.h>

#define BATCH 512
#define N_NODES 116
#define IN_DIM 123
#define HID 128
#define HEADS 4
#define FLAT_DIM 1280

static constexpr int ROWS = 8;
static constexpr int BN_TOT = BATCH * N_NODES;      // 59392
static constexpr int HROW = N_NODES * HID;          // 14848
static constexpr int ADJROW = N_NODES * N_NODES;    // 13456

typedef short short8 __attribute__((ext_vector_type(8)));
typedef float f32x16 __attribute__((ext_vector_type(16)));

__device__ __forceinline__ float elu1(float x) {
    return x > 0.f ? x : expm1f(x);
}

// ---------------- encoder: h = BN(elu(x @ W_enc + b_enc)) ----------------
__global__ __launch_bounds__(128) void enc_kernel(
    const float* __restrict__ x, const float* __restrict__ W,
    const float* __restrict__ bias,
    const float* __restrict__ g, const float* __restrict__ bta,
    const float* __restrict__ mn, const float* __restrict__ vr,
    float* __restrict__ hout)
{
    __shared__ float s_x[ROWS * IN_DIM];
    const int t = threadIdx.x;
    const int row0 = blockIdx.x * ROWS;
    for (int idx = t; idx < ROWS * IN_DIM; idx += 128)
        s_x[idx] = x[(size_t)row0 * IN_DIM + idx];
    __syncthreads();
    float acc[ROWS];
    const float bv = bias[t];
#pragma unroll
    for (int r = 0; r < ROWS; ++r) acc[r] = bv;
    for (int k = 0; k < IN_DIM; ++k) {
        const float w = W[k * HID + t];
#pragma unroll
        for (int r = 0; r < ROWS; ++r) acc[r] += s_x[r * IN_DIM + k] * w;
    }
    const float gg = g[t], bb = bta[t], mm = mn[t];
    const float rstd = rsqrtf(vr[t] + 1e-5f);
#pragma unroll
    for (int r = 0; r < ROWS; ++r) {
        float val = elu1(acc[r]);
        val = (val - mm) * rstd * gg + bb;
        hout[(size_t)(row0 + r) * HID + t] = val;
    }
}

// ---------------- Wh = h @ W, plus ei/ej GAT score halves ----------------
// FUSE_VN: stage h + 0.1*vn[b] instead of h (eliminates add_vn pass)
template <bool FUSE_VN>
__global__ __launch_bounds__(128) void wh_kernel(
    const float* __restrict__ h, const float* __restrict__ W,
    const float* __restrict__ a, const float* __restrict__ vn,
    float* __restrict__ Wh, float* __restrict__ ei, float* __restrict__ ej)
{
    __shared__ float s_h[ROWS * HID];
    const int t = threadIdx.x;
    const int row0 = blockIdx.x * ROWS;
#pragma unroll
    for (int r = 0; r < ROWS; ++r) {
        const int row = row0 + r;
        float v = h[(size_t)row * HID + t];
        if (FUSE_VN) {
            const int b = row / N_NODES;
            v += 0.1f * vn[(size_t)b * HID + t];
        }
        s_h[r * HID + t] = v;
    }
    __syncthreads();
    float acc[ROWS] = {};
    for (int k = 0; k < HID; ++k) {
        const float w = W[k * HID + t];
#pragma unroll
        for (int r = 0; r < ROWS; ++r) acc[r] += s_h[r * HID + k] * w;
    }
    const int hh = t >> 5, d = t & 31;
    const float asrc = a[hh * 64 + d];
    const float adst = a[hh * 64 + 32 + d];
#pragma unroll
    for (int r = 0; r < ROWS; ++r) {
        const int row = row0 + r;
        Wh[(size_t)row * HID + t] = acc[r];
        float ps = acc[r] * asrc;
        float pd = acc[r] * adst;
#pragma unroll
        for (int off = 16; off; off >>= 1) {
            ps += __shfl_xor(ps, off);
            pd += __shfl_xor(pd, off);
        }
        if (d == 0) {
            ei[row * HEADS + hh] = ps;
            ej[row * HEADS + hh] = pd;
        }
    }
}

// ---------------- GAT attention + aggregation + BN + elu + residual ------
// one block per (batch, head); MFMA aggregation with rowsum-via-MFMA
// (unnormalized P in LDS; normalize in f32 epilogue). Also emits
// premean[b][f] = mean_n(h_new) for the virtual-node MLP.
template <bool ADD_H>
__global__ __launch_bounds__(256) void gat_aggr(
    const float* __restrict__ Wh, float* __restrict__ hio,
    const float* __restrict__ ei, const float* __restrict__ ej,
    const float* __restrict__ adj,
    const float* __restrict__ g, const float* __restrict__ bta,
    const float* __restrict__ mn, const float* __restrict__ vr,
    const float* __restrict__ vn, float* __restrict__ premean)
{
    constexpr int KP = 136;  // bf16 pitch: 272 B, 17 dwords -> conflict-limited MFMA reads
    __shared__ __align__(16) __hip_bfloat16 s_p[128][KP];  // P unnormalized, rows=i, cols=j(K)
    __shared__ __align__(16) __hip_bfloat16 s_b[32][KP];   // WhT, rows=d(N), cols=j(K)
    __shared__ float s_ei[N_NODES];
    __shared__ float s_ej[N_NODES];
    __shared__ float s_red[4][64];

    const int t = threadIdx.x;
    // XCD-grouping remap: the 4 head-blocks of one b land on one XCD (n%8 const)
    const int n_ = blockIdx.x;
    const int b = (n_ & 7) * 64 + (n_ >> 5);
    const int h = (n_ >> 3) & 3;
    const size_t whbase = (size_t)b * HROW + h * 32;

    // ---- phase 1: stage WhT slice (bf16, zero-pad K to 128) + ei/ej ----
    for (int idx = t; idx < 32 * 128; idx += 256) {
        const int d = idx & 31, j = idx >> 5;
        const float v = (j < N_NODES) ? Wh[whbase + (size_t)j * HID + d] : 0.f;
        s_b[d][j] = __float2bfloat16(v);
    }
    for (int idx = t; idx < 2 * N_NODES; idx += 256) {
        if (idx < N_NODES)
            s_ei[idx] = ei[((size_t)b * N_NODES + idx) * HEADS + h];
        else
            s_ej[idx - N_NODES] = ej[((size_t)b * N_NODES + idx - N_NODES) * HEADS + h];
    }
    __syncthreads();

    // ---- phase 2: UNNORMALIZED scores; independent iterations, no shuffles ----
    {
        const int w = t >> 6, l = t & 63;
        const size_t adjb = (size_t)b * ADJROW;
        const float ejl = s_ej[l];
        const bool up = (l < N_NODES - 64);
        const float ejl2 = up ? s_ej[l + 64] : 0.f;
        const int i0 = w * 29;
        for (int i = i0; i < i0 + 29; ++i) {
            const float eii = s_ei[i];
            const float av1 = adj[adjb + (size_t)i * N_NODES + l];
            float e1 = eii + ejl;
            e1 = e1 > 0.f ? e1 : 0.2f * e1;
            const float x1 = (av1 != 0.f) ? __expf(e1) : 0.f;
            float x2 = 0.f;
            if (up) {
                const float av2 = adj[adjb + (size_t)i * N_NODES + l + 64];
                float e2 = eii + ejl2;
                e2 = e2 > 0.f ? e2 : 0.2f * e2;
                x2 = (av2 != 0.f) ? __expf(e2) : 0.f;
            }
            s_p[i][l] = __float2bfloat16(x1);
            s_p[i][l + 64] = __float2bfloat16(x2);  // zeros K-pad cols
        }
    }
    __syncthreads();

    // ---- phase 3: MFMA — O = P_u @ WhT and rowsum = P_u @ ones ----
    {
        const int lane = t & 63, w = t >> 6;
        const int half = lane >> 5, nn = lane & 31;
        f32x16 acc = {};
        f32x16 accs = {};
        short8 ones;
#pragma unroll
        for (int e = 0; e < 8; ++e) ones[e] = (short)0x3F80;  // bf16 1.0
#pragma unroll
        for (int s = 0; s < 8; ++s) {
            const int k0 = s * 16 + half * 8;
            const short8 afrag = *reinterpret_cast<const short8*>(&s_p[w * 32 + nn][k0]);
            const short8 bfrag = *reinterpret_cast<const short8*>(&s_b[nn][k0]);
            acc = __builtin_amdgcn_mfma_f32_32x32x16_bf16(afrag, bfrag, acc, 0, 0, 0);
            accs = __builtin_amdgcn_mfma_f32_32x32x16_bf16(afrag, ones, accs, 0, 0, 0);
        }
        // ---- epilogue: normalize + BN + elu + residual (+hio +0.1vn) ----
        const int f = h * 32 + nn;
        const float gg = g[f], bb = bta[f], mm = mn[f];
        const float rstd = rsqrtf(vr[f] + 1e-5f);
        const float vadd = ADD_H ? 0.1f * vn[(size_t)b * HID + f] : 0.f;
        float psum = 0.f;
#pragma unroll
        for (int reg = 0; reg < 16; ++reg) {
            const int row = (reg & 3) + 8 * (reg >> 2) + 4 * half;
            const int i = w * 32 + row;
            if (i < N_NODES) {
                const size_t off = ((size_t)b * N_NODES + i) * HID + f;
                const float aval = acc[reg] / accs[reg];
                float xv = elu1((aval - mm) * rstd * gg + bb);
                float outv = xv + Wh[off];
                if (ADD_H) outv += hio[off] + vadd;
                hio[off] = outv;
                psum += outv;
            }
        }
        s_red[w][lane] = psum;
    }
    __syncthreads();
    // premean over nodes for this block's 32 features
    if (t < 32) {
        float s = 0.f;
#pragma unroll
        for (int w2 = 0; w2 < 4; ++w2) s += s_red[w2][t] + s_red[w2][t + 32];
        premean[(size_t)b * HID + h * 32 + t] = s * (1.f / N_NODES);
    }
}

// ---------------- vn0 = vne + mean_n(h) ----------------
__global__ __launch_bounds__(128) void vn0_kernel(
    const float* __restrict__ h, const float* __restrict__ vne,
    float* __restrict__ vn)
{
    const int b = blockIdx.x, f = threadIdx.x;
    float s = 0.f;
    for (int n = 0; n < N_NODES; ++n) s += h[(size_t)b * HROW + n * HID + f];
    vn[b * HID + f] = vne[f] + s * (1.f / N_NODES);
}

// ---------------- vn_out = elu(cat([prev, premean]) @ Wv + bv) ------------
__global__ __launch_bounds__(128) void vn_mlp_kernel(
    const float* __restrict__ prev, const float* __restrict__ premean,
    const float* __restrict__ Wv, const float* __restrict__ bv,
    float* __restrict__ vout)
{
    __shared__ float cat[2 * HID];
    const int b = blockIdx.x, f = threadIdx.x;
    cat[f] = prev[b * HID + f];
    cat[HID + f] = premean[b * HID + f];
    __syncthreads();
    float acc = bv[f];
    for (int k = 0; k < 2 * HID; ++k) acc += cat[k] * Wv[k * HID + f];
    vout[b * HID + f] = elu1(acc);
}

// ---------------- pooling + net attention + flat + LayerNorm --------------
__global__ __launch_bounds__(128) void pool_flat_kernel(
    const float* __restrict__ h, const float* __restrict__ vnf,
    const float* __restrict__ pm,
    const float* __restrict__ Wa1, const float* __restrict__ ba1,
    const float* __restrict__ Wa2, const float* __restrict__ ba2,
    const float* __restrict__ ln_g, const float* __restrict__ ln_b,
    float* __restrict__ out)
{
    __shared__ float s_pm[N_NODES * 9];
    __shared__ float s_p[9][HID];
    __shared__ float s_s[9];
    __shared__ float s_red[4];
    const int b = blockIdx.x, f = threadIdx.x;
    for (int idx = f; idx < N_NODES * 9; idx += 128) s_pm[idx] = pm[idx];
    float p[9] = {};
    __syncthreads();
    for (int n = 0; n < N_NODES; ++n) {
        const float hv = h[(size_t)b * HROW + n * HID + f];
#pragma unroll
        for (int k = 0; k < 9; ++k) p[k] += s_pm[n * 9 + k] * hv;
    }
#pragma unroll
    for (int k = 0; k < 9; ++k) s_p[k][f] = p[k];
    __syncthreads();
    // scores: 4 networks per pass, 32 lanes each
    for (int pass = 0; pass < 3; ++pass) {
        const int k = pass * 4 + (f >> 5);
        if (k < 9) {
            const int j = f & 31;
            float z = ba1[j];
            for (int d = 0; d < HID; ++d) z += s_p[k][d] * Wa1[d * 32 + j];
            z = tanhf(z);
            float part = z * Wa2[j];
#pragma unroll
            for (int off = 16; off; off >>= 1) part += __shfl_xor(part, off);
            if (j == 0) s_s[k] = part + ba2[0];
        }
    }
    __syncthreads();
    // softmax over 9 networks (redundant per thread)
    float smax = -1e30f;
#pragma unroll
    for (int k = 0; k < 9; ++k) smax = fmaxf(smax, s_s[k]);
    float wgt[9], ssum = 0.f;
#pragma unroll
    for (int k = 0; k < 9; ++k) { wgt[k] = expf(s_s[k] - smax); ssum += wgt[k]; }
    const float sinv = 1.f / ssum;
    float vals[10];
#pragma unroll
    for (int k = 0; k < 9; ++k) vals[k] = p[k] * wgt[k] * sinv;
    vals[9] = vnf[b * HID + f];
    float lsum = 0.f, lsq = 0.f;
#pragma unroll
    for (int q = 0; q < 10; ++q) { lsum += vals[q]; lsq += vals[q] * vals[q]; }
#pragma unroll
    for (int off = 32; off; off >>= 1) {
        lsum += __shfl_xor(lsum, off);
        lsq += __shfl_xor(lsq, off);
    }
    const int lane = f & 63, wid = f >> 6;
    if (lane == 0) { s_red[wid * 2] = lsum; s_red[wid * 2 + 1] = lsq; }
    __syncthreads();
    const float tot = s_red[0] + s_red[2];
    const float totsq = s_red[1] + s_red[3];
    const float mean = tot * (1.f / FLAT_DIM);
    const float var = totsq * (1.f / FLAT_DIM) - mean * mean;
    const float rstd = rsqrtf(var + 1e-5f);
    float* fout = out + 1024 + (size_t)b * FLAT_DIM;
#pragma unroll
    for (int k = 0; k < 9; ++k) {
        const int j = k * HID + f;
        fout[j] = (vals[k] - mean) * rstd * ln_g[j] + ln_b[j];
    }
    const int j = 9 * HID + f;
    fout[j] = (vals[9] - mean) * rstd * ln_g[j] + ln_b[j];
}

// ---------------- classifier: one row per block ---------------------------
__global__ __launch_bounds__(256) void cls_kernel(
    const float* __restrict__ flat,
    const float* __restrict__ Wc1, const float* __restrict__ bc1,
    const float* __restrict__ Wc2, const float* __restrict__ bc2,
    float* __restrict__ out)
{
    __shared__ float s_f[FLAT_DIM];
    __shared__ float s_hid[256];
    const int t = threadIdx.x;
    const int row = blockIdx.x;
    {
        const float4* src = reinterpret_cast<const float4*>(flat + (size_t)row * FLAT_DIM);
        float4* dst = reinterpret_cast<float4*>(s_f);
        for (int idx = t; idx < FLAT_DIM / 4; idx += 256) dst[idx] = src[idx];
    }
    __syncthreads();
    float acc = bc1[t];
#pragma unroll 8
    for (int k = 0; k < FLAT_DIM; ++k)
        acc += s_f[k] * Wc1[k * 256 + t];
    s_hid[t] = elu1(acc);
    __syncthreads();
    const int w = t >> 6, l = t & 63;
    if (w < 2) {
        float part = 0.f;
#pragma unroll
        for (int q = 0; q < 4; ++q) part += s_hid[q * 64 + l] * Wc2[(q * 64 + l) * 2 + w];
#pragma unroll
        for (int off = 32; off; off >>= 1) part += __shfl_xor(part, off);
        if (l == 0) out[(size_t)row * 2 + w] = part + bc2[w];
    }
}

extern "C" void kernel_launch(void* const* d_in, const int* in_sizes, int n_in,
                              void* d_out, int out_size, void* d_ws, size_t ws_size,
                              hipStream_t stream)
{
    const float* x     = (const float*)d_in[0];
    const float* adj   = (const float*)d_in[1];
    const float* W_enc = (const float*)d_in[2];
    const float* b_enc = (const float*)d_in[3];
    const float* bn_g  = (const float*)d_in[4];
    const float* bn_b  = (const float*)d_in[5];
    const float* bn_m  = (const float*)d_in[6];
    const float* bn_v  = (const float*)d_in[7];
    const float* vne   = (const float*)d_in[8];
    const float* W1    = (const float*)d_in[9];
    const float* a1    = (const float*)d_in[10];
    const float* g1    = (const float*)d_in[11];
    const float* bt1   = (const float*)d_in[12];
    const float* m1    = (const float*)d_in[13];
    const float* v1    = (const float*)d_in[14];
    const float* W2    = (const float*)d_in[15];
    const float* a2    = (const float*)d_in[16];
    const float* g2    = (const float*)d_in[17];
    const float* bt2   = (const float*)d_in[18];
    const float* m2    = (const float*)d_in[19];
    const float* v2    = (const float*)d_in[20];
    const float* Wv    = (const float*)d_in[21];
    const float* bv    = (const float*)d_in[22];
    const float* pm    = (const float*)d_in[23];
    const float* Wa1   = (const float*)d_in[24];
    const float* ba1   = (const float*)d_in[25];
    const float* Wa2   = (const float*)d_in[26];
    const float* ba2   = (const float*)d_in[27];
    const float* ln_g  = (const float*)d_in[28];
    const float* ln_b  = (const float*)d_in[29];
    const float* Wc1   = (const float*)d_in[30];
    const float* bc1   = (const float*)d_in[31];
    const float* Wc2   = (const float*)d_in[32];
    const float* bc2   = (const float*)d_in[33];
    float* out = (float*)d_out;

    float* ws = (float*)d_ws;
    float* h   = ws;                                  // 7,602,176 floats
    float* Wh  = h + (size_t)BN_TOT * HID;            // 7,602,176
    float* ei  = Wh + (size_t)BN_TOT * HID;           // 237,568
    float* ej  = ei + (size_t)BN_TOT * HEADS;         // 237,568
    float* vn0 = ej + (size_t)BN_TOT * HEADS;         // 65,536
    float* vnn = vn0 + BATCH * HID;
    float* vnf = vnn + BATCH * HID;
    float* pm1 = vnf + BATCH * HID;                   // premean after layer 1
    float* pm2 = pm1 + BATCH * HID;                   // premean after layer 2

    enc_kernel<<<BN_TOT / ROWS, 128, 0, stream>>>(x, W_enc, b_enc, bn_g, bn_b,
                                                  bn_m, bn_v, h);
    vn0_kernel<<<BATCH, 128, 0, stream>>>(h, vne, vn0);
    // GAT layer 1
    wh_kernel<false><<<BN_TOT / ROWS, 128, 0, stream>>>(h, W1, a1, nullptr, Wh, ei, ej);
    gat_aggr<false><<<BATCH * HEADS, 256, 0, stream>>>(Wh, h, ei, ej, adj, g1, bt1,
                                                       m1, v1, nullptr, pm1);
    // virtual node update (reads premean; no h rescan)
    vn_mlp_kernel<<<BATCH, 128, 0, stream>>>(vn0, pm1, Wv, bv, vnn);
    // GAT layer 2 (+h residual, +0.1*vnn fused into staging and epilogue)
    wh_kernel<true><<<BN_TOT / ROWS, 128, 0, stream>>>(h, W2, a2, vnn, Wh, ei, ej);
    gat_aggr<true><<<BATCH * HEADS, 256, 0, stream>>>(Wh, h, ei, ej, adj, g2, bt2,
                                                      m2, v2, vnn, pm2);
    // final virtual node
    vn_mlp_kernel<<<BATCH, 128, 0, stream>>>(vnn, pm2, Wv, bv, vnf);
    // pooling + flat + LayerNorm (writes out[1024:])
    pool_flat_kernel<<<BATCH, 128, 0, stream>>>(h, vnf, pm, Wa1, ba1, Wa2, ba2,
                                                ln_g, ln_b, out);
    // classifier (reads flat from out, writes out[0:1024])
    cls_kernel<<<BATCH, 256, 0, stream>>>(out + 1024, Wc1, bc1, Wc2, bc2, out);
}

// Round 7
// 341.146 us; speedup vs baseline: 2.5829x; 1.2066x over previous
//
#include <hip/hip_runtime.h>
#include <hip/hip_bf16.h>
#include <math.h>

#define BATCH 512
#define N_NODES 116
#define IN_DIM 123
#define HID 128
#define HEADS 4
#define FLAT_DIM 1280

static constexpr int ROWS = 8;
static constexpr int BN_TOT = BATCH * N_NODES;      // 59392
static constexpr int HROW = N_NODES * HID;          // 14848
static constexpr int ADJROW = N_NODES * N_NODES;    // 13456

typedef short short8 __attribute__((ext_vector_type(8)));
typedef float f32x16 __attribute__((ext_vector_type(16)));

__device__ __forceinline__ float elu1(float x) {
    return x > 0.f ? x : expm1f(x);
}
__device__ __forceinline__ short bfb(float x) {
    __hip_bfloat16 b = __float2bfloat16(x);
    return *reinterpret_cast<short*>(&b);
}

// ---------------- encoder: h = BN(elu(x @ W_enc + b_enc)) ----------------
__global__ __launch_bounds__(128) void enc_kernel(
    const float* __restrict__ x, const float* __restrict__ W,
    const float* __restrict__ bias,
    const float* __restrict__ g, const float* __restrict__ bta,
    const float* __restrict__ mn, const float* __restrict__ vr,
    float* __restrict__ hout)
{
    __shared__ float s_x[ROWS * IN_DIM];
    const int t = threadIdx.x;
    const int row0 = blockIdx.x * ROWS;
    for (int idx = t; idx < ROWS * IN_DIM; idx += 128)
        s_x[idx] = x[(size_t)row0 * IN_DIM + idx];
    __syncthreads();
    float acc[ROWS];
    const float bv = bias[t];
#pragma unroll
    for (int r = 0; r < ROWS; ++r) acc[r] = bv;
    for (int k = 0; k < IN_DIM; ++k) {
        const float w = W[k * HID + t];
#pragma unroll
        for (int r = 0; r < ROWS; ++r) acc[r] += s_x[r * IN_DIM + k] * w;
    }
    const float gg = g[t], bb = bta[t], mm = mn[t];
    const float rstd = rsqrtf(vr[t] + 1e-5f);
#pragma unroll
    for (int r = 0; r < ROWS; ++r) {
        float val = elu1(acc[r]);
        val = (val - mm) * rstd * gg + bb;
        hout[(size_t)(row0 + r) * HID + t] = val;
    }
}

// ---------------- wei/wej: fold attention vector a into W -----------------
// wei[h*128+k] = sum_d W[k, h*32+d] * a[h, d];  wej with a[h, 32+d]
__global__ __launch_bounds__(256) void wei_kernel(
    const float* __restrict__ W, const float* __restrict__ a,
    float* __restrict__ wei, float* __restrict__ wej)
{
    const int idx = blockIdx.x * 256 + threadIdx.x;   // 0..511
    const int h = idx >> 7, k = idx & 127;
    float se = 0.f, sj = 0.f;
#pragma unroll 8
    for (int d = 0; d < 32; ++d) {
        const float wv = W[k * HID + h * 32 + d];
        se += wv * a[h * 64 + d];
        sj += wv * a[h * 64 + 32 + d];
    }
    wei[idx] = se;
    wej[idx] = sj;
}

// ---------------- fused GAT layer: Wh-slice GEMM + scores + softmax +
//                  aggregation + BN + elu + residual + premean -------------
// one block per (batch, head). Reads hin, writes hout (ping-pong).
template <bool ADD_H>
__global__ __launch_bounds__(256) void gat_fused(
    const float* __restrict__ hin, float* __restrict__ hout,
    const float* __restrict__ W,
    const float* __restrict__ wei, const float* __restrict__ wej,
    const float* __restrict__ adj,
    const float* __restrict__ g, const float* __restrict__ bta,
    const float* __restrict__ mn, const float* __restrict__ vr,
    const float* __restrict__ vn, float* __restrict__ premean)
{
    constexpr int KP = 136;  // bf16 pitch for P (272 B rows, 16B-aligned)
    __shared__ __align__(16) __hip_bfloat16 s_p[128][KP];   // 34816 B
    __shared__ float s_whs[128][32];                        // 16384 B (pitch 32: all patterns conflict-free)
    __shared__ float s_ei[128];
    __shared__ float s_ej[128];
    __shared__ float s_red[4][64];                          // total 53248 B -> 3 blocks/CU

    const int t = threadIdx.x;
    // XCD-grouping remap: 4 head-blocks of one b stay on one XCD
    const int n_ = blockIdx.x;
    const int b = (n_ & 7) * 64 + (n_ >> 5);
    const int h = (n_ >> 3) & 3;

    const int lane = t & 63, w = t >> 6;
    const int half = lane >> 5, nn = lane & 31;

    // ---- phase 1: Whs = hg @ W[:, 32h:32h+32] via MFMA; ei/ej in f32 ----
    {
        const int row = w * 32 + nn;   // node index 0..127 (116..127 = dead rows)
        const float* hrow = hin + ((size_t)b * N_NODES + row) * HID;
        f32x16 wacc = {};
        float eip = 0.f, ejp = 0.f;
#pragma unroll
        for (int s = 0; s < 8; ++s) {
            const int k0 = s * 16 + half * 8;
            float av[8];
            *reinterpret_cast<float4*>(&av[0]) = *reinterpret_cast<const float4*>(&hrow[k0]);
            *reinterpret_cast<float4*>(&av[4]) = *reinterpret_cast<const float4*>(&hrow[k0 + 4]);
            if (ADD_H) {
                float4 v0 = *reinterpret_cast<const float4*>(&vn[(size_t)b * HID + k0]);
                float4 v1 = *reinterpret_cast<const float4*>(&vn[(size_t)b * HID + k0 + 4]);
                av[0] += 0.1f * v0.x; av[1] += 0.1f * v0.y;
                av[2] += 0.1f * v0.z; av[3] += 0.1f * v0.w;
                av[4] += 0.1f * v1.x; av[5] += 0.1f * v1.y;
                av[6] += 0.1f * v1.z; av[7] += 0.1f * v1.w;
            }
            short8 afrag, bfrag;
#pragma unroll
            for (int e = 0; e < 8; ++e) {
                afrag[e] = bfb(av[e]);
                bfrag[e] = bfb(W[(k0 + e) * HID + h * 32 + nn]);
                eip += av[e] * wei[h * 128 + k0 + e];
                ejp += av[e] * wej[h * 128 + k0 + e];
            }
            wacc = __builtin_amdgcn_mfma_f32_32x32x16_bf16(afrag, bfrag, wacc, 0, 0, 0);
        }
        eip += __shfl_xor(eip, 32);
        ejp += __shfl_xor(ejp, 32);
        if (half == 0) { s_ei[row] = eip; s_ej[row] = ejp; }
        // scatter Whs tile to LDS (C layout: col=nn, row=(reg&3)+8*(reg>>2)+4*half)
#pragma unroll
        for (int reg = 0; reg < 16; ++reg) {
            const int r = (reg & 3) + 8 * (reg >> 2) + 4 * half;
            s_whs[w * 32 + r][nn] = wacc[reg];
        }
    }
    // zero K-pad rows 116..127 of s_whs (B-side of aggregation MFMA)
    for (int idx = t; idx < 12 * 32; idx += 256)
        s_whs[116 + (idx >> 5)][idx & 31] = 0.f;
    __syncthreads();

    // ---- phase 2: unnormalized exp scores (no shuffles, no max-sub) ----
    {
        const int l = lane;
        const size_t adjb = (size_t)b * ADJROW;
        const float ejl = s_ej[l];
        const bool up = (l < N_NODES - 64);
        const float ejl2 = up ? s_ej[l + 64] : 0.f;
        const int i0 = w * 29;
        for (int i = i0; i < i0 + 29; ++i) {
            const float eii = s_ei[i];
            const float av1 = adj[adjb + (size_t)i * N_NODES + l];
            float e1 = eii + ejl;
            e1 = e1 > 0.f ? e1 : 0.2f * e1;
            const float x1 = (av1 != 0.f) ? __expf(e1) : 0.f;
            float x2 = 0.f;
            if (up) {
                const float av2 = adj[adjb + (size_t)i * N_NODES + l + 64];
                float e2 = eii + ejl2;
                e2 = e2 > 0.f ? e2 : 0.2f * e2;
                x2 = (av2 != 0.f) ? __expf(e2) : 0.f;
            }
            s_p[i][l] = __float2bfloat16(x1);
            s_p[i][l + 64] = __float2bfloat16(x2);  // also zeros K-pad cols
        }
    }
    __syncthreads();

    // ---- phase 3: MFMA — O = P_u @ WhsT and rowsum = P_u @ ones ----
    {
        f32x16 acc = {};
        f32x16 accs = {};
        short8 ones;
#pragma unroll
        for (int e = 0; e < 8; ++e) ones[e] = (short)0x3F80;  // bf16 1.0
#pragma unroll
        for (int s = 0; s < 8; ++s) {
            const int k0 = s * 16 + half * 8;
            const short8 afrag = *reinterpret_cast<const short8*>(&s_p[w * 32 + nn][k0]);
            short8 bfrag;
#pragma unroll
            for (int e = 0; e < 8; ++e) bfrag[e] = bfb(s_whs[k0 + e][nn]);
            acc = __builtin_amdgcn_mfma_f32_32x32x16_bf16(afrag, bfrag, acc, 0, 0, 0);
            accs = __builtin_amdgcn_mfma_f32_32x32x16_bf16(afrag, ones, accs, 0, 0, 0);
        }
        // ---- epilogue: normalize + BN + elu + residual ----
        const int f = h * 32 + nn;
        const float gg = g[f], bb = bta[f], mm = mn[f];
        const float rstd = rsqrtf(vr[f] + 1e-5f);
        const float vadd = ADD_H ? 0.1f * vn[(size_t)b * HID + f] : 0.f;
        float psum = 0.f;
#pragma unroll
        for (int reg = 0; reg < 16; ++reg) {
            const int row = (reg & 3) + 8 * (reg >> 2) + 4 * half;
            const int i = w * 32 + row;
            if (i < N_NODES) {
                const size_t off = ((size_t)b * N_NODES + i) * HID + f;
                const float aval = acc[reg] / accs[reg];
                float xv = elu1((aval - mm) * rstd * gg + bb);
                float outv = xv + s_whs[i][nn];
                if (ADD_H) outv += hin[off] + vadd;
                hout[off] = outv;
                psum += outv;
            }
        }
        s_red[w][lane] = psum;
    }
    __syncthreads();
    // premean over nodes for this block's 32 features
    if (t < 32) {
        float s = 0.f;
#pragma unroll
        for (int w2 = 0; w2 < 4; ++w2) s += s_red[w2][t] + s_red[w2][t + 32];
        premean[(size_t)b * HID + h * 32 + t] = s * (1.f / N_NODES);
    }
}

// ---------------- vn0 = vne + mean_n(h) ----------------
__global__ __launch_bounds__(128) void vn0_kernel(
    const float* __restrict__ h, const float* __restrict__ vne,
    float* __restrict__ vn)
{
    const int b = blockIdx.x, f = threadIdx.x;
    float s = 0.f;
    for (int n = 0; n < N_NODES; ++n) s += h[(size_t)b * HROW + n * HID + f];
    vn[b * HID + f] = vne[f] + s * (1.f / N_NODES);
}

// ---------------- vn_out = elu(cat([prev, premean]) @ Wv + bv) ------------
__global__ __launch_bounds__(128) void vn_mlp_kernel(
    const float* __restrict__ prev, const float* __restrict__ premean,
    const float* __restrict__ Wv, const float* __restrict__ bv,
    float* __restrict__ vout)
{
    __shared__ float cat[2 * HID];
    const int b = blockIdx.x, f = threadIdx.x;
    cat[f] = prev[b * HID + f];
    cat[HID + f] = premean[b * HID + f];
    __syncthreads();
    float acc = bv[f];
    for (int k = 0; k < 2 * HID; ++k) acc += cat[k] * Wv[k * HID + f];
    vout[b * HID + f] = elu1(acc);
}

// ---------------- pooling + net attention + flat + LayerNorm --------------
__global__ __launch_bounds__(128) void pool_flat_kernel(
    const float* __restrict__ h, const float* __restrict__ vnf,
    const float* __restrict__ pm,
    const float* __restrict__ Wa1, const float* __restrict__ ba1,
    const float* __restrict__ Wa2, const float* __restrict__ ba2,
    const float* __restrict__ ln_g, const float* __restrict__ ln_b,
    float* __restrict__ out)
{
    __shared__ float s_pm[N_NODES * 9];
    __shared__ float s_p[9][HID];
    __shared__ float s_s[9];
    __shared__ float s_red[4];
    const int b = blockIdx.x, f = threadIdx.x;
    for (int idx = f; idx < N_NODES * 9; idx += 128) s_pm[idx] = pm[idx];
    float p[9] = {};
    __syncthreads();
    for (int n = 0; n < N_NODES; ++n) {
        const float hv = h[(size_t)b * HROW + n * HID + f];
#pragma unroll
        for (int k = 0; k < 9; ++k) p[k] += s_pm[n * 9 + k] * hv;
    }
#pragma unroll
    for (int k = 0; k < 9; ++k) s_p[k][f] = p[k];
    __syncthreads();
    for (int pass = 0; pass < 3; ++pass) {
        const int k = pass * 4 + (f >> 5);
        if (k < 9) {
            const int j = f & 31;
            float z = ba1[j];
            for (int d = 0; d < HID; ++d) z += s_p[k][d] * Wa1[d * 32 + j];
            z = tanhf(z);
            float part = z * Wa2[j];
#pragma unroll
            for (int off = 16; off; off >>= 1) part += __shfl_xor(part, off);
            if (j == 0) s_s[k] = part + ba2[0];
        }
    }
    __syncthreads();
    float smax = -1e30f;
#pragma unroll
    for (int k = 0; k < 9; ++k) smax = fmaxf(smax, s_s[k]);
    float wgt[9], ssum = 0.f;
#pragma unroll
    for (int k = 0; k < 9; ++k) { wgt[k] = expf(s_s[k] - smax); ssum += wgt[k]; }
    const float sinv = 1.f / ssum;
    float vals[10];
#pragma unroll
    for (int k = 0; k < 9; ++k) vals[k] = p[k] * wgt[k] * sinv;
    vals[9] = vnf[b * HID + f];
    float lsum = 0.f, lsq = 0.f;
#pragma unroll
    for (int q = 0; q < 10; ++q) { lsum += vals[q]; lsq += vals[q] * vals[q]; }
#pragma unroll
    for (int off = 32; off; off >>= 1) {
        lsum += __shfl_xor(lsum, off);
        lsq += __shfl_xor(lsq, off);
    }
    const int lane = f & 63, wid = f >> 6;
    if (lane == 0) { s_red[wid * 2] = lsum; s_red[wid * 2 + 1] = lsq; }
    __syncthreads();
    const float tot = s_red[0] + s_red[2];
    const float totsq = s_red[1] + s_red[3];
    const float mean = tot * (1.f / FLAT_DIM);
    const float var = totsq * (1.f / FLAT_DIM) - mean * mean;
    const float rstd = rsqrtf(var + 1e-5f);
    float* fout = out + 1024 + (size_t)b * FLAT_DIM;
#pragma unroll
    for (int k = 0; k < 9; ++k) {
        const int j = k * HID + f;
        fout[j] = (vals[k] - mean) * rstd * ln_g[j] + ln_b[j];
    }
    const int j = 9 * HID + f;
    fout[j] = (vals[9] - mean) * rstd * ln_g[j] + ln_b[j];
}

// ---------------- classifier: one row per block ---------------------------
__global__ __launch_bounds__(256) void cls_kernel(
    const float* __restrict__ flat,
    const float* __restrict__ Wc1, const float* __restrict__ bc1,
    const float* __restrict__ Wc2, const float* __restrict__ bc2,
    float* __restrict__ out)
{
    __shared__ float s_f[FLAT_DIM];
    __shared__ float s_hid[256];
    const int t = threadIdx.x;
    const int row = blockIdx.x;
    {
        const float4* src = reinterpret_cast<const float4*>(flat + (size_t)row * FLAT_DIM);
        float4* dst = reinterpret_cast<float4*>(s_f);
        for (int idx = t; idx < FLAT_DIM / 4; idx += 256) dst[idx] = src[idx];
    }
    __syncthreads();
    float acc = bc1[t];
#pragma unroll 8
    for (int k = 0; k < FLAT_DIM; ++k)
        acc += s_f[k] * Wc1[k * 256 + t];
    s_hid[t] = elu1(acc);
    __syncthreads();
    const int w = t >> 6, l = t & 63;
    if (w < 2) {
        float part = 0.f;
#pragma unroll
        for (int q = 0; q < 4; ++q) part += s_hid[q * 64 + l] * Wc2[(q * 64 + l) * 2 + w];
#pragma unroll
        for (int off = 32; off; off >>= 1) part += __shfl_xor(part, off);
        if (l == 0) out[(size_t)row * 2 + w] = part + bc2[w];
    }
}

extern "C" void kernel_launch(void* const* d_in, const int* in_sizes, int n_in,
                              void* d_out, int out_size, void* d_ws, size_t ws_size,
                              hipStream_t stream)
{
    const float* x     = (const float*)d_in[0];
    const float* adj   = (const float*)d_in[1];
    const float* W_enc = (const float*)d_in[2];
    const float* b_enc = (const float*)d_in[3];
    const float* bn_g  = (const float*)d_in[4];
    const float* bn_b  = (const float*)d_in[5];
    const float* bn_m  = (const float*)d_in[6];
    const float* bn_v  = (const float*)d_in[7];
    const float* vne   = (const float*)d_in[8];
    const float* W1    = (const float*)d_in[9];
    const float* a1    = (const float*)d_in[10];
    const float* g1    = (const float*)d_in[11];
    const float* bt1   = (const float*)d_in[12];
    const float* m1    = (const float*)d_in[13];
    const float* v1    = (const float*)d_in[14];
    const float* W2    = (const float*)d_in[15];
    const float* a2    = (const float*)d_in[16];
    const float* g2    = (const float*)d_in[17];
    const float* bt2   = (const float*)d_in[18];
    const float* m2    = (const float*)d_in[19];
    const float* v2    = (const float*)d_in[20];
    const float* Wv    = (const float*)d_in[21];
    const float* bv    = (const float*)d_in[22];
    const float* pm    = (const float*)d_in[23];
    const float* Wa1   = (const float*)d_in[24];
    const float* ba1   = (const float*)d_in[25];
    const float* Wa2   = (const float*)d_in[26];
    const float* ba2   = (const float*)d_in[27];
    const float* ln_g  = (const float*)d_in[28];
    const float* ln_b  = (const float*)d_in[29];
    const float* Wc1   = (const float*)d_in[30];
    const float* bc1   = (const float*)d_in[31];
    const float* Wc2   = (const float*)d_in[32];
    const float* bc2   = (const float*)d_in[33];
    float* out = (float*)d_out;

    float* ws = (float*)d_ws;
    float* hA   = ws;                                 // 7,602,176 floats
    float* hB   = hA + (size_t)BN_TOT * HID;          // 7,602,176
    float* vn0  = hB + (size_t)BN_TOT * HID;          // 65,536
    float* vnn  = vn0 + BATCH * HID;
    float* vnf  = vnn + BATCH * HID;
    float* pms1 = vnf + BATCH * HID;                  // premean after layer 1
    float* pms2 = pms1 + BATCH * HID;                 // premean after layer 2
    float* wei1 = pms2 + BATCH * HID;                 // 512 each
    float* wej1 = wei1 + 512;
    float* wei2 = wej1 + 512;
    float* wej2 = wei2 + 512;

    // fold a into W for f32 ei/ej (independent of enc)
    wei_kernel<<<2, 256, 0, stream>>>(W1, a1, wei1, wej1);
    wei_kernel<<<2, 256, 0, stream>>>(W2, a2, wei2, wej2);

    enc_kernel<<<BN_TOT / ROWS, 128, 0, stream>>>(x, W_enc, b_enc, bn_g, bn_b,
                                                  bn_m, bn_v, hA);
    vn0_kernel<<<BATCH, 128, 0, stream>>>(hA, vne, vn0);
    // GAT layer 1 (fused Wh GEMM): hA -> hB
    gat_fused<false><<<BATCH * HEADS, 256, 0, stream>>>(
        hA, hB, W1, wei1, wej1, adj, g1, bt1, m1, v1, nullptr, pms1);
    vn_mlp_kernel<<<BATCH, 128, 0, stream>>>(vn0, pms1, Wv, bv, vnn);
    // GAT layer 2 (+h residual, +0.1*vnn fused): hB -> hA
    gat_fused<true><<<BATCH * HEADS, 256, 0, stream>>>(
        hB, hA, W2, wei2, wej2, adj, g2, bt2, m2, v2, vnn, pms2);
    vn_mlp_kernel<<<BATCH, 128, 0, stream>>>(vnn, pms2, Wv, bv, vnf);
    // pooling + flat + LayerNorm (writes out[1024:])
    pool_flat_kernel<<<BATCH, 128, 0, stream>>>(hA, vnf, pm, Wa1, ba1, Wa2, ba2,
                                                ln_g, ln_b, out);
    // classifier (reads flat from out, writes out[0:1024])
    cls_kernel<<<BATCH, 256, 0, stream>>>(out + 1024, Wc1, bc1, Wc2, bc2, out);
}

// Round 8
// 290.260 us; speedup vs baseline: 3.0357x; 1.1753x over previous
//
#include <hip/hip_runtime.h>
#include <hip/hip_bf16.h>
#include <math.h>

#define BATCH 512
#define N_NODES 116
#define IN_DIM 123
#define HID 128
#define HEADS 4
#define FLAT_DIM 1280

static constexpr int ROWS = 8;
static constexpr int BN_TOT = BATCH * N_NODES;      // 59392
static constexpr int HROW = N_NODES * HID;          // 14848
static constexpr int ADJROW = N_NODES * N_NODES;    // 13456

typedef short short8 __attribute__((ext_vector_type(8)));
typedef float f32x16 __attribute__((ext_vector_type(16)));

__device__ __forceinline__ float elu1(float x) {
    return x > 0.f ? x : expm1f(x);
}
__device__ __forceinline__ short bfb(float x) {
    __hip_bfloat16 b = __float2bfloat16(x);
    return *reinterpret_cast<short*>(&b);
}

// ---------------- encoder: h = BN(elu(x @ W_enc + b_enc)) ----------------
__global__ __launch_bounds__(128) void enc_kernel(
    const float* __restrict__ x, const float* __restrict__ W,
    const float* __restrict__ bias,
    const float* __restrict__ g, const float* __restrict__ bta,
    const float* __restrict__ mn, const float* __restrict__ vr,
    float* __restrict__ hout)
{
    __shared__ float s_x[ROWS * IN_DIM];
    const int t = threadIdx.x;
    const int row0 = blockIdx.x * ROWS;
    for (int idx = t; idx < ROWS * IN_DIM; idx += 128)
        s_x[idx] = x[(size_t)row0 * IN_DIM + idx];
    __syncthreads();
    float acc[ROWS];
    const float bv = bias[t];
#pragma unroll
    for (int r = 0; r < ROWS; ++r) acc[r] = bv;
    for (int k = 0; k < IN_DIM; ++k) {
        const float w = W[k * HID + t];
#pragma unroll
        for (int r = 0; r < ROWS; ++r) acc[r] += s_x[r * IN_DIM + k] * w;
    }
    const float gg = g[t], bb = bta[t], mm = mn[t];
    const float rstd = rsqrtf(vr[t] + 1e-5f);
#pragma unroll
    for (int r = 0; r < ROWS; ++r) {
        float val = elu1(acc[r]);
        val = (val - mm) * rstd * gg + bb;
        hout[(size_t)(row0 + r) * HID + t] = val;
    }
}

// ---------------- weight prep: Wt bf16 [h][nn][k] + Weij bf16 -------------
// Wt[idx] = W[k][32h+nn];  Weij col0 = wei[h][k], col1 = wej[h][k], rest 0
__global__ __launch_bounds__(256) void wprep_kernel(
    const float* __restrict__ W, const float* __restrict__ a,
    short* __restrict__ Wt, short* __restrict__ Weij)
{
    const int idx = blockIdx.x * 256 + threadIdx.x;  // 0..16383
    const int h = idx >> 12, nn = (idx >> 7) & 31, k = idx & 127;
    Wt[idx] = bfb(W[k * HID + h * 32 + nn]);
    short wv = 0;
    if (nn < 2) {
        const float* ap = a + h * 64 + nn * 32;
        float s = 0.f;
#pragma unroll 8
        for (int d = 0; d < 32; ++d) s += W[k * HID + h * 32 + d] * ap[d];
        wv = bfb(s);
    }
    Weij[idx] = wv;
}

// ---------------- adj bit-pack: one wave per (b,i) row --------------------
__global__ __launch_bounds__(256) void adjpack_kernel(
    const float* __restrict__ adj, unsigned int* __restrict__ adjp)
{
    const int row = blockIdx.x * 4 + (threadIdx.x >> 6);  // b*116+i
    const int l = threadIdx.x & 63;
    const float a1 = adj[(size_t)row * N_NODES + l];
    const float a2 = (l < N_NODES - 64) ? adj[(size_t)row * N_NODES + 64 + l] : 0.f;
    const unsigned long long m1 = __ballot(a1 != 0.f);
    const unsigned long long m2 = __ballot(a2 != 0.f);
    if (l == 0) {
        uint4 v;
        v.x = (unsigned int)m1; v.y = (unsigned int)(m1 >> 32);
        v.z = (unsigned int)m2; v.w = (unsigned int)(m2 >> 32);
        *reinterpret_cast<uint4*>(&adjp[(size_t)row * 4]) = v;
    }
}

// ---------------- fused GAT layer (MFMA Wh + MFMA ei/ej + softmax +
//                  MFMA aggregation + BN + elu + residual + premean) -------
// one block per (batch, head). Reads hin, writes hout (ping-pong).
template <bool ADD_H>
__global__ __launch_bounds__(256) void gat_fused(
    const float* __restrict__ hin, float* __restrict__ hout,
    const short* __restrict__ Wt, const short* __restrict__ Weij,
    const unsigned int* __restrict__ adjp,
    const float* __restrict__ g, const float* __restrict__ bta,
    const float* __restrict__ mn, const float* __restrict__ vr,
    const float* __restrict__ vn, float* __restrict__ premean)
{
    constexpr int KP = 136;  // bf16 pitch for P (272 B rows, 16B-aligned)
    __shared__ __align__(16) __hip_bfloat16 s_p[128][KP];   // 34816 B
    __shared__ float s_whs[128][32];                        // 16384 B
    __shared__ float s_ei[128];
    __shared__ float s_ej[128];
    __shared__ float s_red[4][64];                          // total 53248 B -> 3 blocks/CU

    const int t = threadIdx.x;
    // XCD-grouping remap: 4 head-blocks of one b stay on one XCD
    const int n_ = blockIdx.x;
    const int b = (n_ & 7) * 64 + (n_ >> 5);
    const int h = (n_ >> 3) & 3;

    const int lane = t & 63, w = t >> 6;
    const int half = lane >> 5, nn = lane & 31;

    // ---- phase 1: Whs = hg @ W-slice and [ei|ej] = hg @ Weij, both MFMA ----
    {
        const int row = w * 32 + nn;   // node 0..127 (116..127 dead)
        const int hr = (row < N_NODES) ? row : 0;
        const float* hrow = hin + ((size_t)b * N_NODES + hr) * HID;
        const short8* wtp = reinterpret_cast<const short8*>(Wt + ((h * 32 + nn) << 7));
        const short8* wep = reinterpret_cast<const short8*>(Weij + ((h * 32 + nn) << 7));
        f32x16 wacc = {};
        f32x16 eacc = {};
#pragma unroll
        for (int s = 0; s < 8; ++s) {
            const int k0 = s * 16 + half * 8;
            float av[8];
            *reinterpret_cast<float4*>(&av[0]) = *reinterpret_cast<const float4*>(&hrow[k0]);
            *reinterpret_cast<float4*>(&av[4]) = *reinterpret_cast<const float4*>(&hrow[k0 + 4]);
            if (ADD_H) {
                float4 v0 = *reinterpret_cast<const float4*>(&vn[(size_t)b * HID + k0]);
                float4 v1 = *reinterpret_cast<const float4*>(&vn[(size_t)b * HID + k0 + 4]);
                av[0] += 0.1f * v0.x; av[1] += 0.1f * v0.y;
                av[2] += 0.1f * v0.z; av[3] += 0.1f * v0.w;
                av[4] += 0.1f * v1.x; av[5] += 0.1f * v1.y;
                av[6] += 0.1f * v1.z; av[7] += 0.1f * v1.w;
            }
            short8 afrag;
#pragma unroll
            for (int e = 0; e < 8; ++e) afrag[e] = bfb(av[e]);
            const int fi = s * 2 + half;
            wacc = __builtin_amdgcn_mfma_f32_32x32x16_bf16(afrag, wtp[fi], wacc, 0, 0, 0);
            eacc = __builtin_amdgcn_mfma_f32_32x32x16_bf16(afrag, wep[fi], eacc, 0, 0, 0);
        }
        // scatter Whs tile (C: col=nn, row=(reg&3)+8*(reg>>2)+4*half)
#pragma unroll
        for (int reg = 0; reg < 16; ++reg) {
            const int r = (reg & 3) + 8 * (reg >> 2) + 4 * half;
            s_whs[w * 32 + r][nn] = wacc[reg];
        }
        if (nn == 0) {
#pragma unroll
            for (int reg = 0; reg < 16; ++reg) {
                const int r = (reg & 3) + 8 * (reg >> 2) + 4 * half;
                s_ei[w * 32 + r] = eacc[reg];
            }
        }
        if (nn == 1) {
#pragma unroll
            for (int reg = 0; reg < 16; ++reg) {
                const int r = (reg & 3) + 8 * (reg >> 2) + 4 * half;
                s_ej[w * 32 + r] = eacc[reg];
            }
        }
    }
    // zero K-pad rows 116..127 of s_whs (B side of aggregation MFMA)
    for (int idx = t; idx < 12 * 32; idx += 256)
        s_whs[116 + (idx >> 5)][idx & 31] = 0.f;
    __syncthreads();

    // ---- phase 2: unnormalized exp scores from packed adj (broadcast loads) ----
    {
        const int l = lane;
        const float ejl = s_ej[l];
        const bool up = (l < N_NODES - 64);
        const float ejl2 = up ? s_ej[l + 64] : 0.f;
        const int i0 = w * 29;
        const uint4* ap = reinterpret_cast<const uint4*>(
            adjp + ((size_t)b * N_NODES + i0) * 4);
        uint4 aw = ap[0];
        for (int ii = 0; ii < 29; ++ii) {
            uint4 nw = aw;
            if (ii + 1 < 29) nw = ap[ii + 1];   // prefetch off the chain
            const int i = i0 + ii;
            const float eii = s_ei[i];
            const unsigned int w1 = (l & 32) ? aw.y : aw.x;
            const unsigned int w2 = (l & 32) ? aw.w : aw.z;
            const bool bit1 = (w1 >> (l & 31)) & 1;
            const bool bit2 = (w2 >> (l & 31)) & 1;
            float e1 = eii + ejl;
            e1 = e1 > 0.f ? e1 : 0.2f * e1;
            const float x1 = bit1 ? __expf(e1) : 0.f;
            float x2 = 0.f;
            if (up) {
                float e2 = eii + ejl2;
                e2 = e2 > 0.f ? e2 : 0.2f * e2;
                x2 = bit2 ? __expf(e2) : 0.f;
            }
            s_p[i][l] = __float2bfloat16(x1);
            s_p[i][l + 64] = __float2bfloat16(x2);  // also zeros K-pad cols
            aw = nw;
        }
    }
    __syncthreads();

    // ---- phase 3: MFMA — O = P_u @ WhsT and rowsum = P_u @ ones ----
    {
        f32x16 acc = {};
        f32x16 accs = {};
        short8 ones;
#pragma unroll
        for (int e = 0; e < 8; ++e) ones[e] = (short)0x3F80;  // bf16 1.0
#pragma unroll
        for (int s = 0; s < 8; ++s) {
            const int k0 = s * 16 + half * 8;
            const short8 afrag = *reinterpret_cast<const short8*>(&s_p[w * 32 + nn][k0]);
            short8 bfrag;
#pragma unroll
            for (int e = 0; e < 8; ++e) bfrag[e] = bfb(s_whs[k0 + e][nn]);
            acc = __builtin_amdgcn_mfma_f32_32x32x16_bf16(afrag, bfrag, acc, 0, 0, 0);
            accs = __builtin_amdgcn_mfma_f32_32x32x16_bf16(afrag, ones, accs, 0, 0, 0);
        }
        // ---- epilogue: normalize + BN + elu + residual ----
        const int f = h * 32 + nn;
        const float gg = g[f], bb = bta[f], mm = mn[f];
        const float rstd = rsqrtf(vr[f] + 1e-5f);
        const float vadd = ADD_H ? 0.1f * vn[(size_t)b * HID + f] : 0.f;
        float psum = 0.f;
#pragma unroll
        for (int reg = 0; reg < 16; ++reg) {
            const int row = (reg & 3) + 8 * (reg >> 2) + 4 * half;
            const int i = w * 32 + row;
            if (i < N_NODES) {
                const size_t off = ((size_t)b * N_NODES + i) * HID + f;
                const float aval = acc[reg] / accs[reg];
                float xv = elu1((aval - mm) * rstd * gg + bb);
                float outv = xv + s_whs[i][nn];
                if (ADD_H) outv += hin[off] + vadd;
                hout[off] = outv;
                psum += outv;
            }
        }
        s_red[w][lane] = psum;
    }
    __syncthreads();
    // premean over nodes for this block's 32 features
    if (t < 32) {
        float s = 0.f;
#pragma unroll
        for (int w2 = 0; w2 < 4; ++w2) s += s_red[w2][t] + s_red[w2][t + 32];
        premean[(size_t)b * HID + h * 32 + t] = s * (1.f / N_NODES);
    }
}

// ---------------- vn0 = vne + mean_n(h) ----------------
__global__ __launch_bounds__(128) void vn0_kernel(
    const float* __restrict__ h, const float* __restrict__ vne,
    float* __restrict__ vn)
{
    const int b = blockIdx.x, f = threadIdx.x;
    float s = 0.f;
    for (int n = 0; n < N_NODES; ++n) s += h[(size_t)b * HROW + n * HID + f];
    vn[b * HID + f] = vne[f] + s * (1.f / N_NODES);
}

// ---------------- vn_out = elu(cat([prev, premean]) @ Wv + bv) ------------
__global__ __launch_bounds__(128) void vn_mlp_kernel(
    const float* __restrict__ prev, const float* __restrict__ premean,
    const float* __restrict__ Wv, const float* __restrict__ bv,
    float* __restrict__ vout)
{
    __shared__ float cat[2 * HID];
    const int b = blockIdx.x, f = threadIdx.x;
    cat[f] = prev[b * HID + f];
    cat[HID + f] = premean[b * HID + f];
    __syncthreads();
    float acc = bv[f];
    for (int k = 0; k < 2 * HID; ++k) acc += cat[k] * Wv[k * HID + f];
    vout[b * HID + f] = elu1(acc);
}

// ---------------- pooling + net attention + flat + LayerNorm --------------
__global__ __launch_bounds__(128) void pool_flat_kernel(
    const float* __restrict__ h, const float* __restrict__ vnf,
    const float* __restrict__ pm,
    const float* __restrict__ Wa1, const float* __restrict__ ba1,
    const float* __restrict__ Wa2, const float* __restrict__ ba2,
    const float* __restrict__ ln_g, const float* __restrict__ ln_b,
    float* __restrict__ out)
{
    __shared__ float s_pm[N_NODES * 9];
    __shared__ float s_p[9][HID];
    __shared__ float s_s[9];
    __shared__ float s_red[4];
    const int b = blockIdx.x, f = threadIdx.x;
    for (int idx = f; idx < N_NODES * 9; idx += 128) s_pm[idx] = pm[idx];
    float p[9] = {};
    __syncthreads();
    for (int n = 0; n < N_NODES; ++n) {
        const float hv = h[(size_t)b * HROW + n * HID + f];
#pragma unroll
        for (int k = 0; k < 9; ++k) p[k] += s_pm[n * 9 + k] * hv;
    }
#pragma unroll
    for (int k = 0; k < 9; ++k) s_p[k][f] = p[k];
    __syncthreads();
    for (int pass = 0; pass < 3; ++pass) {
        const int k = pass * 4 + (f >> 5);
        if (k < 9) {
            const int j = f & 31;
            float z = ba1[j];
            for (int d = 0; d < HID; ++d) z += s_p[k][d] * Wa1[d * 32 + j];
            z = tanhf(z);
            float part = z * Wa2[j];
#pragma unroll
            for (int off = 16; off; off >>= 1) part += __shfl_xor(part, off);
            if (j == 0) s_s[k] = part + ba2[0];
        }
    }
    __syncthreads();
    float smax = -1e30f;
#pragma unroll
    for (int k = 0; k < 9; ++k) smax = fmaxf(smax, s_s[k]);
    float wgt[9], ssum = 0.f;
#pragma unroll
    for (int k = 0; k < 9; ++k) { wgt[k] = expf(s_s[k] - smax); ssum += wgt[k]; }
    const float sinv = 1.f / ssum;
    float vals[10];
#pragma unroll
    for (int k = 0; k < 9; ++k) vals[k] = p[k] * wgt[k] * sinv;
    vals[9] = vnf[b * HID + f];
    float lsum = 0.f, lsq = 0.f;
#pragma unroll
    for (int q = 0; q < 10; ++q) { lsum += vals[q]; lsq += vals[q] * vals[q]; }
#pragma unroll
    for (int off = 32; off; off >>= 1) {
        lsum += __shfl_xor(lsum, off);
        lsq += __shfl_xor(lsq, off);
    }
    const int lane = f & 63, wid = f >> 6;
    if (lane == 0) { s_red[wid * 2] = lsum; s_red[wid * 2 + 1] = lsq; }
    __syncthreads();
    const float tot = s_red[0] + s_red[2];
    const float totsq = s_red[1] + s_red[3];
    const float mean = tot * (1.f / FLAT_DIM);
    const float var = totsq * (1.f / FLAT_DIM) - mean * mean;
    const float rstd = rsqrtf(var + 1e-5f);
    float* fout = out + 1024 + (size_t)b * FLAT_DIM;
#pragma unroll
    for (int k = 0; k < 9; ++k) {
        const int j = k * HID + f;
        fout[j] = (vals[k] - mean) * rstd * ln_g[j] + ln_b[j];
    }
    const int j = 9 * HID + f;
    fout[j] = (vals[9] - mean) * rstd * ln_g[j] + ln_b[j];
}

// ---------------- classifier: one row per block ---------------------------
__global__ __launch_bounds__(256) void cls_kernel(
    const float* __restrict__ flat,
    const float* __restrict__ Wc1, const float* __restrict__ bc1,
    const float* __restrict__ Wc2, const float* __restrict__ bc2,
    float* __restrict__ out)
{
    __shared__ float s_f[FLAT_DIM];
    __shared__ float s_hid[256];
    const int t = threadIdx.x;
    const int row = blockIdx.x;
    {
        const float4* src = reinterpret_cast<const float4*>(flat + (size_t)row * FLAT_DIM);
        float4* dst = reinterpret_cast<float4*>(s_f);
        for (int idx = t; idx < FLAT_DIM / 4; idx += 256) dst[idx] = src[idx];
    }
    __syncthreads();
    float acc = bc1[t];
#pragma unroll 8
    for (int k = 0; k < FLAT_DIM; ++k)
        acc += s_f[k] * Wc1[k * 256 + t];
    s_hid[t] = elu1(acc);
    __syncthreads();
    const int w = t >> 6, l = t & 63;
    if (w < 2) {
        float part = 0.f;
#pragma unroll
        for (int q = 0; q < 4; ++q) part += s_hid[q * 64 + l] * Wc2[(q * 64 + l) * 2 + w];
#pragma unroll
        for (int off = 32; off; off >>= 1) part += __shfl_xor(part, off);
        if (l == 0) out[(size_t)row * 2 + w] = part + bc2[w];
    }
}

extern "C" void kernel_launch(void* const* d_in, const int* in_sizes, int n_in,
                              void* d_out, int out_size, void* d_ws, size_t ws_size,
                              hipStream_t stream)
{
    const float* x     = (const float*)d_in[0];
    const float* adj   = (const float*)d_in[1];
    const float* W_enc = (const float*)d_in[2];
    const float* b_enc = (const float*)d_in[3];
    const float* bn_g  = (const float*)d_in[4];
    const float* bn_b  = (const float*)d_in[5];
    const float* bn_m  = (const float*)d_in[6];
    const float* bn_v  = (const float*)d_in[7];
    const float* vne   = (const float*)d_in[8];
    const float* W1    = (const float*)d_in[9];
    const float* a1    = (const float*)d_in[10];
    const float* g1    = (const float*)d_in[11];
    const float* bt1   = (const float*)d_in[12];
    const float* m1    = (const float*)d_in[13];
    const float* v1    = (const float*)d_in[14];
    const float* W2    = (const float*)d_in[15];
    const float* a2    = (const float*)d_in[16];
    const float* g2    = (const float*)d_in[17];
    const float* bt2   = (const float*)d_in[18];
    const float* m2    = (const float*)d_in[19];
    const float* v2    = (const float*)d_in[20];
    const float* Wv    = (const float*)d_in[21];
    const float* bv    = (const float*)d_in[22];
    const float* pm    = (const float*)d_in[23];
    const float* Wa1   = (const float*)d_in[24];
    const float* ba1   = (const float*)d_in[25];
    const float* Wa2   = (const float*)d_in[26];
    const float* ba2   = (const float*)d_in[27];
    const float* ln_g  = (const float*)d_in[28];
    const float* ln_b  = (const float*)d_in[29];
    const float* Wc1   = (const float*)d_in[30];
    const float* bc1   = (const float*)d_in[31];
    const float* Wc2   = (const float*)d_in[32];
    const float* bc2   = (const float*)d_in[33];
    float* out = (float*)d_out;

    float* ws = (float*)d_ws;
    float* hA   = ws;                                 // 7,602,176 floats
    float* hB   = hA + (size_t)BN_TOT * HID;          // 7,602,176
    float* vn0  = hB + (size_t)BN_TOT * HID;          // 65,536 each below
    float* vnn  = vn0 + BATCH * HID;
    float* vnf  = vnn + BATCH * HID;
    float* pms1 = vnf + BATCH * HID;
    float* pms2 = pms1 + BATCH * HID;
    unsigned int* adjp = (unsigned int*)(pms2 + BATCH * HID);  // 237,568 uints
    short* Wt1  = (short*)(adjp + (size_t)BN_TOT * 4);         // 16384 shorts each
    short* We1  = Wt1 + 16384;
    short* Wt2  = We1 + 16384;
    short* We2  = Wt2 + 16384;

    // prep: bf16 weights + folded attention vectors + packed adjacency
    wprep_kernel<<<64, 256, 0, stream>>>(W1, a1, Wt1, We1);
    wprep_kernel<<<64, 256, 0, stream>>>(W2, a2, Wt2, We2);
    adjpack_kernel<<<BN_TOT / 4, 256, 0, stream>>>(adj, adjp);

    enc_kernel<<<BN_TOT / ROWS, 128, 0, stream>>>(x, W_enc, b_enc, bn_g, bn_b,
                                                  bn_m, bn_v, hA);
    vn0_kernel<<<BATCH, 128, 0, stream>>>(hA, vne, vn0);
    // GAT layer 1: hA -> hB
    gat_fused<false><<<BATCH * HEADS, 256, 0, stream>>>(
        hA, hB, Wt1, We1, adjp, g1, bt1, m1, v1, nullptr, pms1);
    vn_mlp_kernel<<<BATCH, 128, 0, stream>>>(vn0, pms1, Wv, bv, vnn);
    // GAT layer 2 (+h residual, +0.1*vnn fused): hB -> hA
    gat_fused<true><<<BATCH * HEADS, 256, 0, stream>>>(
        hB, hA, Wt2, We2, adjp, g2, bt2, m2, v2, vnn, pms2);
    vn_mlp_kernel<<<BATCH, 128, 0, stream>>>(vnn, pms2, Wv, bv, vnf);
    // pooling + flat + LayerNorm (writes out[1024:])
    pool_flat_kernel<<<BATCH, 128, 0, stream>>>(hA, vnf, pm, Wa1, ba1, Wa2, ba2,
                                                ln_g, ln_b, out);
    // classifier (reads flat from out, writes out[0:1024])
    cls_kernel<<<BATCH, 256, 0, stream>>>(out + 1024, Wc1, bc1, Wc2, bc2, out);
}

// Round 9
// 276.918 us; speedup vs baseline: 3.1819x; 1.0482x over previous
//
#include <hip/hip_runtime.h>
#include <hip/hip_bf16.h>
#include <math.h>

#define BATCH 512
#define N_NODES 116
#define IN_DIM 123
#define HID 128
#define HEADS 4
#define FLAT_DIM 1280

static constexpr int ROWS = 8;
static constexpr int BN_TOT = BATCH * N_NODES;      // 59392
static constexpr int HROW = N_NODES * HID;          // 14848
static constexpr int ADJROW = N_NODES * N_NODES;    // 13456

typedef short short8 __attribute__((ext_vector_type(8)));
typedef float f32x16 __attribute__((ext_vector_type(16)));

__device__ __forceinline__ float elu1(float x) {
    return x > 0.f ? x : expm1f(x);
}
__device__ __forceinline__ short bfb(float x) {
    __hip_bfloat16 b = __float2bfloat16(x);
    return *reinterpret_cast<short*>(&b);
}

// ---------------- encoder: h = BN(elu(x @ W_enc + b_enc)) ----------------
__global__ __launch_bounds__(128) void enc_kernel(
    const float* __restrict__ x, const float* __restrict__ W,
    const float* __restrict__ bias,
    const float* __restrict__ g, const float* __restrict__ bta,
    const float* __restrict__ mn, const float* __restrict__ vr,
    float* __restrict__ hout)
{
    __shared__ float s_x[ROWS * IN_DIM];
    const int t = threadIdx.x;
    const int row0 = blockIdx.x * ROWS;
    for (int idx = t; idx < ROWS * IN_DIM; idx += 128)
        s_x[idx] = x[(size_t)row0 * IN_DIM + idx];
    __syncthreads();
    float acc[ROWS];
    const float bv = bias[t];
#pragma unroll
    for (int r = 0; r < ROWS; ++r) acc[r] = bv;
    for (int k = 0; k < IN_DIM; ++k) {
        const float w = W[k * HID + t];
#pragma unroll
        for (int r = 0; r < ROWS; ++r) acc[r] += s_x[r * IN_DIM + k] * w;
    }
    const float gg = g[t], bb = bta[t], mm = mn[t];
    const float rstd = rsqrtf(vr[t] + 1e-5f);
#pragma unroll
    for (int r = 0; r < ROWS; ++r) {
        float val = elu1(acc[r]);
        val = (val - mm) * rstd * gg + bb;
        hout[(size_t)(row0 + r) * HID + t] = val;
    }
}

// ---------------- weight prep: Wt bf16 [h][nn][k] + Weij bf16 -------------
__global__ __launch_bounds__(256) void wprep_kernel(
    const float* __restrict__ W, const float* __restrict__ a,
    short* __restrict__ Wt, short* __restrict__ Weij)
{
    const int idx = blockIdx.x * 256 + threadIdx.x;  // 0..16383
    const int h = idx >> 12, nn = (idx >> 7) & 31, k = idx & 127;
    Wt[idx] = bfb(W[k * HID + h * 32 + nn]);
    short wv = 0;
    if (nn < 2) {
        const float* ap = a + h * 64 + nn * 32;
        float s = 0.f;
#pragma unroll 8
        for (int d = 0; d < 32; ++d) s += W[k * HID + h * 32 + d] * ap[d];
        wv = bfb(s);
    }
    Weij[idx] = wv;
}

// ---------------- classifier weight prep: wc1t bf16 [n][k] ----------------
__global__ __launch_bounds__(256) void wc1prep_kernel(
    const float* __restrict__ Wc1, short* __restrict__ wc1t)
{
    const int idx = blockIdx.x * 256 + threadIdx.x;  // n fastest
    const int k = idx >> 8, n = idx & 255;
    wc1t[(size_t)n * FLAT_DIM + k] = bfb(Wc1[(size_t)k * 256 + n]);
}

// ---------------- adj bit-pack: one wave per (b,i) row --------------------
__global__ __launch_bounds__(256) void adjpack_kernel(
    const float* __restrict__ adj, unsigned int* __restrict__ adjp)
{
    const int row = blockIdx.x * 4 + (threadIdx.x >> 6);  // b*116+i
    const int l = threadIdx.x & 63;
    const float a1 = adj[(size_t)row * N_NODES + l];
    const float a2 = (l < N_NODES - 64) ? adj[(size_t)row * N_NODES + 64 + l] : 0.f;
    const unsigned long long m1 = __ballot(a1 != 0.f);
    const unsigned long long m2 = __ballot(a2 != 0.f);
    if (l == 0) {
        uint4 v;
        v.x = (unsigned int)m1; v.y = (unsigned int)(m1 >> 32);
        v.z = (unsigned int)m2; v.w = (unsigned int)(m2 >> 32);
        *reinterpret_cast<uint4*>(&adjp[(size_t)row * 4]) = v;
    }
}

// ---------------- fused GAT layer (unchanged from round 8) ---------------
template <bool ADD_H>
__global__ __launch_bounds__(256) void gat_fused(
    const float* __restrict__ hin, float* __restrict__ hout,
    const short* __restrict__ Wt, const short* __restrict__ Weij,
    const unsigned int* __restrict__ adjp,
    const float* __restrict__ g, const float* __restrict__ bta,
    const float* __restrict__ mn, const float* __restrict__ vr,
    const float* __restrict__ vn, float* __restrict__ premean)
{
    constexpr int KP = 136;
    __shared__ __align__(16) __hip_bfloat16 s_p[128][KP];   // 34816 B
    __shared__ float s_whs[128][32];                        // 16384 B
    __shared__ float s_ei[128];
    __shared__ float s_ej[128];
    __shared__ float s_red[4][64];                          // 53248 B -> 3 blocks/CU

    const int t = threadIdx.x;
    const int n_ = blockIdx.x;
    const int b = (n_ & 7) * 64 + (n_ >> 5);
    const int h = (n_ >> 3) & 3;

    const int lane = t & 63, w = t >> 6;
    const int half = lane >> 5, nn = lane & 31;

    // ---- phase 1: Whs = hg @ W-slice and [ei|ej] = hg @ Weij, both MFMA ----
    {
        const int row = w * 32 + nn;
        const int hr = (row < N_NODES) ? row : 0;
        const float* hrow = hin + ((size_t)b * N_NODES + hr) * HID;
        const short8* wtp = reinterpret_cast<const short8*>(Wt + ((h * 32 + nn) << 7));
        const short8* wep = reinterpret_cast<const short8*>(Weij + ((h * 32 + nn) << 7));
        f32x16 wacc = {};
        f32x16 eacc = {};
#pragma unroll
        for (int s = 0; s < 8; ++s) {
            const int k0 = s * 16 + half * 8;
            float av[8];
            *reinterpret_cast<float4*>(&av[0]) = *reinterpret_cast<const float4*>(&hrow[k0]);
            *reinterpret_cast<float4*>(&av[4]) = *reinterpret_cast<const float4*>(&hrow[k0 + 4]);
            if (ADD_H) {
                float4 v0 = *reinterpret_cast<const float4*>(&vn[(size_t)b * HID + k0]);
                float4 v1 = *reinterpret_cast<const float4*>(&vn[(size_t)b * HID + k0 + 4]);
                av[0] += 0.1f * v0.x; av[1] += 0.1f * v0.y;
                av[2] += 0.1f * v0.z; av[3] += 0.1f * v0.w;
                av[4] += 0.1f * v1.x; av[5] += 0.1f * v1.y;
                av[6] += 0.1f * v1.z; av[7] += 0.1f * v1.w;
            }
            short8 afrag;
#pragma unroll
            for (int e = 0; e < 8; ++e) afrag[e] = bfb(av[e]);
            const int fi = s * 2 + half;
            wacc = __builtin_amdgcn_mfma_f32_32x32x16_bf16(afrag, wtp[fi], wacc, 0, 0, 0);
            eacc = __builtin_amdgcn_mfma_f32_32x32x16_bf16(afrag, wep[fi], eacc, 0, 0, 0);
        }
#pragma unroll
        for (int reg = 0; reg < 16; ++reg) {
            const int r = (reg & 3) + 8 * (reg >> 2) + 4 * half;
            s_whs[w * 32 + r][nn] = wacc[reg];
        }
        if (nn == 0) {
#pragma unroll
            for (int reg = 0; reg < 16; ++reg) {
                const int r = (reg & 3) + 8 * (reg >> 2) + 4 * half;
                s_ei[w * 32 + r] = eacc[reg];
            }
        }
        if (nn == 1) {
#pragma unroll
            for (int reg = 0; reg < 16; ++reg) {
                const int r = (reg & 3) + 8 * (reg >> 2) + 4 * half;
                s_ej[w * 32 + r] = eacc[reg];
            }
        }
    }
    for (int idx = t; idx < 12 * 32; idx += 256)
        s_whs[116 + (idx >> 5)][idx & 31] = 0.f;
    __syncthreads();

    // ---- phase 2: unnormalized exp scores from packed adj ----
    {
        const int l = lane;
        const float ejl = s_ej[l];
        const bool up = (l < N_NODES - 64);
        const float ejl2 = up ? s_ej[l + 64] : 0.f;
        const int i0 = w * 29;
        const uint4* ap = reinterpret_cast<const uint4*>(
            adjp + ((size_t)b * N_NODES + i0) * 4);
        uint4 aw = ap[0];
        for (int ii = 0; ii < 29; ++ii) {
            uint4 nw = aw;
            if (ii + 1 < 29) nw = ap[ii + 1];
            const int i = i0 + ii;
            const float eii = s_ei[i];
            const unsigned int w1 = (l & 32) ? aw.y : aw.x;
            const unsigned int w2 = (l & 32) ? aw.w : aw.z;
            const bool bit1 = (w1 >> (l & 31)) & 1;
            const bool bit2 = (w2 >> (l & 31)) & 1;
            float e1 = eii + ejl;
            e1 = e1 > 0.f ? e1 : 0.2f * e1;
            const float x1 = bit1 ? __expf(e1) : 0.f;
            float x2 = 0.f;
            if (up) {
                float e2 = eii + ejl2;
                e2 = e2 > 0.f ? e2 : 0.2f * e2;
                x2 = bit2 ? __expf(e2) : 0.f;
            }
            s_p[i][l] = __float2bfloat16(x1);
            s_p[i][l + 64] = __float2bfloat16(x2);
            aw = nw;
        }
    }
    __syncthreads();

    // ---- phase 3: MFMA — O = P_u @ WhsT and rowsum = P_u @ ones ----
    {
        f32x16 acc = {};
        f32x16 accs = {};
        short8 ones;
#pragma unroll
        for (int e = 0; e < 8; ++e) ones[e] = (short)0x3F80;
#pragma unroll
        for (int s = 0; s < 8; ++s) {
            const int k0 = s * 16 + half * 8;
            const short8 afrag = *reinterpret_cast<const short8*>(&s_p[w * 32 + nn][k0]);
            short8 bfrag;
#pragma unroll
            for (int e = 0; e < 8; ++e) bfrag[e] = bfb(s_whs[k0 + e][nn]);
            acc = __builtin_amdgcn_mfma_f32_32x32x16_bf16(afrag, bfrag, acc, 0, 0, 0);
            accs = __builtin_amdgcn_mfma_f32_32x32x16_bf16(afrag, ones, accs, 0, 0, 0);
        }
        const int f = h * 32 + nn;
        const float gg = g[f], bb = bta[f], mm = mn[f];
        const float rstd = rsqrtf(vr[f] + 1e-5f);
        const float vadd = ADD_H ? 0.1f * vn[(size_t)b * HID + f] : 0.f;
        float psum = 0.f;
#pragma unroll
        for (int reg = 0; reg < 16; ++reg) {
            const int row = (reg & 3) + 8 * (reg >> 2) + 4 * half;
            const int i = w * 32 + row;
            if (i < N_NODES) {
                const size_t off = ((size_t)b * N_NODES + i) * HID + f;
                const float aval = acc[reg] / accs[reg];
                float xv = elu1((aval - mm) * rstd * gg + bb);
                float outv = xv + s_whs[i][nn];
                if (ADD_H) outv += hin[off] + vadd;
                hout[off] = outv;
                psum += outv;
            }
        }
        s_red[w][lane] = psum;
    }
    __syncthreads();
    if (t < 32) {
        float s = 0.f;
#pragma unroll
        for (int w2 = 0; w2 < 4; ++w2) s += s_red[w2][t] + s_red[w2][t + 32];
        premean[(size_t)b * HID + h * 32 + t] = s * (1.f / N_NODES);
    }
}

// ---------------- vn0 = vne + mean_n(h) ----------------
__global__ __launch_bounds__(128) void vn0_kernel(
    const float* __restrict__ h, const float* __restrict__ vne,
    float* __restrict__ vn)
{
    const int b = blockIdx.x, f = threadIdx.x;
    float s = 0.f;
    for (int n = 0; n < N_NODES; ++n) s += h[(size_t)b * HROW + n * HID + f];
    vn[b * HID + f] = vne[f] + s * (1.f / N_NODES);
}

// ---------------- vn_out = elu(cat([prev, premean]) @ Wv + bv) ------------
__global__ __launch_bounds__(128) void vn_mlp_kernel(
    const float* __restrict__ prev, const float* __restrict__ premean,
    const float* __restrict__ Wv, const float* __restrict__ bv,
    float* __restrict__ vout)
{
    __shared__ float cat[2 * HID];
    const int b = blockIdx.x, f = threadIdx.x;
    cat[f] = prev[b * HID + f];
    cat[HID + f] = premean[b * HID + f];
    __syncthreads();
    float acc = bv[f];
    for (int k = 0; k < 2 * HID; ++k) acc += cat[k] * Wv[k * HID + f];
    vout[b * HID + f] = elu1(acc);
}

// ---------------- pooling + net attention + flat + LayerNorm --------------
// also emits flatb (bf16 copy of flat) for the MFMA classifier
__global__ __launch_bounds__(128) void pool_flat_kernel(
    const float* __restrict__ h, const float* __restrict__ vnf,
    const float* __restrict__ pm,
    const float* __restrict__ Wa1, const float* __restrict__ ba1,
    const float* __restrict__ Wa2, const float* __restrict__ ba2,
    const float* __restrict__ ln_g, const float* __restrict__ ln_b,
    float* __restrict__ out, short* __restrict__ flatb)
{
    __shared__ float s_pm[N_NODES * 9];
    __shared__ float s_p[9][HID];
    __shared__ float s_s[9];
    __shared__ float s_red[4];
    const int b = blockIdx.x, f = threadIdx.x;
    for (int idx = f; idx < N_NODES * 9; idx += 128) s_pm[idx] = pm[idx];
    float p[9] = {};
    __syncthreads();
    for (int n = 0; n < N_NODES; ++n) {
        const float hv = h[(size_t)b * HROW + n * HID + f];
#pragma unroll
        for (int k = 0; k < 9; ++k) p[k] += s_pm[n * 9 + k] * hv;
    }
#pragma unroll
    for (int k = 0; k < 9; ++k) s_p[k][f] = p[k];
    __syncthreads();
    for (int pass = 0; pass < 3; ++pass) {
        const int k = pass * 4 + (f >> 5);
        if (k < 9) {
            const int j = f & 31;
            float z = ba1[j];
            for (int d = 0; d < HID; ++d) z += s_p[k][d] * Wa1[d * 32 + j];
            z = tanhf(z);
            float part = z * Wa2[j];
#pragma unroll
            for (int off = 16; off; off >>= 1) part += __shfl_xor(part, off);
            if (j == 0) s_s[k] = part + ba2[0];
        }
    }
    __syncthreads();
    float smax = -1e30f;
#pragma unroll
    for (int k = 0; k < 9; ++k) smax = fmaxf(smax, s_s[k]);
    float wgt[9], ssum = 0.f;
#pragma unroll
    for (int k = 0; k < 9; ++k) { wgt[k] = expf(s_s[k] - smax); ssum += wgt[k]; }
    const float sinv = 1.f / ssum;
    float vals[10];
#pragma unroll
    for (int k = 0; k < 9; ++k) vals[k] = p[k] * wgt[k] * sinv;
    vals[9] = vnf[b * HID + f];
    float lsum = 0.f, lsq = 0.f;
#pragma unroll
    for (int q = 0; q < 10; ++q) { lsum += vals[q]; lsq += vals[q] * vals[q]; }
#pragma unroll
    for (int off = 32; off; off >>= 1) {
        lsum += __shfl_xor(lsum, off);
        lsq += __shfl_xor(lsq, off);
    }
    const int lane = f & 63, wid = f >> 6;
    if (lane == 0) { s_red[wid * 2] = lsum; s_red[wid * 2 + 1] = lsq; }
    __syncthreads();
    const float tot = s_red[0] + s_red[2];
    const float totsq = s_red[1] + s_red[3];
    const float mean = tot * (1.f / FLAT_DIM);
    const float var = totsq * (1.f / FLAT_DIM) - mean * mean;
    const float rstd = rsqrtf(var + 1e-5f);
    float* fout = out + 1024 + (size_t)b * FLAT_DIM;
    short* fb = flatb + (size_t)b * FLAT_DIM;
#pragma unroll
    for (int k = 0; k < 9; ++k) {
        const int j = k * HID + f;
        const float v = (vals[k] - mean) * rstd * ln_g[j] + ln_b[j];
        fout[j] = v;
        fb[j] = bfb(v);
    }
    const int j = 9 * HID + f;
    const float v9 = (vals[9] - mean) * rstd * ln_g[j] + ln_b[j];
    fout[j] = v9;
    fb[j] = bfb(v9);
}

// ---------------- classifier stage 1: hid = elu(flat @ Wc1 + bc1), MFMA ---
// grid: 16 M-tiles x 2 N-halves; wave w -> col-tile (nh*128 + 32w)
__global__ __launch_bounds__(256) void cls_mm_kernel(
    const short* __restrict__ flatb, const short* __restrict__ wc1t,
    const float* __restrict__ bc1, float* __restrict__ hid)
{
    const int t = threadIdx.x;
    const int lane = t & 63, w = t >> 6;
    const int half = lane >> 5, nn = lane & 31;
    const int mt = blockIdx.x >> 1;
    const int nh = blockIdx.x & 1;
    const int r0 = mt * 32;
    const int c0 = nh * 128 + w * 32;
    const short8* ap = reinterpret_cast<const short8*>(flatb + (size_t)(r0 + nn) * FLAT_DIM);
    const short8* bp = reinterpret_cast<const short8*>(wc1t + (size_t)(c0 + nn) * FLAT_DIM);
    f32x16 acc = {};
#pragma unroll 8
    for (int s = 0; s < 80; ++s) {
        const int fi = s * 2 + half;
        acc = __builtin_amdgcn_mfma_f32_32x32x16_bf16(ap[fi], bp[fi], acc, 0, 0, 0);
    }
    const float bb = bc1[c0 + nn];
#pragma unroll
    for (int reg = 0; reg < 16; ++reg) {
        const int row = (reg & 3) + 8 * (reg >> 2) + 4 * half;
        hid[(size_t)(r0 + row) * 256 + c0 + nn] = elu1(acc[reg] + bb);
    }
}

// ---------------- classifier stage 2: logits = hid @ Wc2 + bc2 (f32) ------
__global__ __launch_bounds__(256) void logits_kernel(
    const float* __restrict__ hid, const float* __restrict__ Wc2,
    const float* __restrict__ bc2, float* __restrict__ out)
{
    const int idx = blockIdx.x * 256 + threadIdx.x;  // 0..1023
    const int row = idx >> 1, c = idx & 1;
    const float4* hp = reinterpret_cast<const float4*>(hid + (size_t)row * 256);
    float acc = 0.f;
#pragma unroll 8
    for (int q = 0; q < 64; ++q) {
        const float4 hv = hp[q];
        acc += hv.x * Wc2[(q * 4 + 0) * 2 + c] + hv.y * Wc2[(q * 4 + 1) * 2 + c]
             + hv.z * Wc2[(q * 4 + 2) * 2 + c] + hv.w * Wc2[(q * 4 + 3) * 2 + c];
    }
    out[idx] = acc + bc2[c];
}

extern "C" void kernel_launch(void* const* d_in, const int* in_sizes, int n_in,
                              void* d_out, int out_size, void* d_ws, size_t ws_size,
                              hipStream_t stream)
{
    const float* x     = (const float*)d_in[0];
    const float* adj   = (const float*)d_in[1];
    const float* W_enc = (const float*)d_in[2];
    const float* b_enc = (const float*)d_in[3];
    const float* bn_g  = (const float*)d_in[4];
    const float* bn_b  = (const float*)d_in[5];
    const float* bn_m  = (const float*)d_in[6];
    const float* bn_v  = (const float*)d_in[7];
    const float* vne   = (const float*)d_in[8];
    const float* W1    = (const float*)d_in[9];
    const float* a1    = (const float*)d_in[10];
    const float* g1    = (const float*)d_in[11];
    const float* bt1   = (const float*)d_in[12];
    const float* m1    = (const float*)d_in[13];
    const float* v1    = (const float*)d_in[14];
    const float* W2    = (const float*)d_in[15];
    const float* a2    = (const float*)d_in[16];
    const float* g2    = (const float*)d_in[17];
    const float* bt2   = (const float*)d_in[18];
    const float* m2    = (const float*)d_in[19];
    const float* v2    = (const float*)d_in[20];
    const float* Wv    = (const float*)d_in[21];
    const float* bv    = (const float*)d_in[22];
    const float* pm    = (const float*)d_in[23];
    const float* Wa1   = (const float*)d_in[24];
    const float* ba1   = (const float*)d_in[25];
    const float* Wa2   = (const float*)d_in[26];
    const float* ba2   = (const float*)d_in[27];
    const float* ln_g  = (const float*)d_in[28];
    const float* ln_b  = (const float*)d_in[29];
    const float* Wc1   = (const float*)d_in[30];
    const float* bc1   = (const float*)d_in[31];
    const float* Wc2   = (const float*)d_in[32];
    const float* bc2   = (const float*)d_in[33];
    float* out = (float*)d_out;

    float* ws = (float*)d_ws;
    float* hA   = ws;                                 // 7,602,176 floats
    float* hB   = hA + (size_t)BN_TOT * HID;          // 7,602,176
    float* vn0  = hB + (size_t)BN_TOT * HID;
    float* vnn  = vn0 + BATCH * HID;
    float* vnf  = vnn + BATCH * HID;
    float* pms1 = vnf + BATCH * HID;
    float* pms2 = pms1 + BATCH * HID;
    unsigned int* adjp = (unsigned int*)(pms2 + BATCH * HID);  // 237,568 uints
    short* Wt1  = (short*)(adjp + (size_t)BN_TOT * 4);         // 16384 shorts each
    short* We1  = Wt1 + 16384;
    short* Wt2  = We1 + 16384;
    short* We2  = Wt2 + 16384;
    // classifier scratch lives inside hB (free after GAT layer 2)
    short* flatb = (short*)hB;                        // 655,360 shorts
    short* wc1t  = flatb + (size_t)BATCH * FLAT_DIM;  // 327,680 shorts
    float* hid   = (float*)(wc1t + 256 * FLAT_DIM);   // 131,072 floats

    // prep: bf16 weights + folded attention vectors + packed adjacency
    wprep_kernel<<<64, 256, 0, stream>>>(W1, a1, Wt1, We1);
    wprep_kernel<<<64, 256, 0, stream>>>(W2, a2, Wt2, We2);
    adjpack_kernel<<<BN_TOT / 4, 256, 0, stream>>>(adj, adjp);

    enc_kernel<<<BN_TOT / ROWS, 128, 0, stream>>>(x, W_enc, b_enc, bn_g, bn_b,
                                                  bn_m, bn_v, hA);
    vn0_kernel<<<BATCH, 128, 0, stream>>>(hA, vne, vn0);
    // GAT layer 1: hA -> hB
    gat_fused<false><<<BATCH * HEADS, 256, 0, stream>>>(
        hA, hB, Wt1, We1, adjp, g1, bt1, m1, v1, nullptr, pms1);
    vn_mlp_kernel<<<BATCH, 128, 0, stream>>>(vn0, pms1, Wv, bv, vnn);
    // GAT layer 2 (+h residual, +0.1*vnn fused): hB -> hA
    gat_fused<true><<<BATCH * HEADS, 256, 0, stream>>>(
        hB, hA, Wt2, We2, adjp, g2, bt2, m2, v2, vnn, pms2);
    vn_mlp_kernel<<<BATCH, 128, 0, stream>>>(vnn, pms2, Wv, bv, vnf);
    // hB now free: prep classifier weights into it
    wc1prep_kernel<<<1280, 256, 0, stream>>>(Wc1, wc1t);
    // pooling + flat + LayerNorm (writes out[1024:] and flatb)
    pool_flat_kernel<<<BATCH, 128, 0, stream>>>(hA, vnf, pm, Wa1, ba1, Wa2, ba2,
                                                ln_g, ln_b, out, flatb);
    // classifier: MFMA GEMM + tiny logits pass (writes out[0:1024])
    cls_mm_kernel<<<32, 256, 0, stream>>>(flatb, wc1t, bc1, hid);
    logits_kernel<<<4, 256, 0, stream>>>(hid, Wc2, bc2, out);
}

// Round 10
// 248.027 us; speedup vs baseline: 3.5526x; 1.1165x over previous
//
#include <hip/hip_runtime.h>
#include <hip/hip_bf16.h>
#include <math.h>

#define BATCH 512
#define N_NODES 116
#define IN_DIM 123
#define HID 128
#define HEADS 4
#define FLAT_DIM 1280

static constexpr int BN_TOT = BATCH * N_NODES;      // 59392
static constexpr int HROW = N_NODES * HID;          // 14848
static constexpr int ADJROW = N_NODES * N_NODES;    // 13456

typedef short short8 __attribute__((ext_vector_type(8)));
typedef float f32x16 __attribute__((ext_vector_type(16)));

__device__ __forceinline__ float elu1(float x) {
    return x > 0.f ? x : expm1f(x);
}
__device__ __forceinline__ short bfb(float x) {
    __hip_bfloat16 b = __float2bfloat16(x);
    return *reinterpret_cast<short*>(&b);
}

// ---------------- x prep: f32 [row][123] -> bf16 [row][128] zero-pad ------
__global__ __launch_bounds__(256) void xprep_kernel(
    const float* __restrict__ x, short* __restrict__ xb)
{
    const int idx = blockIdx.x * 256 + threadIdx.x;
    const int row = idx >> 7, k = idx & 127;
    xb[idx] = (k < IN_DIM) ? bfb(x[(size_t)row * IN_DIM + k]) : (short)0;
}

// ---------------- W_enc prep: bf16 [col][k=128] zero-pad ------------------
__global__ __launch_bounds__(256) void wencprep_kernel(
    const float* __restrict__ W, short* __restrict__ Wb)
{
    const int idx = blockIdx.x * 256 + threadIdx.x;  // 0..16383
    const int col = idx >> 7, k = idx & 127;
    Wb[idx] = (k < IN_DIM) ? bfb(W[(size_t)k * HID + col]) : (short)0;
}

// ---------------- encoder via MFMA: h = BN(elu(xb @ Wencb + b)) -----------
// 464 blocks x 4 waves; wave = 32-row band; no LDS, no barriers
__global__ __launch_bounds__(256) void enc_mfma(
    const short* __restrict__ xb, const short* __restrict__ Wencb,
    const float* __restrict__ bias,
    const float* __restrict__ g, const float* __restrict__ bta,
    const float* __restrict__ mn, const float* __restrict__ vr,
    float* __restrict__ hout)
{
    const int t = threadIdx.x;
    const int lane = t & 63, w = t >> 6;
    const int half = lane >> 5, nn = lane & 31;
    const int row0 = blockIdx.x * 128 + w * 32;
    const short8* ap = reinterpret_cast<const short8*>(xb + (size_t)(row0 + nn) * 128);
    short8 af[8];
#pragma unroll
    for (int s = 0; s < 8; ++s) af[s] = ap[s * 2 + half];
#pragma unroll
    for (int ct = 0; ct < 4; ++ct) {
        const int col = ct * 32 + nn;
        const short8* bp = reinterpret_cast<const short8*>(Wencb + (size_t)col * 128);
        f32x16 acc = {};
#pragma unroll
        for (int s = 0; s < 8; ++s)
            acc = __builtin_amdgcn_mfma_f32_32x32x16_bf16(af[s], bp[s * 2 + half], acc, 0, 0, 0);
        const float bb = bias[col];
        const float gg = g[col], bbn = bta[col], mm = mn[col];
        const float rstd = rsqrtf(vr[col] + 1e-5f);
#pragma unroll
        for (int reg = 0; reg < 16; ++reg) {
            const int r = (reg & 3) + 8 * (reg >> 2) + 4 * half;
            float val = elu1(acc[reg] + bb);
            val = (val - mm) * rstd * gg + bbn;
            hout[(size_t)(row0 + r) * HID + col] = val;
        }
    }
}

// ---------------- weight prep: Wt bf16 [h][nn][k] + Weij bf16 -------------
__global__ __launch_bounds__(256) void wprep_kernel(
    const float* __restrict__ W, const float* __restrict__ a,
    short* __restrict__ Wt, short* __restrict__ Weij)
{
    const int idx = blockIdx.x * 256 + threadIdx.x;  // 0..16383
    const int h = idx >> 12, nn = (idx >> 7) & 31, k = idx & 127;
    Wt[idx] = bfb(W[k * HID + h * 32 + nn]);
    short wv = 0;
    if (nn < 2) {
        const float* ap = a + h * 64 + nn * 32;
        float s = 0.f;
#pragma unroll 8
        for (int d = 0; d < 32; ++d) s += W[k * HID + h * 32 + d] * ap[d];
        wv = bfb(s);
    }
    Weij[idx] = wv;
}

// ---------------- classifier weight prep: wc1t bf16 [n][k] ----------------
__global__ __launch_bounds__(256) void wc1prep_kernel(
    const float* __restrict__ Wc1, short* __restrict__ wc1t)
{
    const int idx = blockIdx.x * 256 + threadIdx.x;  // n fastest
    const int k = idx >> 8, n = idx & 255;
    wc1t[(size_t)n * FLAT_DIM + k] = bfb(Wc1[(size_t)k * 256 + n]);
}

// ---------------- adj bit-pack: one wave per (b,i) row --------------------
__global__ __launch_bounds__(256) void adjpack_kernel(
    const float* __restrict__ adj, unsigned int* __restrict__ adjp)
{
    const int row = blockIdx.x * 4 + (threadIdx.x >> 6);  // b*116+i
    const int l = threadIdx.x & 63;
    const float a1 = adj[(size_t)row * N_NODES + l];
    const float a2 = (l < N_NODES - 64) ? adj[(size_t)row * N_NODES + 64 + l] : 0.f;
    const unsigned long long m1 = __ballot(a1 != 0.f);
    const unsigned long long m2 = __ballot(a2 != 0.f);
    if (l == 0) {
        uint4 v;
        v.x = (unsigned int)m1; v.y = (unsigned int)(m1 >> 32);
        v.z = (unsigned int)m2; v.w = (unsigned int)(m2 >> 32);
        *reinterpret_cast<uint4*>(&adjp[(size_t)row * 4]) = v;
    }
}

// ---------------- fused GAT layer ----------------------------------------
template <bool ADD_H>
__global__ __launch_bounds__(256) void gat_fused(
    const float* __restrict__ hin, float* __restrict__ hout,
    const short* __restrict__ Wt, const short* __restrict__ Weij,
    const unsigned int* __restrict__ adjp,
    const float* __restrict__ g, const float* __restrict__ bta,
    const float* __restrict__ mn, const float* __restrict__ vr,
    const float* __restrict__ vn, float* __restrict__ premean)
{
    constexpr int KP = 136;
    __shared__ __align__(16) __hip_bfloat16 s_p[128][KP];   // 34816 B
    __shared__ float s_whs[128][32];                        // 16384 B
    __shared__ float s_ei[128];
    __shared__ float s_ej[128];
    __shared__ float s_red[4][64];                          // 53248 B -> 3 blocks/CU

    const int t = threadIdx.x;
    const int n_ = blockIdx.x;
    const int b = (n_ & 7) * 64 + (n_ >> 5);
    const int h = (n_ >> 3) & 3;

    const int lane = t & 63, w = t >> 6;
    const int half = lane >> 5, nn = lane & 31;

    // ---- phase 1: Whs = hg @ W-slice and [ei|ej] = hg @ Weij, both MFMA ----
    {
        const int row = w * 32 + nn;
        const int hr = (row < N_NODES) ? row : 0;
        const float* hrow = hin + ((size_t)b * N_NODES + hr) * HID;
        const short8* wtp = reinterpret_cast<const short8*>(Wt + ((h * 32 + nn) << 7));
        const short8* wep = reinterpret_cast<const short8*>(Weij + ((h * 32 + nn) << 7));
        f32x16 wacc = {};
        f32x16 eacc = {};
#pragma unroll
        for (int s = 0; s < 8; ++s) {
            const int k0 = s * 16 + half * 8;
            float av[8];
            *reinterpret_cast<float4*>(&av[0]) = *reinterpret_cast<const float4*>(&hrow[k0]);
            *reinterpret_cast<float4*>(&av[4]) = *reinterpret_cast<const float4*>(&hrow[k0 + 4]);
            if (ADD_H) {
                float4 v0 = *reinterpret_cast<const float4*>(&vn[(size_t)b * HID + k0]);
                float4 v1 = *reinterpret_cast<const float4*>(&vn[(size_t)b * HID + k0 + 4]);
                av[0] += 0.1f * v0.x; av[1] += 0.1f * v0.y;
                av[2] += 0.1f * v0.z; av[3] += 0.1f * v0.w;
                av[4] += 0.1f * v1.x; av[5] += 0.1f * v1.y;
                av[6] += 0.1f * v1.z; av[7] += 0.1f * v1.w;
            }
            short8 afrag;
#pragma unroll
            for (int e = 0; e < 8; ++e) afrag[e] = bfb(av[e]);
            const int fi = s * 2 + half;
            wacc = __builtin_amdgcn_mfma_f32_32x32x16_bf16(afrag, wtp[fi], wacc, 0, 0, 0);
            eacc = __builtin_amdgcn_mfma_f32_32x32x16_bf16(afrag, wep[fi], eacc, 0, 0, 0);
        }
#pragma unroll
        for (int reg = 0; reg < 16; ++reg) {
            const int r = (reg & 3) + 8 * (reg >> 2) + 4 * half;
            s_whs[w * 32 + r][nn] = wacc[reg];
        }
        if (nn == 0) {
#pragma unroll
            for (int reg = 0; reg < 16; ++reg) {
                const int r = (reg & 3) + 8 * (reg >> 2) + 4 * half;
                s_ei[w * 32 + r] = eacc[reg];
            }
        }
        if (nn == 1) {
#pragma unroll
            for (int reg = 0; reg < 16; ++reg) {
                const int r = (reg & 3) + 8 * (reg >> 2) + 4 * half;
                s_ej[w * 32 + r] = eacc[reg];
            }
        }
    }
    for (int idx = t; idx < 12 * 32; idx += 256)
        s_whs[116 + (idx >> 5)][idx & 31] = 0.f;
    __syncthreads();

    // ---- phase 2: unnormalized exp scores from packed adj ----
    {
        const int l = lane;
        const float ejl = s_ej[l];
        const bool up = (l < N_NODES - 64);
        const float ejl2 = up ? s_ej[l + 64] : 0.f;
        const int i0 = w * 29;
        const uint4* ap = reinterpret_cast<const uint4*>(
            adjp + ((size_t)b * N_NODES + i0) * 4);
        uint4 aw = ap[0];
        for (int ii = 0; ii < 29; ++ii) {
            uint4 nw = aw;
            if (ii + 1 < 29) nw = ap[ii + 1];
            const int i = i0 + ii;
            const float eii = s_ei[i];
            const unsigned int w1 = (l & 32) ? aw.y : aw.x;
            const unsigned int w2 = (l & 32) ? aw.w : aw.z;
            const bool bit1 = (w1 >> (l & 31)) & 1;
            const bool bit2 = (w2 >> (l & 31)) & 1;
            float e1 = eii + ejl;
            e1 = e1 > 0.f ? e1 : 0.2f * e1;
            const float x1 = bit1 ? __expf(e1) : 0.f;
            float x2 = 0.f;
            if (up) {
                float e2 = eii + ejl2;
                e2 = e2 > 0.f ? e2 : 0.2f * e2;
                x2 = bit2 ? __expf(e2) : 0.f;
            }
            s_p[i][l] = __float2bfloat16(x1);
            s_p[i][l + 64] = __float2bfloat16(x2);
            aw = nw;
        }
    }
    __syncthreads();

    // ---- phase 3: MFMA — O = P_u @ WhsT and rowsum = P_u @ ones ----
    {
        f32x16 acc = {};
        f32x16 accs = {};
        short8 ones;
#pragma unroll
        for (int e = 0; e < 8; ++e) ones[e] = (short)0x3F80;
#pragma unroll
        for (int s = 0; s < 8; ++s) {
            const int k0 = s * 16 + half * 8;
            const short8 afrag = *reinterpret_cast<const short8*>(&s_p[w * 32 + nn][k0]);
            short8 bfrag;
#pragma unroll
            for (int e = 0; e < 8; ++e) bfrag[e] = bfb(s_whs[k0 + e][nn]);
            acc = __builtin_amdgcn_mfma_f32_32x32x16_bf16(afrag, bfrag, acc, 0, 0, 0);
            accs = __builtin_amdgcn_mfma_f32_32x32x16_bf16(afrag, ones, accs, 0, 0, 0);
        }
        const int f = h * 32 + nn;
        const float gg = g[f], bb = bta[f], mm = mn[f];
        const float rstd = rsqrtf(vr[f] + 1e-5f);
        const float vadd = ADD_H ? 0.1f * vn[(size_t)b * HID + f] : 0.f;
        float psum = 0.f;
#pragma unroll
        for (int reg = 0; reg < 16; ++reg) {
            const int row = (reg & 3) + 8 * (reg >> 2) + 4 * half;
            const int i = w * 32 + row;
            if (i < N_NODES) {
                const size_t off = ((size_t)b * N_NODES + i) * HID + f;
                const float aval = acc[reg] / accs[reg];
                float xv = elu1((aval - mm) * rstd * gg + bb);
                float outv = xv + s_whs[i][nn];
                if (ADD_H) outv += hin[off] + vadd;
                hout[off] = outv;
                psum += outv;
            }
        }
        s_red[w][lane] = psum;
    }
    __syncthreads();
    if (t < 32) {
        float s = 0.f;
#pragma unroll
        for (int w2 = 0; w2 < 4; ++w2) s += s_red[w2][t] + s_red[w2][t + 32];
        premean[(size_t)b * HID + h * 32 + t] = s * (1.f / N_NODES);
    }
}

// ---------------- vn0 = vne + mean_n(h) ----------------
__global__ __launch_bounds__(128) void vn0_kernel(
    const float* __restrict__ h, const float* __restrict__ vne,
    float* __restrict__ vn)
{
    const int b = blockIdx.x, f = threadIdx.x;
    float s = 0.f;
    for (int n = 0; n < N_NODES; ++n) s += h[(size_t)b * HROW + n * HID + f];
    vn[b * HID + f] = vne[f] + s * (1.f / N_NODES);
}

// ---------------- vn_out = elu(cat([prev, premean]) @ Wv + bv) ------------
__global__ __launch_bounds__(128) void vn_mlp_kernel(
    const float* __restrict__ prev, const float* __restrict__ premean,
    const float* __restrict__ Wv, const float* __restrict__ bv,
    float* __restrict__ vout)
{
    __shared__ float cat[2 * HID];
    const int b = blockIdx.x, f = threadIdx.x;
    cat[f] = prev[b * HID + f];
    cat[HID + f] = premean[b * HID + f];
    __syncthreads();
    float acc = bv[f];
    for (int k = 0; k < 2 * HID; ++k) acc += cat[k] * Wv[k * HID + f];
    vout[b * HID + f] = elu1(acc);
}

// ---------------- pooling + net attention + flat + LayerNorm --------------
__global__ __launch_bounds__(128) void pool_flat_kernel(
    const float* __restrict__ h, const float* __restrict__ vnf,
    const float* __restrict__ pm,
    const float* __restrict__ Wa1, const float* __restrict__ ba1,
    const float* __restrict__ Wa2, const float* __restrict__ ba2,
    const float* __restrict__ ln_g, const float* __restrict__ ln_b,
    float* __restrict__ out, short* __restrict__ flatb)
{
    __shared__ float s_pm[N_NODES * 9];
    __shared__ float s_p[9][HID];
    __shared__ float s_s[9];
    __shared__ float s_red[4];
    const int b = blockIdx.x, f = threadIdx.x;
    for (int idx = f; idx < N_NODES * 9; idx += 128) s_pm[idx] = pm[idx];
    float p[9] = {};
    __syncthreads();
    for (int n = 0; n < N_NODES; ++n) {
        const float hv = h[(size_t)b * HROW + n * HID + f];
#pragma unroll
        for (int k = 0; k < 9; ++k) p[k] += s_pm[n * 9 + k] * hv;
    }
#pragma unroll
    for (int k = 0; k < 9; ++k) s_p[k][f] = p[k];
    __syncthreads();
    for (int pass = 0; pass < 3; ++pass) {
        const int k = pass * 4 + (f >> 5);
        if (k < 9) {
            const int j = f & 31;
            float z = ba1[j];
            for (int d = 0; d < HID; ++d) z += s_p[k][d] * Wa1[d * 32 + j];
            z = tanhf(z);
            float part = z * Wa2[j];
#pragma unroll
            for (int off = 16; off; off >>= 1) part += __shfl_xor(part, off);
            if (j == 0) s_s[k] = part + ba2[0];
        }
    }
    __syncthreads();
    float smax = -1e30f;
#pragma unroll
    for (int k = 0; k < 9; ++k) smax = fmaxf(smax, s_s[k]);
    float wgt[9], ssum = 0.f;
#pragma unroll
    for (int k = 0; k < 9; ++k) { wgt[k] = expf(s_s[k] - smax); ssum += wgt[k]; }
    const float sinv = 1.f / ssum;
    float vals[10];
#pragma unroll
    for (int k = 0; k < 9; ++k) vals[k] = p[k] * wgt[k] * sinv;
    vals[9] = vnf[b * HID + f];
    float lsum = 0.f, lsq = 0.f;
#pragma unroll
    for (int q = 0; q < 10; ++q) { lsum += vals[q]; lsq += vals[q] * vals[q]; }
#pragma unroll
    for (int off = 32; off; off >>= 1) {
        lsum += __shfl_xor(lsum, off);
        lsq += __shfl_xor(lsq, off);
    }
    const int lane = f & 63, wid = f >> 6;
    if (lane == 0) { s_red[wid * 2] = lsum; s_red[wid * 2 + 1] = lsq; }
    __syncthreads();
    const float tot = s_red[0] + s_red[2];
    const float totsq = s_red[1] + s_red[3];
    const float mean = tot * (1.f / FLAT_DIM);
    const float var = totsq * (1.f / FLAT_DIM) - mean * mean;
    const float rstd = rsqrtf(var + 1e-5f);
    float* fout = out + 1024 + (size_t)b * FLAT_DIM;
    short* fb = flatb + (size_t)b * FLAT_DIM;
#pragma unroll
    for (int k = 0; k < 9; ++k) {
        const int j = k * HID + f;
        const float v = (vals[k] - mean) * rstd * ln_g[j] + ln_b[j];
        fout[j] = v;
        fb[j] = bfb(v);
    }
    const int j = 9 * HID + f;
    const float v9 = (vals[9] - mean) * rstd * ln_g[j] + ln_b[j];
    fout[j] = v9;
    fb[j] = bfb(v9);
}

// ---------------- classifier stage 1: hid = elu(flat @ Wc1 + bc1), MFMA ---
__global__ __launch_bounds__(256) void cls_mm_kernel(
    const short* __restrict__ flatb, const short* __restrict__ wc1t,
    const float* __restrict__ bc1, float* __restrict__ hid)
{
    const int t = threadIdx.x;
    const int lane = t & 63, w = t >> 6;
    const int half = lane >> 5, nn = lane & 31;
    const int mt = blockIdx.x >> 1;
    const int nh = blockIdx.x & 1;
    const int r0 = mt * 32;
    const int c0 = nh * 128 + w * 32;
    const short8* ap = reinterpret_cast<const short8*>(flatb + (size_t)(r0 + nn) * FLAT_DIM);
    const short8* bp = reinterpret_cast<const short8*>(wc1t + (size_t)(c0 + nn) * FLAT_DIM);
    f32x16 acc = {};
#pragma unroll 8
    for (int s = 0; s < 80; ++s) {
        const int fi = s * 2 + half;
        acc = __builtin_amdgcn_mfma_f32_32x32x16_bf16(ap[fi], bp[fi], acc, 0, 0, 0);
    }
    const float bb = bc1[c0 + nn];
#pragma unroll
    for (int reg = 0; reg < 16; ++reg) {
        const int row = (reg & 3) + 8 * (reg >> 2) + 4 * half;
        hid[(size_t)(r0 + row) * 256 + c0 + nn] = elu1(acc[reg] + bb);
    }
}

// ---------------- classifier stage 2: logits = hid @ Wc2 + bc2 (f32) ------
__global__ __launch_bounds__(256) void logits_kernel(
    const float* __restrict__ hid, const float* __restrict__ Wc2,
    const float* __restrict__ bc2, float* __restrict__ out)
{
    const int idx = blockIdx.x * 256 + threadIdx.x;  // 0..1023
    const int row = idx >> 1, c = idx & 1;
    const float4* hp = reinterpret_cast<const float4*>(hid + (size_t)row * 256);
    float acc = 0.f;
#pragma unroll 8
    for (int q = 0; q < 64; ++q) {
        const float4 hv = hp[q];
        acc += hv.x * Wc2[(q * 4 + 0) * 2 + c] + hv.y * Wc2[(q * 4 + 1) * 2 + c]
             + hv.z * Wc2[(q * 4 + 2) * 2 + c] + hv.w * Wc2[(q * 4 + 3) * 2 + c];
    }
    out[idx] = acc + bc2[c];
}

extern "C" void kernel_launch(void* const* d_in, const int* in_sizes, int n_in,
                              void* d_out, int out_size, void* d_ws, size_t ws_size,
                              hipStream_t stream)
{
    const float* x     = (const float*)d_in[0];
    const float* adj   = (const float*)d_in[1];
    const float* W_enc = (const float*)d_in[2];
    const float* b_enc = (const float*)d_in[3];
    const float* bn_g  = (const float*)d_in[4];
    const float* bn_b  = (const float*)d_in[5];
    const float* bn_m  = (const float*)d_in[6];
    const float* bn_v  = (const float*)d_in[7];
    const float* vne   = (const float*)d_in[8];
    const float* W1    = (const float*)d_in[9];
    const float* a1    = (const float*)d_in[10];
    const float* g1    = (const float*)d_in[11];
    const float* bt1   = (const float*)d_in[12];
    const float* m1    = (const float*)d_in[13];
    const float* v1    = (const float*)d_in[14];
    const float* W2    = (const float*)d_in[15];
    const float* a2    = (const float*)d_in[16];
    const float* g2    = (const float*)d_in[17];
    const float* bt2   = (const float*)d_in[18];
    const float* m2    = (const float*)d_in[19];
    const float* v2    = (const float*)d_in[20];
    const float* Wv    = (const float*)d_in[21];
    const float* bv    = (const float*)d_in[22];
    const float* pm    = (const float*)d_in[23];
    const float* Wa1   = (const float*)d_in[24];
    const float* ba1   = (const float*)d_in[25];
    const float* Wa2   = (const float*)d_in[26];
    const float* ba2   = (const float*)d_in[27];
    const float* ln_g  = (const float*)d_in[28];
    const float* ln_b  = (const float*)d_in[29];
    const float* Wc1   = (const float*)d_in[30];
    const float* bc1   = (const float*)d_in[31];
    const float* Wc2   = (const float*)d_in[32];
    const float* bc2   = (const float*)d_in[33];
    float* out = (float*)d_out;

    float* ws = (float*)d_ws;
    float* hA   = ws;                                 // 7,602,176 floats
    float* hB   = hA + (size_t)BN_TOT * HID;          // 7,602,176
    float* vn0  = hB + (size_t)BN_TOT * HID;
    float* vnn  = vn0 + BATCH * HID;
    float* vnf  = vnn + BATCH * HID;
    float* pms1 = vnf + BATCH * HID;
    float* pms2 = pms1 + BATCH * HID;
    unsigned int* adjp = (unsigned int*)(pms2 + BATCH * HID);  // 237,568 uints
    short* Wt1  = (short*)(adjp + (size_t)BN_TOT * 4);         // 16384 shorts each
    short* We1  = Wt1 + 16384;
    short* Wt2  = We1 + 16384;
    short* We2  = Wt2 + 16384;
    short* Wencb = We2 + 16384;                                // 16384 shorts
    // transient aliases inside hB:
    short* xb    = (short*)hB;                        // dead after enc_mfma
    short* flatb = (short*)hB;                        // alive after gat2
    short* wc1t  = flatb + (size_t)BATCH * FLAT_DIM;
    float* hid   = (float*)(wc1t + 256 * FLAT_DIM);

    // prep: bf16 weights + folded attention vectors + packed adjacency + x
    wprep_kernel<<<64, 256, 0, stream>>>(W1, a1, Wt1, We1);
    wprep_kernel<<<64, 256, 0, stream>>>(W2, a2, Wt2, We2);
    wencprep_kernel<<<64, 256, 0, stream>>>(W_enc, Wencb);
    adjpack_kernel<<<BN_TOT / 4, 256, 0, stream>>>(adj, adjp);
    xprep_kernel<<<BN_TOT * 128 / 256, 256, 0, stream>>>(x, xb);

    // encoder via MFMA: xb(=hB) -> hA
    enc_mfma<<<BN_TOT / 128, 256, 0, stream>>>(xb, Wencb, b_enc, bn_g, bn_b,
                                               bn_m, bn_v, hA);
    vn0_kernel<<<BATCH, 128, 0, stream>>>(hA, vne, vn0);
    // GAT layer 1: hA -> hB (xb dead from here)
    gat_fused<false><<<BATCH * HEADS, 256, 0, stream>>>(
        hA, hB, Wt1, We1, adjp, g1, bt1, m1, v1, nullptr, pms1);
    vn_mlp_kernel<<<BATCH, 128, 0, stream>>>(vn0, pms1, Wv, bv, vnn);
    // GAT layer 2 (+h residual, +0.1*vnn fused): hB -> hA
    gat_fused<true><<<BATCH * HEADS, 256, 0, stream>>>(
        hB, hA, Wt2, We2, adjp, g2, bt2, m2, v2, vnn, pms2);
    vn_mlp_kernel<<<BATCH, 128, 0, stream>>>(vnn, pms2, Wv, bv, vnf);
    // hB now free for classifier scratch
    wc1prep_kernel<<<1280, 256, 0, stream>>>(Wc1, wc1t);
    // pooling + flat + LayerNorm (writes out[1024:] and flatb)
    pool_flat_kernel<<<BATCH, 128, 0, stream>>>(hA, vnf, pm, Wa1, ba1, Wa2, ba2,
                                                ln_g, ln_b, out, flatb);
    // classifier: MFMA GEMM + tiny logits pass (writes out[0:1024])
    cls_mm_kernel<<<32, 256, 0, stream>>>(flatb, wc1t, bc1, hid);
    logits_kernel<<<4, 256, 0, stream>>>(hid, Wc2, bc2, out);
}

// Round 11
// 239.708 us; speedup vs baseline: 3.6759x; 1.0347x over previous
//
#include <hip/hip_runtime.h>
#include <hip/hip_bf16.h>
#include <math.h>

#define BATCH 512
#define N_NODES 116
#define IN_DIM 123
#define HID 128
#define HEADS 4
#define FLAT_DIM 1280

static constexpr int BN_TOT = BATCH * N_NODES;      // 59392
static constexpr int HROW = N_NODES * HID;          // 14848
static constexpr int ADJROW = N_NODES * N_NODES;    // 13456

typedef short short8 __attribute__((ext_vector_type(8)));
typedef float f32x16 __attribute__((ext_vector_type(16)));

__device__ __forceinline__ float elu1(float x) {
    return x > 0.f ? x : __expf(x) - 1.f;
}
__device__ __forceinline__ short bfb(float x) {
    __hip_bfloat16 b = __float2bfloat16(x);
    return *reinterpret_cast<short*>(&b);
}

// ---------------- x prep: f32 [row][123] -> bf16 [row][128] zero-pad ------
__global__ __launch_bounds__(256) void xprep_kernel(
    const float* __restrict__ x, short* __restrict__ xb)
{
    const int idx = blockIdx.x * 256 + threadIdx.x;
    const int row = idx >> 7, k = idx & 127;
    xb[idx] = (k < IN_DIM) ? bfb(x[(size_t)row * IN_DIM + k]) : (short)0;
}

// ---------------- W_enc prep: bf16 [col][k=128] zero-pad ------------------
__global__ __launch_bounds__(256) void wencprep_kernel(
    const float* __restrict__ W, short* __restrict__ Wb)
{
    const int idx = blockIdx.x * 256 + threadIdx.x;  // 0..16383
    const int col = idx >> 7, k = idx & 127;
    Wb[idx] = (k < IN_DIM) ? bfb(W[(size_t)k * HID + col]) : (short)0;
}

// ---------------- encoder via MFMA: h = BN(elu(xb @ Wencb + b)) -----------
__global__ __launch_bounds__(256) void enc_mfma(
    const short* __restrict__ xb, const short* __restrict__ Wencb,
    const float* __restrict__ bias,
    const float* __restrict__ g, const float* __restrict__ bta,
    const float* __restrict__ mn, const float* __restrict__ vr,
    float* __restrict__ hout)
{
    const int t = threadIdx.x;
    const int lane = t & 63, w = t >> 6;
    const int half = lane >> 5, nn = lane & 31;
    const int row0 = blockIdx.x * 128 + w * 32;
    const short8* ap = reinterpret_cast<const short8*>(xb + (size_t)(row0 + nn) * 128);
    short8 af[8];
#pragma unroll
    for (int s = 0; s < 8; ++s) af[s] = ap[s * 2 + half];
#pragma unroll
    for (int ct = 0; ct < 4; ++ct) {
        const int col = ct * 32 + nn;
        const short8* bp = reinterpret_cast<const short8*>(Wencb + (size_t)col * 128);
        f32x16 acc = {};
#pragma unroll
        for (int s = 0; s < 8; ++s)
            acc = __builtin_amdgcn_mfma_f32_32x32x16_bf16(af[s], bp[s * 2 + half], acc, 0, 0, 0);
        const float bb = bias[col];
        const float gg = g[col], bbn = bta[col], mm = mn[col];
        const float rstd = rsqrtf(vr[col] + 1e-5f);
#pragma unroll
        for (int reg = 0; reg < 16; ++reg) {
            const int r = (reg & 3) + 8 * (reg >> 2) + 4 * half;
            float val = elu1(acc[reg] + bb);
            val = (val - mm) * rstd * gg + bbn;
            hout[(size_t)(row0 + r) * HID + col] = val;
        }
    }
}

// ---------------- weight prep: Wt bf16 [h][nn][k] + Weij bf16 -------------
__global__ __launch_bounds__(256) void wprep_kernel(
    const float* __restrict__ W, const float* __restrict__ a,
    short* __restrict__ Wt, short* __restrict__ Weij)
{
    const int idx = blockIdx.x * 256 + threadIdx.x;  // 0..16383
    const int h = idx >> 12, nn = (idx >> 7) & 31, k = idx & 127;
    Wt[idx] = bfb(W[k * HID + h * 32 + nn]);
    short wv = 0;
    if (nn < 2) {
        const float* ap = a + h * 64 + nn * 32;
        float s = 0.f;
#pragma unroll 8
        for (int d = 0; d < 32; ++d) s += W[k * HID + h * 32 + d] * ap[d];
        wv = bfb(s);
    }
    Weij[idx] = wv;
}

// ---------------- classifier weight prep: wc1t bf16 [n][k] ----------------
__global__ __launch_bounds__(256) void wc1prep_kernel(
    const float* __restrict__ Wc1, short* __restrict__ wc1t)
{
    const int idx = blockIdx.x * 256 + threadIdx.x;  // n fastest
    const int k = idx >> 8, n = idx & 255;
    wc1t[(size_t)n * FLAT_DIM + k] = bfb(Wc1[(size_t)k * 256 + n]);
}

// ---------------- adj bit-pack: one wave per (b,i) row --------------------
__global__ __launch_bounds__(256) void adjpack_kernel(
    const float* __restrict__ adj, unsigned int* __restrict__ adjp)
{
    const int row = blockIdx.x * 4 + (threadIdx.x >> 6);  // b*116+i
    const int l = threadIdx.x & 63;
    const float a1 = adj[(size_t)row * N_NODES + l];
    const float a2 = (l < N_NODES - 64) ? adj[(size_t)row * N_NODES + 64 + l] : 0.f;
    const unsigned long long m1 = __ballot(a1 != 0.f);
    const unsigned long long m2 = __ballot(a2 != 0.f);
    if (l == 0) {
        uint4 v;
        v.x = (unsigned int)m1; v.y = (unsigned int)(m1 >> 32);
        v.z = (unsigned int)m2; v.w = (unsigned int)(m2 >> 32);
        *reinterpret_cast<uint4*>(&adjp[(size_t)row * 4]) = v;
    }
}

// ---------------- fused GAT layer ----------------------------------------
// LDS 40928 B -> 4 blocks/CU. Phase 2 is wave-local (rows 32w..32w+31),
// so no barrier between phase 2 and phase 3. ei/ej buffer reused for the
// premean partials after the post-phase-3 barrier.
template <bool ADD_H>
__global__ __launch_bounds__(256, 4) void gat_fused(
    const float* __restrict__ hin, float* __restrict__ hout,
    const short* __restrict__ Wt, const short* __restrict__ Weij,
    const unsigned int* __restrict__ adjp,
    const float* __restrict__ g, const float* __restrict__ bta,
    const float* __restrict__ mn, const float* __restrict__ vr,
    const float* __restrict__ vn, float* __restrict__ premean)
{
    constexpr int KP = 136;  // s_p pitch (shorts): 272 B rows, 16B-aligned
    constexpr int WP = 33;   // s_whsb pitch (shorts): odd-ish stride, conflict-free
    __shared__ __align__(16) __hip_bfloat16 s_p[N_NODES][KP];   // 31552 B
    __shared__ __align__(16) __hip_bfloat16 s_whsb[128][WP];    // 8448 B
    __shared__ float s_eir[232];  // ei=[0,116), ej=[116,232); reused as red[4][32]

    const int t = threadIdx.x;
    // XCD-grouping remap: 4 head-blocks of one b stay on one XCD
    const int n_ = blockIdx.x;
    const int b = (n_ & 7) * 64 + (n_ >> 5);
    const int h = (n_ >> 3) & 3;

    const int lane = t & 63, w = t >> 6;
    const int half = lane >> 5, nn = lane & 31;

    // ---- phase 1: Whs = hg @ W-slice and [ei|ej] = hg @ Weij, both MFMA ----
    {
        const int row = w * 32 + nn;
        const int hr = (row < N_NODES) ? row : 0;   // clamp keeps dead rows finite
        const float* hrow = hin + ((size_t)b * N_NODES + hr) * HID;
        const short8* wtp = reinterpret_cast<const short8*>(Wt + ((h * 32 + nn) << 7));
        const short8* wep = reinterpret_cast<const short8*>(Weij + ((h * 32 + nn) << 7));
        f32x16 wacc = {};
        f32x16 eacc = {};
#pragma unroll
        for (int s = 0; s < 8; ++s) {
            const int k0 = s * 16 + half * 8;
            float av[8];
            *reinterpret_cast<float4*>(&av[0]) = *reinterpret_cast<const float4*>(&hrow[k0]);
            *reinterpret_cast<float4*>(&av[4]) = *reinterpret_cast<const float4*>(&hrow[k0 + 4]);
            if (ADD_H) {
                float4 v0 = *reinterpret_cast<const float4*>(&vn[(size_t)b * HID + k0]);
                float4 v1 = *reinterpret_cast<const float4*>(&vn[(size_t)b * HID + k0 + 4]);
                av[0] += 0.1f * v0.x; av[1] += 0.1f * v0.y;
                av[2] += 0.1f * v0.z; av[3] += 0.1f * v0.w;
                av[4] += 0.1f * v1.x; av[5] += 0.1f * v1.y;
                av[6] += 0.1f * v1.z; av[7] += 0.1f * v1.w;
            }
            short8 afrag;
#pragma unroll
            for (int e = 0; e < 8; ++e) afrag[e] = bfb(av[e]);
            const int fi = s * 2 + half;
            wacc = __builtin_amdgcn_mfma_f32_32x32x16_bf16(afrag, wtp[fi], wacc, 0, 0, 0);
            eacc = __builtin_amdgcn_mfma_f32_32x32x16_bf16(afrag, wep[fi], eacc, 0, 0, 0);
        }
        // scatter Whs tile as bf16 (C: col=nn, row=(reg&3)+8*(reg>>2)+4*half)
#pragma unroll
        for (int reg = 0; reg < 16; ++reg) {
            const int r = (reg & 3) + 8 * (reg >> 2) + 4 * half;
            s_whsb[w * 32 + r][nn] = __float2bfloat16(wacc[reg]);
        }
        if (nn == 0) {
#pragma unroll
            for (int reg = 0; reg < 16; ++reg) {
                const int r = w * 32 + (reg & 3) + 8 * (reg >> 2) + 4 * half;
                if (r < N_NODES) s_eir[r] = eacc[reg];
            }
        }
        if (nn == 1) {
#pragma unroll
            for (int reg = 0; reg < 16; ++reg) {
                const int r = w * 32 + (reg & 3) + 8 * (reg >> 2) + 4 * half;
                if (r < N_NODES) s_eir[N_NODES + r] = eacc[reg];
            }
        }
    }
    __syncthreads();

    // ---- phase 2 (wave-local rows): unnormalized exp scores ----
    {
        const int l = lane;
        const float ejl = s_eir[N_NODES + l];
        const bool up = (l < N_NODES - 64);
        const float ejl2 = up ? s_eir[N_NODES + l + 64] : 0.f;
        const int i0 = w * 32;
        const int cnt = min(32, N_NODES - i0);   // 32,32,32,20
        const uint4* ap = reinterpret_cast<const uint4*>(
            adjp + ((size_t)b * N_NODES + i0) * 4);
        uint4 aw = ap[0];
        for (int ii = 0; ii < cnt; ++ii) {
            uint4 nw = aw;
            if (ii + 1 < cnt) nw = ap[ii + 1];
            const int i = i0 + ii;
            const float eii = s_eir[i];
            const unsigned int w1 = (l & 32) ? aw.y : aw.x;
            const unsigned int w2 = (l & 32) ? aw.w : aw.z;
            const bool bit1 = (w1 >> (l & 31)) & 1;
            const bool bit2 = (w2 >> (l & 31)) & 1;
            float e1 = eii + ejl;
            e1 = e1 > 0.f ? e1 : 0.2f * e1;
            const float x1 = bit1 ? __expf(e1) : 0.f;
            float x2 = 0.f;
            if (up) {
                float e2 = eii + ejl2;
                e2 = e2 > 0.f ? e2 : 0.2f * e2;
                x2 = bit2 ? __expf(e2) : 0.f;
            }
            s_p[i][l] = __float2bfloat16(x1);
            s_p[i][l + 64] = __float2bfloat16(x2);  // zeros A-cols 116..127
            aw = nw;
        }
    }
    // no barrier: phase 3 reads only this wave's s_p rows (lgkmcnt orders them)

    // ---- phase 3: MFMA — O = P_u @ Whs and rowsum = P_u @ ones ----
    float psum = 0.f;
    {
        f32x16 acc = {};
        f32x16 accs = {};
        short8 ones;
#pragma unroll
        for (int e = 0; e < 8; ++e) ones[e] = (short)0x3F80;  // bf16 1.0
#pragma unroll
        for (int s = 0; s < 8; ++s) {
            const int k0 = s * 16 + half * 8;
            // dead A-rows (>=116) read in-allocation garbage; their C rows are discarded
            const short8 afrag = *reinterpret_cast<const short8*>(
                &s_p[0][0] + (size_t)(w * 32 + nn) * KP + k0);
            short8 bfrag;
#pragma unroll
            for (int e = 0; e < 8; ++e)
                bfrag[e] = *reinterpret_cast<const short*>(&s_whsb[k0 + e][nn]);
            acc = __builtin_amdgcn_mfma_f32_32x32x16_bf16(afrag, bfrag, acc, 0, 0, 0);
            accs = __builtin_amdgcn_mfma_f32_32x32x16_bf16(afrag, ones, accs, 0, 0, 0);
        }
        const int f = h * 32 + nn;
        const float gg = g[f], bb = bta[f], mm = mn[f];
        const float rstd = rsqrtf(vr[f] + 1e-5f);
        const float vadd = ADD_H ? 0.1f * vn[(size_t)b * HID + f] : 0.f;
#pragma unroll
        for (int reg = 0; reg < 16; ++reg) {
            const int row = (reg & 3) + 8 * (reg >> 2) + 4 * half;
            const int i = w * 32 + row;
            if (i < N_NODES) {
                const size_t off = ((size_t)b * N_NODES + i) * HID + f;
                const float aval = acc[reg] / accs[reg];
                float xv = elu1((aval - mm) * rstd * gg + bb);
                float outv = xv + __bfloat162float(s_whsb[i][nn]);
                if (ADD_H) outv += hin[off] + vadd;
                hout[off] = outv;
                psum += outv;
            }
        }
    }
    // fold the two halves (same feature f, disjoint rows)
    psum += __shfl_xor(psum, 32);
    __syncthreads();                       // all waves done reading s_eir
    if (half == 0) s_eir[w * 32 + nn] = psum;
    __syncthreads();
    if (t < 32) {
        const float s = s_eir[t] + s_eir[32 + t] + s_eir[64 + t] + s_eir[96 + t];
        premean[(size_t)b * HID + h * 32 + t] = s * (1.f / N_NODES);
    }
}

// ---------------- vn0 = vne + mean_n(h) ----------------
__global__ __launch_bounds__(128) void vn0_kernel(
    const float* __restrict__ h, const float* __restrict__ vne,
    float* __restrict__ vn)
{
    const int b = blockIdx.x, f = threadIdx.x;
    float s = 0.f;
    for (int n = 0; n < N_NODES; ++n) s += h[(size_t)b * HROW + n * HID + f];
    vn[b * HID + f] = vne[f] + s * (1.f / N_NODES);
}

// ---------------- vn_out = elu(cat([prev, premean]) @ Wv + bv) ------------
__global__ __launch_bounds__(128) void vn_mlp_kernel(
    const float* __restrict__ prev, const float* __restrict__ premean,
    const float* __restrict__ Wv, const float* __restrict__ bv,
    float* __restrict__ vout)
{
    __shared__ float cat[2 * HID];
    const int b = blockIdx.x, f = threadIdx.x;
    cat[f] = prev[b * HID + f];
    cat[HID + f] = premean[b * HID + f];
    __syncthreads();
    float acc = bv[f];
    for (int k = 0; k < 2 * HID; ++k) acc += cat[k] * Wv[k * HID + f];
    vout[b * HID + f] = elu1(acc);
}

// ---------------- pooling + net attention + flat + LayerNorm --------------
__global__ __launch_bounds__(128) void pool_flat_kernel(
    const float* __restrict__ h, const float* __restrict__ vnf,
    const float* __restrict__ pm,
    const float* __restrict__ Wa1, const float* __restrict__ ba1,
    const float* __restrict__ Wa2, const float* __restrict__ ba2,
    const float* __restrict__ ln_g, const float* __restrict__ ln_b,
    float* __restrict__ out, short* __restrict__ flatb)
{
    __shared__ float s_pm[N_NODES * 9];
    __shared__ float s_p[9][HID];
    __shared__ float s_s[9];
    __shared__ float s_red[4];
    const int b = blockIdx.x, f = threadIdx.x;
    for (int idx = f; idx < N_NODES * 9; idx += 128) s_pm[idx] = pm[idx];
    float p[9] = {};
    __syncthreads();
    for (int n = 0; n < N_NODES; ++n) {
        const float hv = h[(size_t)b * HROW + n * HID + f];
#pragma unroll
        for (int k = 0; k < 9; ++k) p[k] += s_pm[n * 9 + k] * hv;
    }
#pragma unroll
    for (int k = 0; k < 9; ++k) s_p[k][f] = p[k];
    __syncthreads();
    for (int pass = 0; pass < 3; ++pass) {
        const int k = pass * 4 + (f >> 5);
        if (k < 9) {
            const int j = f & 31;
            float z = ba1[j];
            for (int d = 0; d < HID; ++d) z += s_p[k][d] * Wa1[d * 32 + j];
            z = tanhf(z);
            float part = z * Wa2[j];
#pragma unroll
            for (int off = 16; off; off >>= 1) part += __shfl_xor(part, off);
            if (j == 0) s_s[k] = part + ba2[0];
        }
    }
    __syncthreads();
    float smax = -1e30f;
#pragma unroll
    for (int k = 0; k < 9; ++k) smax = fmaxf(smax, s_s[k]);
    float wgt[9], ssum = 0.f;
#pragma unroll
    for (int k = 0; k < 9; ++k) { wgt[k] = expf(s_s[k] - smax); ssum += wgt[k]; }
    const float sinv = 1.f / ssum;
    float vals[10];
#pragma unroll
    for (int k = 0; k < 9; ++k) vals[k] = p[k] * wgt[k] * sinv;
    vals[9] = vnf[b * HID + f];
    float lsum = 0.f, lsq = 0.f;
#pragma unroll
    for (int q = 0; q < 10; ++q) { lsum += vals[q]; lsq += vals[q] * vals[q]; }
#pragma unroll
    for (int off = 32; off; off >>= 1) {
        lsum += __shfl_xor(lsum, off);
        lsq += __shfl_xor(lsq, off);
    }
    const int lane = f & 63, wid = f >> 6;
    if (lane == 0) { s_red[wid * 2] = lsum; s_red[wid * 2 + 1] = lsq; }
    __syncthreads();
    const float tot = s_red[0] + s_red[2];
    const float totsq = s_red[1] + s_red[3];
    const float mean = tot * (1.f / FLAT_DIM);
    const float var = totsq * (1.f / FLAT_DIM) - mean * mean;
    const float rstd = rsqrtf(var + 1e-5f);
    float* fout = out + 1024 + (size_t)b * FLAT_DIM;
    short* fb = flatb + (size_t)b * FLAT_DIM;
#pragma unroll
    for (int k = 0; k < 9; ++k) {
        const int j = k * HID + f;
        const float v = (vals[k] - mean) * rstd * ln_g[j] + ln_b[j];
        fout[j] = v;
        fb[j] = bfb(v);
    }
    const int j = 9 * HID + f;
    const float v9 = (vals[9] - mean) * rstd * ln_g[j] + ln_b[j];
    fout[j] = v9;
    fb[j] = bfb(v9);
}

// ---------------- classifier stage 1: hid = elu(flat @ Wc1 + bc1), MFMA ---
__global__ __launch_bounds__(256) void cls_mm_kernel(
    const short* __restrict__ flatb, const short* __restrict__ wc1t,
    const float* __restrict__ bc1, float* __restrict__ hid)
{
    const int t = threadIdx.x;
    const int lane = t & 63, w = t >> 6;
    const int half = lane >> 5, nn = lane & 31;
    const int mt = blockIdx.x >> 1;
    const int nh = blockIdx.x & 1;
    const int r0 = mt * 32;
    const int c0 = nh * 128 + w * 32;
    const short8* ap = reinterpret_cast<const short8*>(flatb + (size_t)(r0 + nn) * FLAT_DIM);
    const short8* bp = reinterpret_cast<const short8*>(wc1t + (size_t)(c0 + nn) * FLAT_DIM);
    f32x16 acc = {};
#pragma unroll 8
    for (int s = 0; s < 80; ++s) {
        const int fi = s * 2 + half;
        acc = __builtin_amdgcn_mfma_f32_32x32x16_bf16(ap[fi], bp[fi], acc, 0, 0, 0);
    }
    const float bb = bc1[c0 + nn];
#pragma unroll
    for (int reg = 0; reg < 16; ++reg) {
        const int row = (reg & 3) + 8 * (reg >> 2) + 4 * half;
        hid[(size_t)(r0 + row) * 256 + c0 + nn] = elu1(acc[reg] + bb);
    }
}

// ---------------- classifier stage 2: logits = hid @ Wc2 + bc2 (f32) ------
__global__ __launch_bounds__(256) void logits_kernel(
    const float* __restrict__ hid, const float* __restrict__ Wc2,
    const float* __restrict__ bc2, float* __restrict__ out)
{
    const int idx = blockIdx.x * 256 + threadIdx.x;  // 0..1023
    const int row = idx >> 1, c = idx & 1;
    const float4* hp = reinterpret_cast<const float4*>(hid + (size_t)row * 256);
    float acc = 0.f;
#pragma unroll 8
    for (int q = 0; q < 64; ++q) {
        const float4 hv = hp[q];
        acc += hv.x * Wc2[(q * 4 + 0) * 2 + c] + hv.y * Wc2[(q * 4 + 1) * 2 + c]
             + hv.z * Wc2[(q * 4 + 2) * 2 + c] + hv.w * Wc2[(q * 4 + 3) * 2 + c];
    }
    out[idx] = acc + bc2[c];
}

extern "C" void kernel_launch(void* const* d_in, const int* in_sizes, int n_in,
                              void* d_out, int out_size, void* d_ws, size_t ws_size,
                              hipStream_t stream)
{
    const float* x     = (const float*)d_in[0];
    const float* adj   = (const float*)d_in[1];
    const float* W_enc = (const float*)d_in[2];
    const float* b_enc = (const float*)d_in[3];
    const float* bn_g  = (const float*)d_in[4];
    const float* bn_b  = (const float*)d_in[5];
    const float* bn_m  = (const float*)d_in[6];
    const float* bn_v  = (const float*)d_in[7];
    const float* vne   = (const float*)d_in[8];
    const float* W1    = (const float*)d_in[9];
    const float* a1    = (const float*)d_in[10];
    const float* g1    = (const float*)d_in[11];
    const float* bt1   = (const float*)d_in[12];
    const float* m1    = (const float*)d_in[13];
    const float* v1    = (const float*)d_in[14];
    const float* W2    = (const float*)d_in[15];
    const float* a2    = (const float*)d_in[16];
    const float* g2    = (const float*)d_in[17];
    const float* bt2   = (const float*)d_in[18];
    const float* m2    = (const float*)d_in[19];
    const float* v2    = (const float*)d_in[20];
    const float* Wv    = (const float*)d_in[21];
    const float* bv    = (const float*)d_in[22];
    const float* pm    = (const float*)d_in[23];
    const float* Wa1   = (const float*)d_in[24];
    const float* ba1   = (const float*)d_in[25];
    const float* Wa2   = (const float*)d_in[26];
    const float* ba2   = (const float*)d_in[27];
    const float* ln_g  = (const float*)d_in[28];
    const float* ln_b  = (const float*)d_in[29];
    const float* Wc1   = (const float*)d_in[30];
    const float* bc1   = (const float*)d_in[31];
    const float* Wc2   = (const float*)d_in[32];
    const float* bc2   = (const float*)d_in[33];
    float* out = (float*)d_out;

    float* ws = (float*)d_ws;
    float* hA   = ws;                                 // 7,602,176 floats
    float* hB   = hA + (size_t)BN_TOT * HID;          // 7,602,176
    float* vn0  = hB + (size_t)BN_TOT * HID;
    float* vnn  = vn0 + BATCH * HID;
    float* vnf  = vnn + BATCH * HID;
    float* pms1 = vnf + BATCH * HID;
    float* pms2 = pms1 + BATCH * HID;
    unsigned int* adjp = (unsigned int*)(pms2 + BATCH * HID);  // 237,568 uints
    short* Wt1  = (short*)(adjp + (size_t)BN_TOT * 4);         // 16384 shorts each
    short* We1  = Wt1 + 16384;
    short* Wt2  = We1 + 16384;
    short* We2  = Wt2 + 16384;
    short* Wencb = We2 + 16384;                                // 16384 shorts
    // transient aliases inside hB:
    short* xb    = (short*)hB;                        // dead after enc_mfma
    short* flatb = (short*)hB;                        // alive after gat2
    short* wc1t  = flatb + (size_t)BATCH * FLAT_DIM;
    float* hid   = (float*)(wc1t + 256 * FLAT_DIM);

    // prep: bf16 weights + folded attention vectors + packed adjacency + x
    wprep_kernel<<<64, 256, 0, stream>>>(W1, a1, Wt1, We1);
    wprep_kernel<<<64, 256, 0, stream>>>(W2, a2, Wt2, We2);
    wencprep_kernel<<<64, 256, 0, stream>>>(W_enc, Wencb);
    adjpack_kernel<<<BN_TOT / 4, 256, 0, stream>>>(adj, adjp);
    xprep_kernel<<<BN_TOT * 128 / 256, 256, 0, stream>>>(x, xb);

    // encoder via MFMA: xb(=hB) -> hA
    enc_mfma<<<BN_TOT / 128, 256, 0, stream>>>(xb, Wencb, b_enc, bn_g, bn_b,
                                               bn_m, bn_v, hA);
    vn0_kernel<<<BATCH, 128, 0, stream>>>(hA, vne, vn0);
    // GAT layer 1: hA -> hB (xb dead from here)
    gat_fused<false><<<BATCH * HEADS, 256, 0, stream>>>(
        hA, hB, Wt1, We1, adjp, g1, bt1, m1, v1, nullptr, pms1);
    vn_mlp_kernel<<<BATCH, 128, 0, stream>>>(vn0, pms1, Wv, bv, vnn);
    // GAT layer 2 (+h residual, +0.1*vnn fused): hB -> hA
    gat_fused<true><<<BATCH * HEADS, 256, 0, stream>>>(
        hB, hA, Wt2, We2, adjp, g2, bt2, m2, v2, vnn, pms2);
    vn_mlp_kernel<<<BATCH, 128, 0, stream>>>(vnn, pms2, Wv, bv, vnf);
    // hB now free for classifier scratch
    wc1prep_kernel<<<1280, 256, 0, stream>>>(Wc1, wc1t);
    // pooling + flat + LayerNorm (writes out[1024:] and flatb)
    pool_flat_kernel<<<BATCH, 128, 0, stream>>>(hA, vnf, pm, Wa1, ba1, Wa2, ba2,
                                                ln_g, ln_b, out, flatb);
    // classifier: MFMA GEMM + tiny logits pass (writes out[0:1024])
    cls_mm_kernel<<<32, 256, 0, stream>>>(flatb, wc1t, bc1, hid);
    logits_kernel<<<4, 256, 0, stream>>>(hid, Wc2, bc2, out);
}